// Round 5
// baseline (298.808 us; speedup 1.0000x reference)
//
#include <hip/hip_runtime.h>
#include <math.h>

#define T 2048
#define D 768
#define E 8
#define FF 3072
#define NPOS (2 * T)
#define MAXTILE 40
#define MAXTILE2 72
#define PSTRIDE ((size_t)(NPOS + 64) * D)

using bf16x8 = __attribute__((ext_vector_type(8))) short;
using f32x4  = __attribute__((ext_vector_type(4))) float;
using u16x8  = __attribute__((ext_vector_type(8))) unsigned short;

__device__ __forceinline__ unsigned short f2bf(float f) {
    union { float f; unsigned u; } v; v.f = f;
    unsigned r = v.u + 0x7FFF + ((v.u >> 16) & 1);
    return (unsigned short)(r >> 16);
}
__device__ __forceinline__ float bf2f(unsigned short u) {
    union { unsigned u; float f; } v; v.u = ((unsigned)u) << 16;
    return v.f;
}
__device__ __forceinline__ float siluf(float v) {
    return v / (1.0f + __expf(-v));
}
__device__ __forceinline__ void gload16(const void* g, void* l) {
    __builtin_amdgcn_global_load_lds(
        (const __attribute__((address_space(1))) void*)g,
        (__attribute__((address_space(3))) void*)l, 16, 0, 0);
}

// ---------------------------------------------------------------------------
// Pre-pass: x f32 -> bf16
// ---------------------------------------------------------------------------
__global__ __launch_bounds__(256)
void convert_x_kernel(const float* __restrict__ x, unsigned short* __restrict__ xb) {
    int i = blockIdx.x * 256 + threadIdx.x;
    const float4* p = (const float4*)x + (size_t)i * 2;
    float4 a = p[0], b = p[1];
    u16x8 o;
    o[0] = f2bf(a.x); o[1] = f2bf(a.y); o[2] = f2bf(a.z); o[3] = f2bf(a.w);
    o[4] = f2bf(b.x); o[5] = f2bf(b.y); o[6] = f2bf(b.z); o[7] = f2bf(b.w);
    *((u16x8*)xb + i) = o;
}

// ---------------------------------------------------------------------------
// Pre-pass: transpose+convert  in f32 [Z][R][C] -> out bf16 [Z][C][R]
// Phase-1 lane map: 16 r-values per wave-instr -> 4-way banks (was 16-way).
// ---------------------------------------------------------------------------
__global__ __launch_bounds__(256)
void transpose_convert(const float* __restrict__ in, unsigned short* __restrict__ out,
                       int R, int C) {
    __shared__ unsigned short tb[64][72];
    int z = blockIdx.z;
    int r0 = blockIdx.y * 64, c0 = blockIdx.x * 64;
    int tid = threadIdx.x;
    const float* ip = in + (size_t)z * R * C;

    int ccL = tid & 3;
    int rl  = (tid >> 2) & 15;
    int ccH = tid >> 6;
    int c = (ccH * 4 + ccL) * 4;
#pragma unroll
    for (int p = 0; p < 4; ++p) {
        int r = rl + 16 * p;
        float4 v = *(const float4*)(ip + (size_t)(r0 + r) * C + (c0 + c));
        tb[c + 0][r] = f2bf(v.x);
        tb[c + 1][r] = f2bf(v.y);
        tb[c + 2][r] = f2bf(v.z);
        tb[c + 3][r] = f2bf(v.w);
    }
    __syncthreads();
    unsigned short* op = out + (size_t)z * R * C + (size_t)c0 * R + r0;
    int cc = tid >> 2;
    int rs = (tid & 3) * 16;
#pragma unroll
    for (int i = 0; i < 2; ++i) {
        u16x8 w = *(const u16x8*)&tb[cc][rs + 8 * i];
        *(u16x8*)(op + (size_t)cc * R + rs + 8 * i) = w;
    }
}

// ---------------------------------------------------------------------------
// Router
// ---------------------------------------------------------------------------
__global__ void router_kernel(const float* __restrict__ x,
                              const float* __restrict__ rw,
                              const float* __restrict__ rb,
                              const float* __restrict__ dgw,
                              const float* __restrict__ dgb,
                              int* __restrict__ e_arr,
                              float* __restrict__ s_arr,
                              int* __restrict__ counts) {
    int lane = threadIdx.x & 63;
    int wv = threadIdx.x >> 6;
    int t = blockIdx.x * 4 + wv;
    if (t >= T) return;

    float lg[E], dl[E];
#pragma unroll
    for (int e = 0; e < E; ++e) { lg[e] = 0.f; dl[e] = 0.f; }

    const float* xt = x + (size_t)t * D;
#pragma unroll
    for (int i = 0; i < D / 64; ++i) {
        int d = lane + 64 * i;
        float xv = xt[d];
#pragma unroll
        for (int e = 0; e < E; ++e) {
            lg[e] = fmaf(xv, rw[d * E + e], lg[e]);
            dl[e] = fmaf(xv, dgw[e * D + d], dl[e]);
        }
    }
#pragma unroll
    for (int e = 0; e < E; ++e) {
        for (int off = 32; off; off >>= 1) {
            lg[e] += __shfl_xor(lg[e], off);
            dl[e] += __shfl_xor(dl[e], off);
        }
    }
    if (lane == 0) {
        float p[E];
        float m = -1e30f;
#pragma unroll
        for (int e = 0; e < E; ++e) { lg[e] += rb[e]; m = fmaxf(m, lg[e]); }
        float s = 0.f;
#pragma unroll
        for (int e = 0; e < E; ++e) { p[e] = __expf(lg[e] - m); s += p[e]; }
        float inv = 1.0f / s;
#pragma unroll
        for (int e = 0; e < E; ++e) p[e] *= inv;

        int i0 = 0; float b0 = p[0];
#pragma unroll
        for (int e = 1; e < E; ++e) if (p[e] > b0) { b0 = p[e]; i0 = e; }
        int i1 = -1; float b1 = -1.0f;
#pragma unroll
        for (int e = 0; e < E; ++e) if (e != i0 && p[e] > b1) { b1 = p[e]; i1 = e; }

        float eb = __expf(b1 - b0);
        float w0 = 1.0f / (1.0f + eb);
        float w1 = eb / (1.0f + eb);

        float dg0 = 1.0f / (1.0f + __expf(-(dl[i0] + dgb[i0])));
        float dg1 = 1.0f / (1.0f + __expf(-(dl[i1] + dgb[i1])));

        e_arr[t * 2 + 0] = i0;
        e_arr[t * 2 + 1] = i1;
        s_arr[t * 2 + 0] = dg0 * w0;
        s_arr[t * 2 + 1] = dg1 * w1;
        atomicAdd(&counts[i0], 1);
        atomicAdd(&counts[i1], 1);
    }
}

// ---------------------------------------------------------------------------
// Scan — bases, cursor, expert_load, M-tile lists (128-row and 64-row)
// ---------------------------------------------------------------------------
__global__ void scan_kernel(const int* __restrict__ counts,
                            int* __restrict__ bases,
                            int* __restrict__ cursor,
                            float* __restrict__ load_out,
                            int* __restrict__ tme, int* __restrict__ tmm,
                            int* __restrict__ tml,
                            int* __restrict__ tme2, int* __restrict__ tmm2,
                            int* __restrict__ tml2) {
    if (threadIdx.x == 0 && blockIdx.x == 0) {
        int b = 0, nt = 0, nt2 = 0;
        for (int e = 0; e < E; ++e) {
            int c = counts[e];
            bases[e] = b;
            cursor[e] = b;
            load_out[e] = (float)c;
            for (int m = 0; m < c; m += 128) {
                tme[nt] = e;
                tmm[nt] = b + m;
                tml[nt] = (c - m < 128) ? (c - m) : 128;
                ++nt;
            }
            for (int m = 0; m < c; m += 64) {
                tme2[nt2] = e;
                tmm2[nt2] = b + m;
                tml2[nt2] = (c - m < 64) ? (c - m) : 64;
                ++nt2;
            }
            b += c;
        }
        bases[E] = b;
        for (; nt < MAXTILE; ++nt) tme[nt] = -1;
        for (; nt2 < MAXTILE2; ++nt2) tme2[nt2] = -1;
    }
}

__global__ void assign_kernel(const int* __restrict__ e_arr,
                              int* __restrict__ cursor,
                              int* __restrict__ a_tok,
                              int* __restrict__ pos_of) {
    int t = blockIdx.x * blockDim.x + threadIdx.x;
    if (t >= T) return;
#pragma unroll
    for (int s = 0; s < 2; ++s) {
        int e = e_arr[t * 2 + s];
        int pos = atomicAdd(&cursor[e], 1);
        a_tok[pos] = t;
        pos_of[t * 2 + s] = pos;
    }
}

// ---------------------------------------------------------------------------
// GEMM1: acts[pos][f] = silu(x@w1+b1)*silu(x@w3+b3), bf16.
// Tile 128(M) x 64(F), K=768, BK=64, gload_lds staging, XOR-swizzled LDS.
// ---------------------------------------------------------------------------
__global__ __launch_bounds__(256, 2)
void gemm1_kernel(const unsigned short* __restrict__ xb,
                  const unsigned short* __restrict__ w1t, const float* __restrict__ w1b,
                  const unsigned short* __restrict__ w3t, const float* __restrict__ w3b,
                  const int* __restrict__ a_tok,
                  const int* __restrict__ tme, const int* __restrict__ tmm,
                  const int* __restrict__ tml,
                  unsigned short* __restrict__ acts) {
    int mt = blockIdx.y;
    int e = tme[mt];
    if (e < 0) return;
    int mstart = tmm[mt], mlen = tml[mt];
    int fBase = blockIdx.x * 64;

    __shared__ char As[2][16384];
    __shared__ char Bs[2][16384];   // [0,8K)=w1 tile, [8K,16K)=w3 tile

    int tid = threadIdx.x;
    int lane = tid & 63, wv = tid >> 6;
    int wr = wv & 1, wc = wv >> 1;
    int l15 = lane & 15, lk = lane >> 4;
    int lrow = lane >> 3;
    int swl = (((lane & 7) ^ lrow) << 4);

    const char* xbp = (const char*)xb;
    size_t aoff[4];
#pragma unroll
    for (int i = 0; i < 4; ++i) {
        int r = (wv + 4 * i) * 8 + lrow;
        int rr = r < mlen ? r : mlen - 1;
        aoff[i] = (size_t)a_tok[mstart + rr] * (D * 2) + swl;
    }
    const char* w1p = (const char*)(w1t + (size_t)e * FF * D);
    const char* w3p = (const char*)(w3t + (size_t)e * FF * D);
    size_t boff[2];
#pragma unroll
    for (int i = 0; i < 2; ++i) {
        int f = (wv + 4 * i) * 8 + lrow;
        boff[i] = (size_t)(fBase + f) * (D * 2) + swl;
    }

    auto stage = [&](int buf, int k0) {
        int kb = k0 * 2;
        char* ab = &As[buf][0];
        char* bb = &Bs[buf][0];
#pragma unroll
        for (int i = 0; i < 4; ++i)
            gload16(xbp + aoff[i] + kb, ab + (wv + 4 * i) * 1024);
#pragma unroll
        for (int i = 0; i < 2; ++i) {
            gload16(w1p + boff[i] + kb, bb + (wv + 4 * i) * 1024);
            gload16(w3p + boff[i] + kb, bb + 8192 + (wv + 4 * i) * 1024);
        }
    };

    f32x4 hacc[4][2], gacc[4][2];
#pragma unroll
    for (int m = 0; m < 4; ++m)
#pragma unroll
        for (int n = 0; n < 2; ++n) {
            hacc[m][n] = f32x4{0.f, 0.f, 0.f, 0.f};
            gacc[m][n] = f32x4{0.f, 0.f, 0.f, 0.f};
        }

    stage(0, 0);
    __syncthreads();
    for (int ks = 0; ks < 12; ++ks) {
        int cur = ks & 1;
        if (ks < 11) stage(cur ^ 1, (ks + 1) * 64);
        const char* Ab = &As[cur][0];
        const char* Bb = &Bs[cur][0];
#pragma unroll
        for (int ksub = 0; ksub < 2; ++ksub) {
            int kb = ksub * 64 + lk * 16;
            bf16x8 af[4];
#pragma unroll
            for (int m = 0; m < 4; ++m) {
                int row = wr * 64 + m * 16 + l15;
                af[m] = *(const bf16x8*)(Ab + row * 128 + (kb ^ ((row & 7) << 4)));
            }
#pragma unroll
            for (int n = 0; n < 2; ++n) {
                int rowf = wc * 32 + n * 16 + l15;
                int off = rowf * 128 + (kb ^ ((rowf & 7) << 4));
                bf16x8 b1 = *(const bf16x8*)(Bb + off);
                bf16x8 b3 = *(const bf16x8*)(Bb + 8192 + off);
#pragma unroll
                for (int m = 0; m < 4; ++m) {
                    hacc[m][n] = __builtin_amdgcn_mfma_f32_16x16x32_bf16(af[m], b1, hacc[m][n], 0, 0, 0);
                    gacc[m][n] = __builtin_amdgcn_mfma_f32_16x16x32_bf16(af[m], b3, gacc[m][n], 0, 0, 0);
                }
            }
        }
        __syncthreads();
    }

    // epilogue: silu(h)*silu(g) -> bf16 tile in LDS -> vectorized store
    unsigned short* al = (unsigned short*)&As[0][0];
    float b1v[2], b3v[2];
#pragma unroll
    for (int n = 0; n < 2; ++n) {
        int f = fBase + wc * 32 + n * 16 + l15;
        b1v[n] = w1b[e * FF + f];
        b3v[n] = w3b[e * FF + f];
    }
#pragma unroll
    for (int m = 0; m < 4; ++m)
#pragma unroll
        for (int n = 0; n < 2; ++n)
#pragma unroll
            for (int j = 0; j < 4; ++j) {
                float h = hacc[m][n][j] + b1v[n];
                float g = gacc[m][n][j] + b3v[n];
                int row = wr * 64 + m * 16 + lk * 4 + j;
                int col = wc * 32 + n * 16 + l15;
                al[row * 64 + col] = f2bf(siluf(h) * siluf(g));
            }
    __syncthreads();
    int r = tid >> 1, cb = (tid & 1) * 32;
    if (r < mlen) {
        unsigned short* gp = acts + (size_t)(mstart + r) * FF + fBase + cb;
        const unsigned short* lp = al + r * 64 + cb;
#pragma unroll
        for (int i = 0; i < 4; ++i)
            *(u16x8*)(gp + i * 8) = *(const u16x8*)(lp + i * 8);
    }
}

// ---------------------------------------------------------------------------
// GEMM2: ffs_part[ksl][pos][d] = acts[pos][kslice] @ w2[kslice].
// Tile 64(M) x 128(N), split-K=2 (K=1536 each, 24 steps). 48KB LDS, 3/CU.
// ---------------------------------------------------------------------------
__global__ __launch_bounds__(256, 3)
void gemm2_kernel(const unsigned short* __restrict__ acts,
                  const unsigned short* __restrict__ w2t,
                  const int* __restrict__ tme2, const int* __restrict__ tmm2,
                  const int* __restrict__ tml2,
                  float* __restrict__ ffs) {
    int mt = blockIdx.y;
    int e = tme2[mt];
    if (e < 0) return;
    int mstart = tmm2[mt], mlen = tml2[mt];
    int nBase = blockIdx.x * 128;
    int ksl = blockIdx.z;

    __shared__ char As[2][8192];
    __shared__ char Bs[2][16384];

    int tid = threadIdx.x;
    int lane = tid & 63, wv = tid >> 6;
    int wr = wv & 1, wc = wv >> 1;
    int l15 = lane & 15, lk = lane >> 4;
    int lrow = lane >> 3;
    int swl = (((lane & 7) ^ lrow) << 4);

    const char* ap = (const char*)acts;
    const char* w2p = (const char*)(w2t + (size_t)e * (size_t)D * FF);
    size_t aoff[2], boff[4];
#pragma unroll
    for (int i = 0; i < 2; ++i) {
        int r = (wv + 4 * i) * 8 + lrow;
        aoff[i] = (size_t)(mstart + r) * (FF * 2) + swl;
    }
#pragma unroll
    for (int i = 0; i < 4; ++i) {
        int r = (wv + 4 * i) * 8 + lrow;
        boff[i] = (size_t)(nBase + r) * (FF * 2) + swl;
    }
    int kOff = ksl * (FF / 2) * 2;   // byte offset of this K slice

    auto stage = [&](int buf, int k0) {
        int kb = kOff + k0 * 2;
        char* ab = &As[buf][0];
        char* bb = &Bs[buf][0];
#pragma unroll
        for (int i = 0; i < 2; ++i)
            gload16(ap + aoff[i] + kb, ab + (wv + 4 * i) * 1024);
#pragma unroll
        for (int i = 0; i < 4; ++i)
            gload16(w2p + boff[i] + kb, bb + (wv + 4 * i) * 1024);
    };

    f32x4 facc[2][4];
#pragma unroll
    for (int m = 0; m < 2; ++m)
#pragma unroll
        for (int n = 0; n < 4; ++n) facc[m][n] = f32x4{0.f, 0.f, 0.f, 0.f};

    stage(0, 0);
    __syncthreads();
    for (int ks = 0; ks < 24; ++ks) {
        int cur = ks & 1;
        if (ks < 23) stage(cur ^ 1, (ks + 1) * 64);
        const char* Ab = &As[cur][0];
        const char* Bb = &Bs[cur][0];
#pragma unroll
        for (int ksub = 0; ksub < 2; ++ksub) {
            int kb = ksub * 64 + lk * 16;
            bf16x8 af[2], bf[4];
#pragma unroll
            for (int m = 0; m < 2; ++m) {
                int row = wr * 32 + m * 16 + l15;
                af[m] = *(const bf16x8*)(Ab + row * 128 + (kb ^ ((row & 7) << 4)));
            }
#pragma unroll
            for (int n = 0; n < 4; ++n) {
                int row = wc * 64 + n * 16 + l15;
                bf[n] = *(const bf16x8*)(Bb + row * 128 + (kb ^ ((row & 7) << 4)));
            }
#pragma unroll
            for (int m = 0; m < 2; ++m)
#pragma unroll
                for (int n = 0; n < 4; ++n)
                    facc[m][n] = __builtin_amdgcn_mfma_f32_16x16x32_bf16(af[m], bf[n], facc[m][n], 0, 0, 0);
        }
        __syncthreads();
    }

    float* op = ffs + (size_t)ksl * PSTRIDE;
#pragma unroll
    for (int m = 0; m < 2; ++m)
#pragma unroll
        for (int j = 0; j < 4; ++j) {
            int row = wr * 32 + m * 16 + lk * 4 + j;
            if (row < mlen) {
                float* gp = op + (size_t)(mstart + row) * D + nBase + wc * 64;
#pragma unroll
                for (int n = 0; n < 4; ++n)
                    gp[n * 16 + l15] = facc[m][n][j];
            }
        }
}

// ---------------------------------------------------------------------------
// Combine — f = part0 + part1 + w2b; y = x + s*f per slot; dual LN; sum; out
// ---------------------------------------------------------------------------
__global__ __launch_bounds__(256)
void combine_kernel(const float* __restrict__ x,
                    const float* __restrict__ ffs,
                    const int* __restrict__ e_arr,
                    const int* __restrict__ pos_of,
                    const float* __restrict__ s_arr,
                    const float* __restrict__ w2b,
                    const float* __restrict__ lng,
                    const float* __restrict__ lnb,
                    float* __restrict__ out) {
    int t = blockIdx.x;
    int tid = threadIdx.x;
    int p0 = pos_of[t * 2], p1 = pos_of[t * 2 + 1];
    int e0 = e_arr[t * 2], e1 = e_arr[t * 2 + 1];
    float sw0 = s_arr[t * 2], sw1 = s_arr[t * 2 + 1];
    __shared__ float red[4][4];

    float y0[3], y1[3];
    float s0 = 0.f, q0 = 0.f, s1 = 0.f, q1 = 0.f;
#pragma unroll
    for (int m = 0; m < 3; ++m) {
        int d = tid + 256 * m;
        float xv = x[(size_t)t * D + d];
        float f0 = ffs[(size_t)p0 * D + d] + ffs[PSTRIDE + (size_t)p0 * D + d] + w2b[e0 * D + d];
        float f1 = ffs[(size_t)p1 * D + d] + ffs[PSTRIDE + (size_t)p1 * D + d] + w2b[e1 * D + d];
        float a = xv + sw0 * f0;
        float bb = xv + sw1 * f1;
        y0[m] = a; y1[m] = bb;
        s0 += a; q0 += a * a;
        s1 += bb; q1 += bb * bb;
    }
    for (int off = 32; off; off >>= 1) {
        s0 += __shfl_xor(s0, off);
        q0 += __shfl_xor(q0, off);
        s1 += __shfl_xor(s1, off);
        q1 += __shfl_xor(q1, off);
    }
    int wv = tid >> 6, lane = tid & 63;
    if (lane == 0) { red[wv][0] = s0; red[wv][1] = q0; red[wv][2] = s1; red[wv][3] = q1; }
    __syncthreads();
    s0 = red[0][0] + red[1][0] + red[2][0] + red[3][0];
    q0 = red[0][1] + red[1][1] + red[2][1] + red[3][1];
    s1 = red[0][2] + red[1][2] + red[2][2] + red[3][2];
    q1 = red[0][3] + red[1][3] + red[2][3] + red[3][3];

    const float invD = 1.0f / (float)D;
    float mu0 = s0 * invD, var0 = q0 * invD - mu0 * mu0;
    float mu1 = s1 * invD, var1 = q1 * invD - mu1 * mu1;
    float r0 = rsqrtf(var0 + 1e-5f);
    float r1 = rsqrtf(var1 + 1e-5f);

#pragma unroll
    for (int m = 0; m < 3; ++m) {
        int d = tid + 256 * m;
        out[(size_t)t * D + d] =
            (y0[m] - mu0) * r0 * lng[e0 * D + d] + lnb[e0 * D + d] +
            (y1[m] - mu1) * r1 * lng[e1 * D + d] + lnb[e1 * D + d];
    }
}

// ---------------------------------------------------------------------------
extern "C" void kernel_launch(void* const* d_in, const int* in_sizes, int n_in,
                              void* d_out, int out_size, void* d_ws, size_t ws_size,
                              hipStream_t stream) {
    const float* x   = (const float*)d_in[0];
    const float* rw  = (const float*)d_in[1];
    const float* rb  = (const float*)d_in[2];
    const float* dgw = (const float*)d_in[3];
    const float* dgb = (const float*)d_in[4];
    const float* w1  = (const float*)d_in[5];
    const float* w1b = (const float*)d_in[6];
    const float* w2  = (const float*)d_in[7];
    const float* w2b = (const float*)d_in[8];
    const float* w3  = (const float*)d_in[9];
    const float* w3b = (const float*)d_in[10];
    const float* lng = (const float*)d_in[11];
    const float* lnb = (const float*)d_in[12];

    float* out = (float*)d_out;
    float* load_out = out + (size_t)T * D;

    char* w = (char*)d_ws;
    size_t off = 0;
    auto alloc = [&](size_t bytes) -> void* {
        void* p = w + off;
        off = (off + bytes + 255) & ~(size_t)255;
        return p;
    };
    int* counts   = (int*)alloc(8 * sizeof(int));
    int* bases    = (int*)alloc(9 * sizeof(int));
    int* cursor   = (int*)alloc(8 * sizeof(int));
    int* e_arr    = (int*)alloc(NPOS * sizeof(int));
    int* a_tok    = (int*)alloc(NPOS * sizeof(int));
    int* pos_of   = (int*)alloc(NPOS * sizeof(int));
    float* s_arr  = (float*)alloc(NPOS * sizeof(float));
    int* tme      = (int*)alloc(MAXTILE * sizeof(int));
    int* tmm      = (int*)alloc(MAXTILE * sizeof(int));
    int* tml      = (int*)alloc(MAXTILE * sizeof(int));
    int* tme2     = (int*)alloc(MAXTILE2 * sizeof(int));
    int* tmm2     = (int*)alloc(MAXTILE2 * sizeof(int));
    int* tml2     = (int*)alloc(MAXTILE2 * sizeof(int));
    unsigned short* xb  = (unsigned short*)alloc((size_t)T * D * 2);
    unsigned short* w1t = (unsigned short*)alloc((size_t)E * D * FF * 2);
    unsigned short* w3t = (unsigned short*)alloc((size_t)E * D * FF * 2);
    unsigned short* w2t = (unsigned short*)alloc((size_t)E * D * FF * 2);
    unsigned short* acts = (unsigned short*)alloc((size_t)(NPOS + 128) * FF * 2);
    float* ffs    = (float*)alloc(2 * PSTRIDE * sizeof(float));

    hipMemsetAsync(counts, 0, 8 * sizeof(int), stream);
    convert_x_kernel<<<(T * D / 8) / 256, 256, 0, stream>>>(x, xb);
    // w1 and w3 share shape [E][D][FF] -> fused launch, z in [0,16)
    {
        dim3 g13(FF / 64, D / 64, 2 * E);
        // contiguous trick: w1 blocks z<8 read w1, z>=8 read w3 via pointer math
        // (launch two grids to keep pointers simple and deterministic)
        transpose_convert<<<dim3(FF / 64, D / 64, E), 256, 0, stream>>>(w1, w1t, D, FF);
        transpose_convert<<<dim3(FF / 64, D / 64, E), 256, 0, stream>>>(w3, w3t, D, FF);
    }
    transpose_convert<<<dim3(D / 64, FF / 64, E), 256, 0, stream>>>(w2, w2t, FF, D);
    router_kernel<<<T / 4, 256, 0, stream>>>(x, rw, rb, dgw, dgb, e_arr, s_arr, counts);
    scan_kernel<<<1, 64, 0, stream>>>(counts, bases, cursor, load_out,
                                      tme, tmm, tml, tme2, tmm2, tml2);
    assign_kernel<<<(T + 255) / 256, 256, 0, stream>>>(e_arr, cursor, a_tok, pos_of);
    gemm1_kernel<<<dim3(FF / 64, MAXTILE), 256, 0, stream>>>(
        xb, w1t, w1b, w3t, w3b, a_tok, tme, tmm, tml, acts);
    gemm2_kernel<<<dim3(D / 128, MAXTILE2, 2), 256, 0, stream>>>(
        acts, w2t, tme2, tmm2, tml2, ffs);
    combine_kernel<<<T, 256, 0, stream>>>(x, ffs, e_arr, pos_of, s_arr, w2b, lng, lnb, out);
}

// Round 6
// 288.641 us; speedup vs baseline: 1.0352x; 1.0352x over previous
//
#include <hip/hip_runtime.h>
#include <math.h>

#define T 2048
#define D 768
#define E 8
#define FF 3072
#define NPOS (2 * T)
#define MAXTILE 40
#define MAXTILE2 72
#define PSTRIDE ((size_t)(NPOS + 64) * D)

using bf16x8 = __attribute__((ext_vector_type(8))) short;
using f32x4  = __attribute__((ext_vector_type(4))) float;
using u16x8  = __attribute__((ext_vector_type(8))) unsigned short;

__device__ __forceinline__ unsigned short f2bf(float f) {
    union { float f; unsigned u; } v; v.f = f;
    unsigned r = v.u + 0x7FFF + ((v.u >> 16) & 1);
    return (unsigned short)(r >> 16);
}
__device__ __forceinline__ float bf2f(unsigned short u) {
    union { unsigned u; float f; } v; v.u = ((unsigned)u) << 16;
    return v.f;
}
__device__ __forceinline__ float siluf(float v) {
    return v / (1.0f + __expf(-v));
}
__device__ __forceinline__ void gload16(const void* g, void* l) {
    __builtin_amdgcn_global_load_lds(
        (const __attribute__((address_space(1))) void*)g,
        (__attribute__((address_space(3))) void*)l, 16, 0, 0);
}

// ---------------------------------------------------------------------------
// Fused transpose+convert for all 3 weights: f32 [8][R][C] -> bf16 [8][C][R].
// zi<8: w1 (R=D,C=FF); zi<16: w3; zi>=16: w2 (R=FF,C=D, bx/by swapped).
// Phase 1: per thread 4 consecutive rows x 4 cols -> pack per column ->
// 4x ds_write_b64 (was 16x ds_write_b16).
// ---------------------------------------------------------------------------
__global__ __launch_bounds__(256)
void transpose_all(const float* __restrict__ w1, const float* __restrict__ w3,
                   const float* __restrict__ w2,
                   unsigned short* __restrict__ w1t, unsigned short* __restrict__ w3t,
                   unsigned short* __restrict__ w2t) {
    __shared__ unsigned short tb[64][72];   // [c][r], 144B row stride, 16B aligned
    int zi = blockIdx.z;
    const float* in; unsigned short* out; int R, C, r0, c0;
    if (zi < 16) {
        R = D; C = FF;
        int z = zi & 7;
        if (zi < 8) { in = w1 + (size_t)z * R * C; out = w1t + (size_t)z * R * C; }
        else        { in = w3 + (size_t)z * R * C; out = w3t + (size_t)z * R * C; }
        c0 = blockIdx.x * 64;   // 48 tiles over FF
        r0 = blockIdx.y * 64;   // 12 tiles over D
    } else {
        R = FF; C = D;
        int z = zi - 16;
        in = w2 + (size_t)z * R * C; out = w2t + (size_t)z * R * C;
        r0 = blockIdx.x * 64;   // 48 tiles over FF
        c0 = blockIdx.y * 64;   // 12 tiles over D
    }
    int tid = threadIdx.x;
    int ccL = tid & 3;
    int rl  = (tid >> 2) & 15;
    int ccH = tid >> 6;
    int c = (ccH * 4 + ccL) * 4;
    int rb = rl * 4;

    const float* ip = in + (size_t)(r0 + rb) * C + c0 + c;
    float4 v0 = *(const float4*)(ip);
    float4 v1 = *(const float4*)(ip + C);
    float4 v2 = *(const float4*)(ip + 2 * C);
    float4 v3 = *(const float4*)(ip + 3 * C);
    ushort4 p;
    p = make_ushort4(f2bf(v0.x), f2bf(v1.x), f2bf(v2.x), f2bf(v3.x));
    *(ushort4*)&tb[c + 0][rb] = p;
    p = make_ushort4(f2bf(v0.y), f2bf(v1.y), f2bf(v2.y), f2bf(v3.y));
    *(ushort4*)&tb[c + 1][rb] = p;
    p = make_ushort4(f2bf(v0.z), f2bf(v1.z), f2bf(v2.z), f2bf(v3.z));
    *(ushort4*)&tb[c + 2][rb] = p;
    p = make_ushort4(f2bf(v0.w), f2bf(v1.w), f2bf(v2.w), f2bf(v3.w));
    *(ushort4*)&tb[c + 3][rb] = p;

    __syncthreads();
    unsigned short* op = out + (size_t)c0 * R + r0;
    int cc = tid >> 2;
    int rs = (tid & 3) * 16;
#pragma unroll
    for (int i = 0; i < 2; ++i) {
        u16x8 w = *(const u16x8*)&tb[cc][rs + 8 * i];
        *(u16x8*)(op + (size_t)cc * R + rs + 8 * i) = w;
    }
}

// ---------------------------------------------------------------------------
// Router (+ fused x -> bf16 conversion)
// ---------------------------------------------------------------------------
__global__ void router_kernel(const float* __restrict__ x,
                              const float* __restrict__ rw,
                              const float* __restrict__ rb,
                              const float* __restrict__ dgw,
                              const float* __restrict__ dgb,
                              unsigned short* __restrict__ xb,
                              int* __restrict__ e_arr,
                              float* __restrict__ s_arr,
                              int* __restrict__ counts) {
    int lane = threadIdx.x & 63;
    int wv = threadIdx.x >> 6;
    int t = blockIdx.x * 4 + wv;
    if (t >= T) return;

    float lg[E], dl[E];
#pragma unroll
    for (int e = 0; e < E; ++e) { lg[e] = 0.f; dl[e] = 0.f; }

    const float* xt = x + (size_t)t * D;
    unsigned short* xbt = xb + (size_t)t * D;
#pragma unroll
    for (int i = 0; i < D / 64; ++i) {
        int d = lane + 64 * i;
        float xv = xt[d];
        xbt[d] = f2bf(xv);
#pragma unroll
        for (int e = 0; e < E; ++e) {
            lg[e] = fmaf(xv, rw[d * E + e], lg[e]);
            dl[e] = fmaf(xv, dgw[e * D + d], dl[e]);
        }
    }
#pragma unroll
    for (int e = 0; e < E; ++e) {
        for (int off = 32; off; off >>= 1) {
            lg[e] += __shfl_xor(lg[e], off);
            dl[e] += __shfl_xor(dl[e], off);
        }
    }
    if (lane == 0) {
        float p[E];
        float m = -1e30f;
#pragma unroll
        for (int e = 0; e < E; ++e) { lg[e] += rb[e]; m = fmaxf(m, lg[e]); }
        float s = 0.f;
#pragma unroll
        for (int e = 0; e < E; ++e) { p[e] = __expf(lg[e] - m); s += p[e]; }
        float inv = 1.0f / s;
#pragma unroll
        for (int e = 0; e < E; ++e) p[e] *= inv;

        int i0 = 0; float b0 = p[0];
#pragma unroll
        for (int e = 1; e < E; ++e) if (p[e] > b0) { b0 = p[e]; i0 = e; }
        int i1 = -1; float b1 = -1.0f;
#pragma unroll
        for (int e = 0; e < E; ++e) if (e != i0 && p[e] > b1) { b1 = p[e]; i1 = e; }

        float eb = __expf(b1 - b0);
        float w0 = 1.0f / (1.0f + eb);
        float w1 = eb / (1.0f + eb);

        float dg0 = 1.0f / (1.0f + __expf(-(dl[i0] + dgb[i0])));
        float dg1 = 1.0f / (1.0f + __expf(-(dl[i1] + dgb[i1])));

        e_arr[t * 2 + 0] = i0;
        e_arr[t * 2 + 1] = i1;
        s_arr[t * 2 + 0] = dg0 * w0;
        s_arr[t * 2 + 1] = dg1 * w1;
        atomicAdd(&counts[i0], 1);
        atomicAdd(&counts[i1], 1);
    }
}

// ---------------------------------------------------------------------------
// Scan — bases, cursor, expert_load, M-tile lists (128-row and 64-row)
// ---------------------------------------------------------------------------
__global__ void scan_kernel(const int* __restrict__ counts,
                            int* __restrict__ bases,
                            int* __restrict__ cursor,
                            float* __restrict__ load_out,
                            int* __restrict__ tme, int* __restrict__ tmm,
                            int* __restrict__ tml,
                            int* __restrict__ tme2, int* __restrict__ tmm2,
                            int* __restrict__ tml2) {
    if (threadIdx.x == 0 && blockIdx.x == 0) {
        int b = 0, nt = 0, nt2 = 0;
        for (int e = 0; e < E; ++e) {
            int c = counts[e];
            bases[e] = b;
            cursor[e] = b;
            load_out[e] = (float)c;
            for (int m = 0; m < c; m += 128) {
                tme[nt] = e;
                tmm[nt] = b + m;
                tml[nt] = (c - m < 128) ? (c - m) : 128;
                ++nt;
            }
            for (int m = 0; m < c; m += 64) {
                tme2[nt2] = e;
                tmm2[nt2] = b + m;
                tml2[nt2] = (c - m < 64) ? (c - m) : 64;
                ++nt2;
            }
            b += c;
        }
        bases[E] = b;
        for (; nt < MAXTILE; ++nt) tme[nt] = -1;
        for (; nt2 < MAXTILE2; ++nt2) tme2[nt2] = -1;
    }
}

__global__ void assign_kernel(const int* __restrict__ e_arr,
                              int* __restrict__ cursor,
                              int* __restrict__ a_tok,
                              int* __restrict__ pos_of) {
    int t = blockIdx.x * blockDim.x + threadIdx.x;
    if (t >= T) return;
#pragma unroll
    for (int s = 0; s < 2; ++s) {
        int e = e_arr[t * 2 + s];
        int pos = atomicAdd(&cursor[e], 1);
        a_tok[pos] = t;
        pos_of[t * 2 + s] = pos;
    }
}

// ---------------------------------------------------------------------------
// GEMM1: acts[pos][f] = silu(x@w1+b1)*silu(x@w3+b3), bf16.
// Tile 128(M) x 64(F), K=768, BK=64. Counted-vmcnt pipeline: raw s_barrier,
// vmcnt(8) (never 0 in steady state), stage after reuse-barrier. T5 setprio.
// ---------------------------------------------------------------------------
__global__ __launch_bounds__(256, 2)
void gemm1_kernel(const unsigned short* __restrict__ xb,
                  const unsigned short* __restrict__ w1t, const float* __restrict__ w1b,
                  const unsigned short* __restrict__ w3t, const float* __restrict__ w3b,
                  const int* __restrict__ a_tok,
                  const int* __restrict__ tme, const int* __restrict__ tmm,
                  const int* __restrict__ tml,
                  unsigned short* __restrict__ acts) {
    int mt = blockIdx.y;
    int e = tme[mt];
    if (e < 0) return;
    int mstart = tmm[mt], mlen = tml[mt];
    int fBase = blockIdx.x * 64;

    __shared__ char As[2][16384];
    __shared__ char Bs[2][16384];   // [0,8K)=w1 tile, [8K,16K)=w3 tile

    int tid = threadIdx.x;
    int lane = tid & 63, wv = tid >> 6;
    int wr = wv & 1, wc = wv >> 1;
    int l15 = lane & 15, lk = lane >> 4;
    int lrow = lane >> 3;
    int swl = (((lane & 7) ^ lrow) << 4);

    const char* xbp = (const char*)xb;
    size_t aoff[4];
#pragma unroll
    for (int i = 0; i < 4; ++i) {
        int r = (wv + 4 * i) * 8 + lrow;
        int rr = r < mlen ? r : mlen - 1;
        aoff[i] = (size_t)a_tok[mstart + rr] * (D * 2) + swl;
    }
    const char* w1p = (const char*)(w1t + (size_t)e * FF * D);
    const char* w3p = (const char*)(w3t + (size_t)e * FF * D);
    size_t boff[2];
#pragma unroll
    for (int i = 0; i < 2; ++i) {
        int f = (wv + 4 * i) * 8 + lrow;
        boff[i] = (size_t)(fBase + f) * (D * 2) + swl;
    }

    auto stage = [&](int buf, int k0) {
        int kb = k0 * 2;
        char* ab = &As[buf][0];
        char* bb = &Bs[buf][0];
#pragma unroll
        for (int i = 0; i < 4; ++i)
            gload16(xbp + aoff[i] + kb, ab + (wv + 4 * i) * 1024);
#pragma unroll
        for (int i = 0; i < 2; ++i) {
            gload16(w1p + boff[i] + kb, bb + (wv + 4 * i) * 1024);
            gload16(w3p + boff[i] + kb, bb + 8192 + (wv + 4 * i) * 1024);
        }
    };

    f32x4 hacc[4][2], gacc[4][2];
#pragma unroll
    for (int m = 0; m < 4; ++m)
#pragma unroll
        for (int n = 0; n < 2; ++n) {
            hacc[m][n] = f32x4{0.f, 0.f, 0.f, 0.f};
            gacc[m][n] = f32x4{0.f, 0.f, 0.f, 0.f};
        }

    stage(0, 0);
    stage(1, 64);
#pragma unroll 1
    for (int ks = 0; ks < 12; ++ks) {
        int cur = ks & 1;
        // wait for buf[cur]'s 8 loads (oldest); keep the younger 8 in flight
        if (ks < 11) asm volatile("s_waitcnt vmcnt(8)" ::: "memory");
        else         asm volatile("s_waitcnt vmcnt(0)" ::: "memory");
        __builtin_amdgcn_s_barrier();
        const char* Ab = &As[cur][0];
        const char* Bb = &Bs[cur][0];
        __builtin_amdgcn_s_setprio(1);
#pragma unroll
        for (int ksub = 0; ksub < 2; ++ksub) {
            int kb = ksub * 64 + lk * 16;
            bf16x8 af[4];
#pragma unroll
            for (int m = 0; m < 4; ++m) {
                int row = wr * 64 + m * 16 + l15;
                af[m] = *(const bf16x8*)(Ab + row * 128 + (kb ^ ((row & 7) << 4)));
            }
#pragma unroll
            for (int n = 0; n < 2; ++n) {
                int rowf = wc * 32 + n * 16 + l15;
                int off = rowf * 128 + (kb ^ ((rowf & 7) << 4));
                bf16x8 b1 = *(const bf16x8*)(Bb + off);
                bf16x8 b3 = *(const bf16x8*)(Bb + 8192 + off);
#pragma unroll
                for (int m = 0; m < 4; ++m) {
                    hacc[m][n] = __builtin_amdgcn_mfma_f32_16x16x32_bf16(af[m], b1, hacc[m][n], 0, 0, 0);
                    gacc[m][n] = __builtin_amdgcn_mfma_f32_16x16x32_bf16(af[m], b3, gacc[m][n], 0, 0, 0);
                }
            }
        }
        __builtin_amdgcn_s_setprio(0);
        __builtin_amdgcn_s_barrier();           // all waves done reading buf[cur]
        if (ks < 10) stage(cur, (ks + 2) * 64); // refill for iteration ks+2
    }

    // epilogue: silu(h)*silu(g) -> bf16 tile in LDS -> vectorized store
    unsigned short* al = (unsigned short*)&As[0][0];
    float b1v[2], b3v[2];
#pragma unroll
    for (int n = 0; n < 2; ++n) {
        int f = fBase + wc * 32 + n * 16 + l15;
        b1v[n] = w1b[e * FF + f];
        b3v[n] = w3b[e * FF + f];
    }
#pragma unroll
    for (int m = 0; m < 4; ++m)
#pragma unroll
        for (int n = 0; n < 2; ++n)
#pragma unroll
            for (int j = 0; j < 4; ++j) {
                float h = hacc[m][n][j] + b1v[n];
                float g = gacc[m][n][j] + b3v[n];
                int row = wr * 64 + m * 16 + lk * 4 + j;
                int col = wc * 32 + n * 16 + l15;
                al[row * 64 + col] = f2bf(siluf(h) * siluf(g));
            }
    __syncthreads();
    int r = tid >> 1, cb = (tid & 1) * 32;
    if (r < mlen) {
        unsigned short* gp = acts + (size_t)(mstart + r) * FF + fBase + cb;
        const unsigned short* lp = al + r * 64 + cb;
#pragma unroll
        for (int i = 0; i < 4; ++i)
            *(u16x8*)(gp + i * 8) = *(const u16x8*)(lp + i * 8);
    }
}

// ---------------------------------------------------------------------------
// GEMM2: ffs_part[ksl][pos][d] = acts[pos][kslice] @ w2[kslice].
// Tile 64(M) x 128(N), split-K=2. Counted-vmcnt pipeline (vmcnt(6)).
// ---------------------------------------------------------------------------
__global__ __launch_bounds__(256, 3)
void gemm2_kernel(const unsigned short* __restrict__ acts,
                  const unsigned short* __restrict__ w2t,
                  const int* __restrict__ tme2, const int* __restrict__ tmm2,
                  const int* __restrict__ tml2,
                  float* __restrict__ ffs) {
    int mt = blockIdx.y;
    int e = tme2[mt];
    if (e < 0) return;
    int mstart = tmm2[mt], mlen = tml2[mt];
    int nBase = blockIdx.x * 128;
    int ksl = blockIdx.z;

    __shared__ char As[2][8192];
    __shared__ char Bs[2][16384];

    int tid = threadIdx.x;
    int lane = tid & 63, wv = tid >> 6;
    int wr = wv & 1, wc = wv >> 1;
    int l15 = lane & 15, lk = lane >> 4;
    int lrow = lane >> 3;
    int swl = (((lane & 7) ^ lrow) << 4);

    const char* ap = (const char*)acts;
    const char* w2p = (const char*)(w2t + (size_t)e * (size_t)D * FF);
    size_t aoff[2], boff[4];
#pragma unroll
    for (int i = 0; i < 2; ++i) {
        int r = (wv + 4 * i) * 8 + lrow;
        aoff[i] = (size_t)(mstart + r) * (FF * 2) + swl;
    }
#pragma unroll
    for (int i = 0; i < 4; ++i) {
        int r = (wv + 4 * i) * 8 + lrow;
        boff[i] = (size_t)(nBase + r) * (FF * 2) + swl;
    }
    int kOff = ksl * (FF / 2) * 2;   // byte offset of this K slice

    auto stage = [&](int buf, int k0) {
        int kb = kOff + k0 * 2;
        char* ab = &As[buf][0];
        char* bb = &Bs[buf][0];
#pragma unroll
        for (int i = 0; i < 2; ++i)
            gload16(ap + aoff[i] + kb, ab + (wv + 4 * i) * 1024);
#pragma unroll
        for (int i = 0; i < 4; ++i)
            gload16(w2p + boff[i] + kb, bb + (wv + 4 * i) * 1024);
    };

    f32x4 facc[2][4];
#pragma unroll
    for (int m = 0; m < 2; ++m)
#pragma unroll
        for (int n = 0; n < 4; ++n) facc[m][n] = f32x4{0.f, 0.f, 0.f, 0.f};

    stage(0, 0);
    stage(1, 64);
#pragma unroll 1
    for (int ks = 0; ks < 24; ++ks) {
        int cur = ks & 1;
        if (ks < 23) asm volatile("s_waitcnt vmcnt(6)" ::: "memory");
        else         asm volatile("s_waitcnt vmcnt(0)" ::: "memory");
        __builtin_amdgcn_s_barrier();
        const char* Ab = &As[cur][0];
        const char* Bb = &Bs[cur][0];
        __builtin_amdgcn_s_setprio(1);
#pragma unroll
        for (int ksub = 0; ksub < 2; ++ksub) {
            int kb = ksub * 64 + lk * 16;
            bf16x8 af[2], bf[4];
#pragma unroll
            for (int m = 0; m < 2; ++m) {
                int row = wr * 32 + m * 16 + l15;
                af[m] = *(const bf16x8*)(Ab + row * 128 + (kb ^ ((row & 7) << 4)));
            }
#pragma unroll
            for (int n = 0; n < 4; ++n) {
                int row = wc * 64 + n * 16 + l15;
                bf[n] = *(const bf16x8*)(Bb + row * 128 + (kb ^ ((row & 7) << 4)));
            }
#pragma unroll
            for (int m = 0; m < 2; ++m)
#pragma unroll
                for (int n = 0; n < 4; ++n)
                    facc[m][n] = __builtin_amdgcn_mfma_f32_16x16x32_bf16(af[m], bf[n], facc[m][n], 0, 0, 0);
        }
        __builtin_amdgcn_s_setprio(0);
        __builtin_amdgcn_s_barrier();
        if (ks < 22) stage(cur, (ks + 2) * 64);
    }

    float* op = ffs + (size_t)ksl * PSTRIDE;
#pragma unroll
    for (int m = 0; m < 2; ++m)
#pragma unroll
        for (int j = 0; j < 4; ++j) {
            int row = wr * 32 + m * 16 + lk * 4 + j;
            if (row < mlen) {
                float* gp = op + (size_t)(mstart + row) * D + nBase + wc * 64;
#pragma unroll
                for (int n = 0; n < 4; ++n)
                    gp[n * 16 + l15] = facc[m][n][j];
            }
        }
}

// ---------------------------------------------------------------------------
// Combine — f = part0 + part1 + w2b; y = x + s*f per slot; dual LN; sum; out
// ---------------------------------------------------------------------------
__global__ __launch_bounds__(256)
void combine_kernel(const float* __restrict__ x,
                    const float* __restrict__ ffs,
                    const int* __restrict__ e_arr,
                    const int* __restrict__ pos_of,
                    const float* __restrict__ s_arr,
                    const float* __restrict__ w2b,
                    const float* __restrict__ lng,
                    const float* __restrict__ lnb,
                    float* __restrict__ out) {
    int t = blockIdx.x;
    int tid = threadIdx.x;
    int p0 = pos_of[t * 2], p1 = pos_of[t * 2 + 1];
    int e0 = e_arr[t * 2], e1 = e_arr[t * 2 + 1];
    float sw0 = s_arr[t * 2], sw1 = s_arr[t * 2 + 1];
    __shared__ float red[4][4];

    float y0[3], y1[3];
    float s0 = 0.f, q0 = 0.f, s1 = 0.f, q1 = 0.f;
#pragma unroll
    for (int m = 0; m < 3; ++m) {
        int d = tid + 256 * m;
        float xv = x[(size_t)t * D + d];
        float f0 = ffs[(size_t)p0 * D + d] + ffs[PSTRIDE + (size_t)p0 * D + d] + w2b[e0 * D + d];
        float f1 = ffs[(size_t)p1 * D + d] + ffs[PSTRIDE + (size_t)p1 * D + d] + w2b[e1 * D + d];
        float a = xv + sw0 * f0;
        float bb = xv + sw1 * f1;
        y0[m] = a; y1[m] = bb;
        s0 += a; q0 += a * a;
        s1 += bb; q1 += bb * bb;
    }
    for (int off = 32; off; off >>= 1) {
        s0 += __shfl_xor(s0, off);
        q0 += __shfl_xor(q0, off);
        s1 += __shfl_xor(s1, off);
        q1 += __shfl_xor(q1, off);
    }
    int wv = tid >> 6, lane = tid & 63;
    if (lane == 0) { red[wv][0] = s0; red[wv][1] = q0; red[wv][2] = s1; red[wv][3] = q1; }
    __syncthreads();
    s0 = red[0][0] + red[1][0] + red[2][0] + red[3][0];
    q0 = red[0][1] + red[1][1] + red[2][1] + red[3][1];
    s1 = red[0][2] + red[1][2] + red[2][2] + red[3][2];
    q1 = red[0][3] + red[1][3] + red[2][3] + red[3][3];

    const float invD = 1.0f / (float)D;
    float mu0 = s0 * invD, var0 = q0 * invD - mu0 * mu0;
    float mu1 = s1 * invD, var1 = q1 * invD - mu1 * mu1;
    float r0 = rsqrtf(var0 + 1e-5f);
    float r1 = rsqrtf(var1 + 1e-5f);

#pragma unroll
    for (int m = 0; m < 3; ++m) {
        int d = tid + 256 * m;
        out[(size_t)t * D + d] =
            (y0[m] - mu0) * r0 * lng[e0 * D + d] + lnb[e0 * D + d] +
            (y1[m] - mu1) * r1 * lng[e1 * D + d] + lnb[e1 * D + d];
    }
}

// ---------------------------------------------------------------------------
extern "C" void kernel_launch(void* const* d_in, const int* in_sizes, int n_in,
                              void* d_out, int out_size, void* d_ws, size_t ws_size,
                              hipStream_t stream) {
    const float* x   = (const float*)d_in[0];
    const float* rw  = (const float*)d_in[1];
    const float* rb  = (const float*)d_in[2];
    const float* dgw = (const float*)d_in[3];
    const float* dgb = (const float*)d_in[4];
    const float* w1  = (const float*)d_in[5];
    const float* w1b = (const float*)d_in[6];
    const float* w2  = (const float*)d_in[7];
    const float* w2b = (const float*)d_in[8];
    const float* w3  = (const float*)d_in[9];
    const float* w3b = (const float*)d_in[10];
    const float* lng = (const float*)d_in[11];
    const float* lnb = (const float*)d_in[12];

    float* out = (float*)d_out;
    float* load_out = out + (size_t)T * D;

    char* w = (char*)d_ws;
    size_t off = 0;
    auto alloc = [&](size_t bytes) -> void* {
        void* p = w + off;
        off = (off + bytes + 255) & ~(size_t)255;
        return p;
    };
    int* counts   = (int*)alloc(8 * sizeof(int));
    int* bases    = (int*)alloc(9 * sizeof(int));
    int* cursor   = (int*)alloc(8 * sizeof(int));
    int* e_arr    = (int*)alloc(NPOS * sizeof(int));
    int* a_tok    = (int*)alloc(NPOS * sizeof(int));
    int* pos_of   = (int*)alloc(NPOS * sizeof(int));
    float* s_arr  = (float*)alloc(NPOS * sizeof(float));
    int* tme      = (int*)alloc(MAXTILE * sizeof(int));
    int* tmm      = (int*)alloc(MAXTILE * sizeof(int));
    int* tml      = (int*)alloc(MAXTILE * sizeof(int));
    int* tme2     = (int*)alloc(MAXTILE2 * sizeof(int));
    int* tmm2     = (int*)alloc(MAXTILE2 * sizeof(int));
    int* tml2     = (int*)alloc(MAXTILE2 * sizeof(int));
    unsigned short* xb  = (unsigned short*)alloc((size_t)T * D * 2);
    unsigned short* w1t = (unsigned short*)alloc((size_t)E * D * FF * 2);
    unsigned short* w3t = (unsigned short*)alloc((size_t)E * D * FF * 2);
    unsigned short* w2t = (unsigned short*)alloc((size_t)E * D * FF * 2);
    unsigned short* acts = (unsigned short*)alloc((size_t)(NPOS + 128) * FF * 2);
    float* ffs    = (float*)alloc(2 * PSTRIDE * sizeof(float));

    hipMemsetAsync(counts, 0, 8 * sizeof(int), stream);
    transpose_all<<<dim3(48, 12, 24), 256, 0, stream>>>(w1, w3, w2, w1t, w3t, w2t);
    router_kernel<<<T / 4, 256, 0, stream>>>(x, rw, rb, dgw, dgb, xb, e_arr, s_arr, counts);
    scan_kernel<<<1, 64, 0, stream>>>(counts, bases, cursor, load_out,
                                      tme, tmm, tml, tme2, tmm2, tml2);
    assign_kernel<<<(T + 255) / 256, 256, 0, stream>>>(e_arr, cursor, a_tok, pos_of);
    gemm1_kernel<<<dim3(FF / 64, MAXTILE), 256, 0, stream>>>(
        xb, w1t, w1b, w3t, w3b, a_tok, tme, tmm, tml, acts);
    gemm2_kernel<<<dim3(D / 128, MAXTILE2, 2), 256, 0, stream>>>(
        acts, w2t, tme2, tmm2, tml2, ffs);
    combine_kernel<<<T, 256, 0, stream>>>(x, ffs, e_arr, pos_of, s_arr, w2b, lng, lnb, out);
}

// Round 8
// 225.658 us; speedup vs baseline: 1.3242x; 1.2791x over previous
//
#include <hip/hip_runtime.h>
#include <math.h>

#define T 2048
#define D 768
#define E 8
#define FF 3072
#define NPOS (2 * T)
#define MAXTILE 40
#define PSTRIDE ((size_t)(NPOS + 128) * D)

using f32x4 = __attribute__((ext_vector_type(4))) float;

template<bool HI>
__device__ __forceinline__ unsigned f2fp8pk(float a, float b, unsigned old) {
    return __builtin_amdgcn_cvt_pk_fp8_f32(a, b, (int)old, HI);
}
__device__ __forceinline__ unsigned char f2fp8(float f) {
    return (unsigned char)(__builtin_amdgcn_cvt_pk_fp8_f32(f, 0.f, 0, false) & 0xff);
}
__device__ __forceinline__ float siluf(float v) {
    return v / (1.0f + __expf(-v));
}
__device__ __forceinline__ void gload16(const void* g, void* l) {
    __builtin_amdgcn_global_load_lds(
        (const __attribute__((address_space(1))) void*)g,
        (__attribute__((address_space(3))) void*)l, 16, 0, 0);
}

// ---------------------------------------------------------------------------
// Fused transpose+convert all 3 weights: f32 [8][R][C] -> fp8 [8][C][R].
// zi<8: w1 (R=D,C=FF); zi<16: w3; zi>=16: w2 (R=FF,C=D; bx/by swapped).
// ---------------------------------------------------------------------------
__global__ __launch_bounds__(256)
void transpose_all(const float* __restrict__ w1, const float* __restrict__ w3,
                   const float* __restrict__ w2,
                   unsigned char* __restrict__ w1t, unsigned char* __restrict__ w3t,
                   unsigned char* __restrict__ w2t) {
    __shared__ unsigned char tb[64][80];   // [c][r], 80B stride: b32/b128-friendly
    int zi = blockIdx.z;
    const float* in; unsigned char* out; int R, C, r0, c0;
    if (zi < 16) {
        R = D; C = FF;
        int z = zi & 7;
        if (zi < 8) { in = w1 + (size_t)z * R * C; out = w1t + (size_t)z * R * C; }
        else        { in = w3 + (size_t)z * R * C; out = w3t + (size_t)z * R * C; }
        c0 = blockIdx.x * 64;
        r0 = blockIdx.y * 64;
    } else {
        R = FF; C = D;
        int z = zi - 16;
        in = w2 + (size_t)z * R * C; out = w2t + (size_t)z * R * C;
        r0 = blockIdx.x * 64;
        c0 = blockIdx.y * 64;
    }
    int tid = threadIdx.x;
    int ccL = tid & 3;
    int rl  = (tid >> 2) & 15;
    int ccH = tid >> 6;
    int c = (ccH * 4 + ccL) * 4;
    int rb = rl * 4;

    const float* ip = in + (size_t)(r0 + rb) * C + c0 + c;
    float4 v0 = *(const float4*)(ip);
    float4 v1 = *(const float4*)(ip + C);
    float4 v2 = *(const float4*)(ip + 2 * C);
    float4 v3 = *(const float4*)(ip + 3 * C);
    unsigned p;
    p = f2fp8pk<false>(v0.x, v1.x, 0); p = f2fp8pk<true>(v2.x, v3.x, p);
    *(unsigned*)&tb[c + 0][rb] = p;
    p = f2fp8pk<false>(v0.y, v1.y, 0); p = f2fp8pk<true>(v2.y, v3.y, p);
    *(unsigned*)&tb[c + 1][rb] = p;
    p = f2fp8pk<false>(v0.z, v1.z, 0); p = f2fp8pk<true>(v2.z, v3.z, p);
    *(unsigned*)&tb[c + 2][rb] = p;
    p = f2fp8pk<false>(v0.w, v1.w, 0); p = f2fp8pk<true>(v2.w, v3.w, p);
    *(unsigned*)&tb[c + 3][rb] = p;

    __syncthreads();
    unsigned char* op = out + (size_t)c0 * R + r0;
    int cc = tid >> 2;
    int rs = (tid & 3) * 16;
    *(uint4*)(op + (size_t)cc * R + rs) = *(const uint4*)&tb[cc][rs];
}

// ---------------------------------------------------------------------------
// Router (+ fused x -> fp8 conversion). Routing math stays f32.
// ---------------------------------------------------------------------------
__global__ void router_kernel(const float* __restrict__ x,
                              const float* __restrict__ rw,
                              const float* __restrict__ rb,
                              const float* __restrict__ dgw,
                              const float* __restrict__ dgb,
                              unsigned char* __restrict__ xb,
                              int* __restrict__ e_arr,
                              float* __restrict__ s_arr,
                              int* __restrict__ counts) {
    int lane = threadIdx.x & 63;
    int wv = threadIdx.x >> 6;
    int t = blockIdx.x * 4 + wv;
    if (t >= T) return;

    float lg[E], dl[E];
#pragma unroll
    for (int e = 0; e < E; ++e) { lg[e] = 0.f; dl[e] = 0.f; }

    const float* xt = x + (size_t)t * D;
    unsigned char* xbt = xb + (size_t)t * D;
#pragma unroll
    for (int i = 0; i < D / 64; ++i) {
        int d = lane + 64 * i;
        float xv = xt[d];
        xbt[d] = f2fp8(xv);
#pragma unroll
        for (int e = 0; e < E; ++e) {
            lg[e] = fmaf(xv, rw[d * E + e], lg[e]);
            dl[e] = fmaf(xv, dgw[e * D + d], dl[e]);
        }
    }
#pragma unroll
    for (int e = 0; e < E; ++e) {
        for (int off = 32; off; off >>= 1) {
            lg[e] += __shfl_xor(lg[e], off);
            dl[e] += __shfl_xor(dl[e], off);
        }
    }
    if (lane == 0) {
        float p[E];
        float m = -1e30f;
#pragma unroll
        for (int e = 0; e < E; ++e) { lg[e] += rb[e]; m = fmaxf(m, lg[e]); }
        float s = 0.f;
#pragma unroll
        for (int e = 0; e < E; ++e) { p[e] = __expf(lg[e] - m); s += p[e]; }
        float inv = 1.0f / s;
#pragma unroll
        for (int e = 0; e < E; ++e) p[e] *= inv;

        int i0 = 0; float b0 = p[0];
#pragma unroll
        for (int e = 1; e < E; ++e) if (p[e] > b0) { b0 = p[e]; i0 = e; }
        int i1 = -1; float b1 = -1.0f;
#pragma unroll
        for (int e = 0; e < E; ++e) if (e != i0 && p[e] > b1) { b1 = p[e]; i1 = e; }

        float eb = __expf(b1 - b0);
        float w0 = 1.0f / (1.0f + eb);
        float w1 = eb / (1.0f + eb);

        float dg0 = 1.0f / (1.0f + __expf(-(dl[i0] + dgb[i0])));
        float dg1 = 1.0f / (1.0f + __expf(-(dl[i1] + dgb[i1])));

        e_arr[t * 2 + 0] = i0;
        e_arr[t * 2 + 1] = i1;
        s_arr[t * 2 + 0] = dg0 * w0;
        s_arr[t * 2 + 1] = dg1 * w1;
        atomicAdd(&counts[i0], 1);
        atomicAdd(&counts[i1], 1);
    }
}

// ---------------------------------------------------------------------------
// Scan — bases, cursor, expert_load, 128-row expert-pure M-tile list
// ---------------------------------------------------------------------------
__global__ void scan_kernel(const int* __restrict__ counts,
                            int* __restrict__ bases,
                            int* __restrict__ cursor,
                            float* __restrict__ load_out,
                            int* __restrict__ tme, int* __restrict__ tmm,
                            int* __restrict__ tml) {
    if (threadIdx.x == 0 && blockIdx.x == 0) {
        int b = 0, nt = 0;
        for (int e = 0; e < E; ++e) {
            int c = counts[e];
            bases[e] = b;
            cursor[e] = b;
            load_out[e] = (float)c;
            for (int m = 0; m < c; m += 128) {
                tme[nt] = e;
                tmm[nt] = b + m;
                tml[nt] = (c - m < 128) ? (c - m) : 128;
                ++nt;
            }
            b += c;
        }
        bases[E] = b;
        for (; nt < MAXTILE; ++nt) tme[nt] = -1;
    }
}

__global__ void assign_kernel(const int* __restrict__ e_arr,
                              int* __restrict__ cursor,
                              int* __restrict__ a_tok,
                              int* __restrict__ pos_of) {
    int t = blockIdx.x * blockDim.x + threadIdx.x;
    if (t >= T) return;
#pragma unroll
    for (int s = 0; s < 2; ++s) {
        int e = e_arr[t * 2 + s];
        int pos = atomicAdd(&cursor[e], 1);
        a_tok[pos] = t;
        pos_of[t * 2 + s] = pos;
    }
}

// ---------------------------------------------------------------------------
// GEMM1 (fp8): acts[pos][f] = fp8(silu(x@w1+b1)*silu(x@w3+b3)).
// Tile 128(M) x 64(F), K=768, BK=128 (6 steps), counted vmcnt(8), setprio.
// ---------------------------------------------------------------------------
__global__ __launch_bounds__(256, 2)
void gemm1_kernel(const unsigned char* __restrict__ xb,
                  const unsigned char* __restrict__ w1t, const float* __restrict__ w1b,
                  const unsigned char* __restrict__ w3t, const float* __restrict__ w3b,
                  const int* __restrict__ a_tok,
                  const int* __restrict__ tme, const int* __restrict__ tmm,
                  const int* __restrict__ tml,
                  unsigned char* __restrict__ acts) {
    int mt = blockIdx.y;
    int e = tme[mt];
    if (e < 0) return;
    int mstart = tmm[mt], mlen = tml[mt];
    int fBase = blockIdx.x * 64;

    __shared__ char As[2][16384];   // A: 128 rows x 128 B (BK=128 fp8)
    __shared__ char Bs[2][16384];   // [0,8K)=w1 64x128B, [8K,16K)=w3

    int tid = threadIdx.x;
    int lane = tid & 63, wv = tid >> 6;
    int wr = wv & 1, wc = wv >> 1;
    int l15 = lane & 15, lk = lane >> 4;
    int lrow = lane >> 3;
    int swl = (((lane & 7) ^ lrow) << 4);

    const char* xbp = (const char*)xb;
    size_t aoff[4];
#pragma unroll
    for (int i = 0; i < 4; ++i) {
        int r = (wv + 4 * i) * 8 + lrow;
        int rr = r < mlen ? r : mlen - 1;
        aoff[i] = (size_t)a_tok[mstart + rr] * D + swl;
    }
    const char* w1p = (const char*)(w1t + (size_t)e * FF * D);
    const char* w3p = (const char*)(w3t + (size_t)e * FF * D);
    size_t boff[2];
#pragma unroll
    for (int i = 0; i < 2; ++i) {
        int f = (wv + 4 * i) * 8 + lrow;
        boff[i] = (size_t)(fBase + f) * D + swl;
    }

    auto stage = [&](int buf, int ks) {
        int kb = ks * 128;
        char* ab = &As[buf][0];
        char* bb = &Bs[buf][0];
#pragma unroll
        for (int i = 0; i < 4; ++i)
            gload16(xbp + aoff[i] + kb, ab + (wv + 4 * i) * 1024);
#pragma unroll
        for (int i = 0; i < 2; ++i) {
            gload16(w1p + boff[i] + kb, bb + (wv + 4 * i) * 1024);
            gload16(w3p + boff[i] + kb, bb + 8192 + (wv + 4 * i) * 1024);
        }
    };

    f32x4 hacc[4][2], gacc[4][2];
#pragma unroll
    for (int m = 0; m < 4; ++m)
#pragma unroll
        for (int n = 0; n < 2; ++n) {
            hacc[m][n] = f32x4{0.f, 0.f, 0.f, 0.f};
            gacc[m][n] = f32x4{0.f, 0.f, 0.f, 0.f};
        }

    stage(0, 0);
    stage(1, 1);
#pragma unroll 1
    for (int ks = 0; ks < 6; ++ks) {
        int cur = ks & 1;
        if (ks < 5) asm volatile("s_waitcnt vmcnt(8)" ::: "memory");
        else        asm volatile("s_waitcnt vmcnt(0)" ::: "memory");
        __builtin_amdgcn_s_barrier();
        const char* Ab = &As[cur][0];
        const char* Bb = &Bs[cur][0];
        __builtin_amdgcn_s_setprio(1);
#pragma unroll
        for (int ksub = 0; ksub < 4; ++ksub) {
            int koff = ksub * 32 + lk * 8;
            long af[4];
#pragma unroll
            for (int m = 0; m < 4; ++m) {
                int row = wr * 64 + m * 16 + l15;
                af[m] = *(const long*)(Ab + row * 128 + (koff ^ ((row & 7) << 4)));
            }
#pragma unroll
            for (int n = 0; n < 2; ++n) {
                int rowf = wc * 32 + n * 16 + l15;
                int off = rowf * 128 + (koff ^ ((rowf & 7) << 4));
                long b1 = *(const long*)(Bb + off);
                long b3 = *(const long*)(Bb + 8192 + off);
#pragma unroll
                for (int m = 0; m < 4; ++m) {
                    hacc[m][n] = __builtin_amdgcn_mfma_f32_16x16x32_fp8_fp8(af[m], b1, hacc[m][n], 0, 0, 0);
                    gacc[m][n] = __builtin_amdgcn_mfma_f32_16x16x32_fp8_fp8(af[m], b3, gacc[m][n], 0, 0, 0);
                }
            }
        }
        __builtin_amdgcn_s_setprio(0);
        __builtin_amdgcn_s_barrier();
        if (ks < 4) stage(cur, ks + 2);
    }

    // epilogue: silu(h)*silu(g) -> fp8 tile in LDS -> vectorized store
    unsigned char* al = (unsigned char*)&As[0][0];   // 128 x 64 fp8 = 8 KB
    float b1v[2], b3v[2];
#pragma unroll
    for (int n = 0; n < 2; ++n) {
        int f = fBase + wc * 32 + n * 16 + l15;
        b1v[n] = w1b[e * FF + f];
        b3v[n] = w3b[e * FF + f];
    }
#pragma unroll
    for (int m = 0; m < 4; ++m)
#pragma unroll
        for (int n = 0; n < 2; ++n)
#pragma unroll
            for (int j = 0; j < 4; ++j) {
                float h = hacc[m][n][j] + b1v[n];
                float g = gacc[m][n][j] + b3v[n];
                int row = wr * 64 + m * 16 + lk * 4 + j;
                int col = wc * 32 + n * 16 + l15;
                al[row * 64 + col] = f2fp8(siluf(h) * siluf(g));
            }
    __syncthreads();
    int r = tid >> 1, cb = (tid & 1) * 32;
    if (r < mlen) {
        unsigned char* gp = acts + (size_t)(mstart + r) * FF + fBase + cb;
        const unsigned char* lp = al + r * 64 + cb;
        *(uint4*)(gp)      = *(const uint4*)(lp);
        *(uint4*)(gp + 16) = *(const uint4*)(lp + 16);
    }
}

// ---------------------------------------------------------------------------
// GEMM2 (fp8): ffs_part[ksl][pos][d] = acts[pos][kslice] @ w2[kslice], f32 out.
// Tile 128(M) x 128(N), split-K=2 (K=1536 each, BK=128 -> 12 steps).
// ---------------------------------------------------------------------------
__global__ __launch_bounds__(256, 2)
void gemm2_kernel(const unsigned char* __restrict__ acts,
                  const unsigned char* __restrict__ w2t,
                  const int* __restrict__ tme, const int* __restrict__ tmm,
                  const int* __restrict__ tml,
                  float* __restrict__ ffs) {
    int mt = blockIdx.y;
    int e = tme[mt];
    if (e < 0) return;
    int mstart = tmm[mt], mlen = tml[mt];
    int nBase = blockIdx.x * 128;
    int ksl = blockIdx.z;

    __shared__ char As[2][16384];
    __shared__ char Bs[2][16384];

    int tid = threadIdx.x;
    int lane = tid & 63, wv = tid >> 6;
    int wr = wv & 1, wc = wv >> 1;
    int l15 = lane & 15, lk = lane >> 4;
    int lrow = lane >> 3;
    int swl = (((lane & 7) ^ lrow) << 4);

    const char* ap = (const char*)acts;
    const char* w2p = (const char*)(w2t + (size_t)e * (size_t)D * FF);
    size_t aoff[4], boff[4];
#pragma unroll
    for (int i = 0; i < 4; ++i) {
        int r = (wv + 4 * i) * 8 + lrow;
        aoff[i] = (size_t)(mstart + r) * FF + swl;
        boff[i] = (size_t)(nBase + r) * FF + swl;
    }
    int kOff = ksl * (FF / 2);   // byte offset of this K slice (fp8)

    auto stage = [&](int buf, int ks) {
        int kb = kOff + ks * 128;
        char* ab = &As[buf][0];
        char* bb = &Bs[buf][0];
#pragma unroll
        for (int i = 0; i < 4; ++i) {
            gload16(ap + aoff[i] + kb, ab + (wv + 4 * i) * 1024);
            gload16(w2p + boff[i] + kb, bb + (wv + 4 * i) * 1024);
        }
    };

    f32x4 facc[4][4];
#pragma unroll
    for (int m = 0; m < 4; ++m)
#pragma unroll
        for (int n = 0; n < 4; ++n) facc[m][n] = f32x4{0.f, 0.f, 0.f, 0.f};

    stage(0, 0);
    stage(1, 1);
#pragma unroll 1
    for (int ks = 0; ks < 12; ++ks) {
        int cur = ks & 1;
        if (ks < 11) asm volatile("s_waitcnt vmcnt(8)" ::: "memory");
        else         asm volatile("s_waitcnt vmcnt(0)" ::: "memory");
        __builtin_amdgcn_s_barrier();
        const char* Ab = &As[cur][0];
        const char* Bb = &Bs[cur][0];
        __builtin_amdgcn_s_setprio(1);
#pragma unroll
        for (int ksub = 0; ksub < 4; ++ksub) {
            int koff = ksub * 32 + lk * 8;
            long af[4], bf[4];
#pragma unroll
            for (int m = 0; m < 4; ++m) {
                int row = wr * 64 + m * 16 + l15;
                af[m] = *(const long*)(Ab + row * 128 + (koff ^ ((row & 7) << 4)));
            }
#pragma unroll
            for (int n = 0; n < 4; ++n) {
                int row = wc * 64 + n * 16 + l15;
                bf[n] = *(const long*)(Bb + row * 128 + (koff ^ ((row & 7) << 4)));
            }
#pragma unroll
            for (int m = 0; m < 4; ++m)
#pragma unroll
                for (int n = 0; n < 4; ++n)
                    facc[m][n] = __builtin_amdgcn_mfma_f32_16x16x32_fp8_fp8(af[m], bf[n], facc[m][n], 0, 0, 0);
        }
        __builtin_amdgcn_s_setprio(0);
        __builtin_amdgcn_s_barrier();
        if (ks < 10) stage(cur, ks + 2);
    }

    float* op = ffs + (size_t)ksl * PSTRIDE;
#pragma unroll
    for (int m = 0; m < 4; ++m)
#pragma unroll
        for (int j = 0; j < 4; ++j) {
            int row = wr * 64 + m * 16 + lk * 4 + j;
            if (row < mlen) {
                float* gp = op + (size_t)(mstart + row) * D + nBase + wc * 64;
#pragma unroll
                for (int n = 0; n < 4; ++n)
                    gp[n * 16 + l15] = facc[m][n][j];
            }
        }
}

// ---------------------------------------------------------------------------
// Combine — f = part0 + part1 + w2b; y = x + s*f per slot; dual LN; sum; out
// ---------------------------------------------------------------------------
__global__ __launch_bounds__(256)
void combine_kernel(const float* __restrict__ x,
                    const float* __restrict__ ffs,
                    const int* __restrict__ e_arr,
                    const int* __restrict__ pos_of,
                    const float* __restrict__ s_arr,
                    const float* __restrict__ w2b,
                    const float* __restrict__ lng,
                    const float* __restrict__ lnb,
                    float* __restrict__ out) {
    int t = blockIdx.x;
    int tid = threadIdx.x;
    int p0 = pos_of[t * 2], p1 = pos_of[t * 2 + 1];
    int e0 = e_arr[t * 2], e1 = e_arr[t * 2 + 1];
    float sw0 = s_arr[t * 2], sw1 = s_arr[t * 2 + 1];
    __shared__ float red[4][4];

    float y0[3], y1[3];
    float s0 = 0.f, q0 = 0.f, s1 = 0.f, q1 = 0.f;
#pragma unroll
    for (int m = 0; m < 3; ++m) {
        int d = tid + 256 * m;
        float xv = x[(size_t)t * D + d];
        float f0 = ffs[(size_t)p0 * D + d] + ffs[PSTRIDE + (size_t)p0 * D + d] + w2b[e0 * D + d];
        float f1 = ffs[(size_t)p1 * D + d] + ffs[PSTRIDE + (size_t)p1 * D + d] + w2b[e1 * D + d];
        float a = xv + sw0 * f0;
        float bb = xv + sw1 * f1;
        y0[m] = a; y1[m] = bb;
        s0 += a; q0 += a * a;
        s1 += bb; q1 += bb * bb;
    }
    for (int off = 32; off; off >>= 1) {
        s0 += __shfl_xor(s0, off);
        q0 += __shfl_xor(q0, off);
        s1 += __shfl_xor(s1, off);
        q1 += __shfl_xor(q1, off);
    }
    int wv = tid >> 6, lane = tid & 63;
    if (lane == 0) { red[wv][0] = s0; red[wv][1] = q0; red[wv][2] = s1; red[wv][3] = q1; }
    __syncthreads();
    s0 = red[0][0] + red[1][0] + red[2][0] + red[3][0];
    q0 = red[0][1] + red[1][1] + red[2][1] + red[3][1];
    s1 = red[0][2] + red[1][2] + red[2][2] + red[3][2];
    q1 = red[0][3] + red[1][3] + red[2][3] + red[3][3];

    const float invD = 1.0f / (float)D;
    float mu0 = s0 * invD, var0 = q0 * invD - mu0 * mu0;
    float mu1 = s1 * invD, var1 = q1 * invD - mu1 * mu1;
    float r0 = rsqrtf(var0 + 1e-5f);
    float r1 = rsqrtf(var1 + 1e-5f);

#pragma unroll
    for (int m = 0; m < 3; ++m) {
        int d = tid + 256 * m;
        out[(size_t)t * D + d] =
            (y0[m] - mu0) * r0 * lng[e0 * D + d] + lnb[e0 * D + d] +
            (y1[m] - mu1) * r1 * lng[e1 * D + d] + lnb[e1 * D + d];
    }
}

// ---------------------------------------------------------------------------
extern "C" void kernel_launch(void* const* d_in, const int* in_sizes, int n_in,
                              void* d_out, int out_size, void* d_ws, size_t ws_size,
                              hipStream_t stream) {
    const float* x   = (const float*)d_in[0];
    const float* rw  = (const float*)d_in[1];
    const float* rb  = (const float*)d_in[2];
    const float* dgw = (const float*)d_in[3];
    const float* dgb = (const float*)d_in[4];
    const float* w1  = (const float*)d_in[5];
    const float* w1b = (const float*)d_in[6];
    const float* w2  = (const float*)d_in[7];
    const float* w2b = (const float*)d_in[8];
    const float* w3  = (const float*)d_in[9];
    const float* w3b = (const float*)d_in[10];
    const float* lng = (const float*)d_in[11];
    const float* lnb = (const float*)d_in[12];

    float* out = (float*)d_out;
    float* load_out = out + (size_t)T * D;

    char* w = (char*)d_ws;
    size_t off = 0;
    auto alloc = [&](size_t bytes) -> void* {
        void* p = w + off;
        off = (off + bytes + 255) & ~(size_t)255;
        return p;
    };
    int* counts   = (int*)alloc(8 * sizeof(int));
    int* bases    = (int*)alloc(9 * sizeof(int));
    int* cursor   = (int*)alloc(8 * sizeof(int));
    int* e_arr    = (int*)alloc(NPOS * sizeof(int));
    int* a_tok    = (int*)alloc(NPOS * sizeof(int));
    int* pos_of   = (int*)alloc(NPOS * sizeof(int));
    float* s_arr  = (float*)alloc(NPOS * sizeof(float));
    int* tme      = (int*)alloc(MAXTILE * sizeof(int));
    int* tmm      = (int*)alloc(MAXTILE * sizeof(int));
    int* tml      = (int*)alloc(MAXTILE * sizeof(int));
    unsigned char* xb  = (unsigned char*)alloc((size_t)T * D);
    unsigned char* w1t = (unsigned char*)alloc((size_t)E * D * FF);
    unsigned char* w3t = (unsigned char*)alloc((size_t)E * D * FF);
    unsigned char* w2t = (unsigned char*)alloc((size_t)E * D * FF);
    unsigned char* acts = (unsigned char*)alloc((size_t)(NPOS + 128) * FF);
    float* ffs    = (float*)alloc(2 * PSTRIDE * sizeof(float));

    (void)hipMemsetAsync(counts, 0, 8 * sizeof(int), stream);
    transpose_all<<<dim3(48, 12, 24), 256, 0, stream>>>(w1, w3, w2, w1t, w3t, w2t);
    router_kernel<<<T / 4, 256, 0, stream>>>(x, rw, rb, dgw, dgb, xb, e_arr, s_arr, counts);
    scan_kernel<<<1, 64, 0, stream>>>(counts, bases, cursor, load_out, tme, tmm, tml);
    assign_kernel<<<(T + 255) / 256, 256, 0, stream>>>(e_arr, cursor, a_tok, pos_of);
    gemm1_kernel<<<dim3(FF / 64, MAXTILE), 256, 0, stream>>>(
        xb, w1t, w1b, w3t, w3b, a_tok, tme, tmm, tml, acts);
    gemm2_kernel<<<dim3(D / 128, MAXTILE, 2), 256, 0, stream>>>(
        acts, w2t, tme, tmm, tml, ffs);
    combine_kernel<<<T, 256, 0, stream>>>(x, ffs, e_arr, pos_of, s_arr, w2b, lng, lnb, out);
}

// Round 9
// 221.484 us; speedup vs baseline: 1.3491x; 1.0188x over previous
//
#include <hip/hip_runtime.h>
#include <math.h>

#define T 2048
#define D 768
#define E 8
#define FF 3072
#define NPOS (2 * T)
#define MAXTILE 40
#define PSTRIDE ((size_t)(NPOS + 128) * D)

using f32x4 = __attribute__((ext_vector_type(4))) float;

template<bool HI>
__device__ __forceinline__ unsigned f2fp8pk(float a, float b, unsigned old) {
    return __builtin_amdgcn_cvt_pk_fp8_f32(a, b, (int)old, HI);
}
__device__ __forceinline__ unsigned char f2fp8(float f) {
    return (unsigned char)(__builtin_amdgcn_cvt_pk_fp8_f32(f, 0.f, 0, false) & 0xff);
}
__device__ __forceinline__ float siluf(float v) {
    return v / (1.0f + __expf(-v));
}
__device__ __forceinline__ void gload16(const void* g, void* l) {
    __builtin_amdgcn_global_load_lds(
        (const __attribute__((address_space(1))) void*)g,
        (__attribute__((address_space(3))) void*)l, 16, 0, 0);
}

// ---------------------------------------------------------------------------
// Fused transpose+convert all 3 weights: f32 [8][R][C] -> fp8 [8][C][R].
// Tile 128 rows x 64 cols: reads 256B/row, writes 128B/row (full HBM line).
// LDS as u32 words [64 cols][33], granule-swizzle g^=(c&7) both phases.
// zi<8: w1 (R=D,C=FF); zi<16: w3; zi>=16: w2 (R=FF,C=D via index remap).
// ---------------------------------------------------------------------------
__global__ __launch_bounds__(256)
void transpose_all(const float* __restrict__ w1, const float* __restrict__ w3,
                   const float* __restrict__ w2,
                   unsigned char* __restrict__ w1t, unsigned char* __restrict__ w3t,
                   unsigned char* __restrict__ w2t) {
    __shared__ unsigned tbw[64][33];   // [col][32 packed-row words + pad]
    int zi = blockIdx.z;
    const float* in; unsigned char* out; int R, C, r0, c0;
    if (zi < 16) {
        R = D; C = FF;
        int z = zi & 7;
        if (zi < 8) { in = w1 + (size_t)z * R * C; out = w1t + (size_t)z * R * C; }
        else        { in = w3 + (size_t)z * R * C; out = w3t + (size_t)z * R * C; }
        r0 = blockIdx.y * 128;            // 6 tiles over D
        c0 = blockIdx.x * 64;             // 48 tiles over FF
    } else {
        R = FF; C = D;
        int z = zi - 16;
        in = w2 + (size_t)z * R * C; out = w2t + (size_t)z * R * C;
        int idx = blockIdx.y * 48 + blockIdx.x;   // 288 = 24 x 12
        r0 = (idx % 24) * 128;            // 24 tiles over FF
        c0 = (idx / 24) * 64;             // 12 tiles over D
    }
    int tid = threadIdx.x;

    // phase 1: read 4 rows x 4 cols f32, pack rows per column, b32 LDS stores
#pragma unroll
    for (int p = 0; p < 2; ++p) {
        int rg = (tid >> 4) + p * 16;     // packed-word row index 0..31
        int cb = (tid & 15) * 4;
        int rb = rg * 4;
        const float* ip = in + (size_t)(r0 + rb) * C + c0 + cb;
        float4 v0 = *(const float4*)(ip);
        float4 v1 = *(const float4*)(ip + C);
        float4 v2 = *(const float4*)(ip + 2 * C);
        float4 v3 = *(const float4*)(ip + 3 * C);
        int g0 = rg >> 2, rw = rg & 3;
        unsigned pk;
        pk = f2fp8pk<false>(v0.x, v1.x, 0); pk = f2fp8pk<true>(v2.x, v3.x, pk);
        { int c = cb + 0; tbw[c][(((g0 ^ (c & 7)) << 2) | rw)] = pk; }
        pk = f2fp8pk<false>(v0.y, v1.y, 0); pk = f2fp8pk<true>(v2.y, v3.y, pk);
        { int c = cb + 1; tbw[c][(((g0 ^ (c & 7)) << 2) | rw)] = pk; }
        pk = f2fp8pk<false>(v0.z, v1.z, 0); pk = f2fp8pk<true>(v2.z, v3.z, pk);
        { int c = cb + 2; tbw[c][(((g0 ^ (c & 7)) << 2) | rw)] = pk; }
        pk = f2fp8pk<false>(v0.w, v1.w, 0); pk = f2fp8pk<true>(v2.w, v3.w, pk);
        { int c = cb + 3; tbw[c][(((g0 ^ (c & 7)) << 2) | rw)] = pk; }
    }
    __syncthreads();

    // phase 2: each lane emits 16B; 8 lanes = one 128B output line
#pragma unroll
    for (int p = 0; p < 2; ++p) {
        int c = (tid >> 3) + p * 32;      // output row (input col) 0..63
        int gs = tid & 7;                 // 16B granule within 128B
        const unsigned* bp = &tbw[c][((gs ^ (c & 7)) << 2)];
        uint4 val;
        val.x = bp[0]; val.y = bp[1]; val.z = bp[2]; val.w = bp[3];
        *(uint4*)(out + (size_t)(c0 + c) * R + r0 + gs * 16) = val;
    }
}

// ---------------------------------------------------------------------------
// Router (+ fused x -> fp8 conversion). Routing math stays f32.
// ---------------------------------------------------------------------------
__global__ void router_kernel(const float* __restrict__ x,
                              const float* __restrict__ rw,
                              const float* __restrict__ rb,
                              const float* __restrict__ dgw,
                              const float* __restrict__ dgb,
                              unsigned char* __restrict__ xb,
                              int* __restrict__ e_arr,
                              float* __restrict__ s_arr,
                              int* __restrict__ counts) {
    int lane = threadIdx.x & 63;
    int wv = threadIdx.x >> 6;
    int t = blockIdx.x * 4 + wv;
    if (t >= T) return;

    float lg[E], dl[E];
#pragma unroll
    for (int e = 0; e < E; ++e) { lg[e] = 0.f; dl[e] = 0.f; }

    const float* xt = x + (size_t)t * D;
    unsigned char* xbt = xb + (size_t)t * D;
#pragma unroll
    for (int i = 0; i < D / 64; ++i) {
        int d = lane + 64 * i;
        float xv = xt[d];
        xbt[d] = f2fp8(xv);
#pragma unroll
        for (int e = 0; e < E; ++e) {
            lg[e] = fmaf(xv, rw[d * E + e], lg[e]);
            dl[e] = fmaf(xv, dgw[e * D + d], dl[e]);
        }
    }
#pragma unroll
    for (int e = 0; e < E; ++e) {
        for (int off = 32; off; off >>= 1) {
            lg[e] += __shfl_xor(lg[e], off);
            dl[e] += __shfl_xor(dl[e], off);
        }
    }
    if (lane == 0) {
        float p[E];
        float m = -1e30f;
#pragma unroll
        for (int e = 0; e < E; ++e) { lg[e] += rb[e]; m = fmaxf(m, lg[e]); }
        float s = 0.f;
#pragma unroll
        for (int e = 0; e < E; ++e) { p[e] = __expf(lg[e] - m); s += p[e]; }
        float inv = 1.0f / s;
#pragma unroll
        for (int e = 0; e < E; ++e) p[e] *= inv;

        int i0 = 0; float b0 = p[0];
#pragma unroll
        for (int e = 1; e < E; ++e) if (p[e] > b0) { b0 = p[e]; i0 = e; }
        int i1 = -1; float b1 = -1.0f;
#pragma unroll
        for (int e = 0; e < E; ++e) if (e != i0 && p[e] > b1) { b1 = p[e]; i1 = e; }

        float eb = __expf(b1 - b0);
        float w0 = 1.0f / (1.0f + eb);
        float w1 = eb / (1.0f + eb);

        float dg0 = 1.0f / (1.0f + __expf(-(dl[i0] + dgb[i0])));
        float dg1 = 1.0f / (1.0f + __expf(-(dl[i1] + dgb[i1])));

        e_arr[t * 2 + 0] = i0;
        e_arr[t * 2 + 1] = i1;
        s_arr[t * 2 + 0] = dg0 * w0;
        s_arr[t * 2 + 1] = dg1 * w1;
        atomicAdd(&counts[i0], 1);
        atomicAdd(&counts[i1], 1);
    }
}

// ---------------------------------------------------------------------------
// Scan — bases, cursor, expert_load, 128-row expert-pure M-tile list
// ---------------------------------------------------------------------------
__global__ void scan_kernel(const int* __restrict__ counts,
                            int* __restrict__ bases,
                            int* __restrict__ cursor,
                            float* __restrict__ load_out,
                            int* __restrict__ tme, int* __restrict__ tmm,
                            int* __restrict__ tml) {
    if (threadIdx.x == 0 && blockIdx.x == 0) {
        int b = 0, nt = 0;
        for (int e = 0; e < E; ++e) {
            int c = counts[e];
            bases[e] = b;
            cursor[e] = b;
            load_out[e] = (float)c;
            for (int m = 0; m < c; m += 128) {
                tme[nt] = e;
                tmm[nt] = b + m;
                tml[nt] = (c - m < 128) ? (c - m) : 128;
                ++nt;
            }
            b += c;
        }
        bases[E] = b;
        for (; nt < MAXTILE; ++nt) tme[nt] = -1;
    }
}

__global__ void assign_kernel(const int* __restrict__ e_arr,
                              int* __restrict__ cursor,
                              int* __restrict__ a_tok,
                              int* __restrict__ pos_of) {
    int t = blockIdx.x * blockDim.x + threadIdx.x;
    if (t >= T) return;
#pragma unroll
    for (int s = 0; s < 2; ++s) {
        int e = e_arr[t * 2 + s];
        int pos = atomicAdd(&cursor[e], 1);
        a_tok[pos] = t;
        pos_of[t * 2 + s] = pos;
    }
}

// ---------------------------------------------------------------------------
// GEMM1 (fp8): acts[pos][f] = fp8(silu(x@w1+b1)*silu(x@w3+b3)).
// Tile 128(M) x 64(F), K=768, BK=128 (6 steps), counted vmcnt(8), setprio.
// ---------------------------------------------------------------------------
__global__ __launch_bounds__(256, 2)
void gemm1_kernel(const unsigned char* __restrict__ xb,
                  const unsigned char* __restrict__ w1t, const float* __restrict__ w1b,
                  const unsigned char* __restrict__ w3t, const float* __restrict__ w3b,
                  const int* __restrict__ a_tok,
                  const int* __restrict__ tme, const int* __restrict__ tmm,
                  const int* __restrict__ tml,
                  unsigned char* __restrict__ acts) {
    int mt = blockIdx.y;
    int e = tme[mt];
    if (e < 0) return;
    int mstart = tmm[mt], mlen = tml[mt];
    int fBase = blockIdx.x * 64;

    __shared__ char As[2][16384];   // A: 128 rows x 128 B (BK=128 fp8)
    __shared__ char Bs[2][16384];   // [0,8K)=w1 64x128B, [8K,16K)=w3

    int tid = threadIdx.x;
    int lane = tid & 63, wv = tid >> 6;
    int wr = wv & 1, wc = wv >> 1;
    int l15 = lane & 15, lk = lane >> 4;
    int lrow = lane >> 3;
    int swl = (((lane & 7) ^ lrow) << 4);

    const char* xbp = (const char*)xb;
    size_t aoff[4];
#pragma unroll
    for (int i = 0; i < 4; ++i) {
        int r = (wv + 4 * i) * 8 + lrow;
        int rr = r < mlen ? r : mlen - 1;
        aoff[i] = (size_t)a_tok[mstart + rr] * D + swl;
    }
    const char* w1p = (const char*)(w1t + (size_t)e * FF * D);
    const char* w3p = (const char*)(w3t + (size_t)e * FF * D);
    size_t boff[2];
#pragma unroll
    for (int i = 0; i < 2; ++i) {
        int f = (wv + 4 * i) * 8 + lrow;
        boff[i] = (size_t)(fBase + f) * D + swl;
    }

    auto stage = [&](int buf, int ks) {
        int kb = ks * 128;
        char* ab = &As[buf][0];
        char* bb = &Bs[buf][0];
#pragma unroll
        for (int i = 0; i < 4; ++i)
            gload16(xbp + aoff[i] + kb, ab + (wv + 4 * i) * 1024);
#pragma unroll
        for (int i = 0; i < 2; ++i) {
            gload16(w1p + boff[i] + kb, bb + (wv + 4 * i) * 1024);
            gload16(w3p + boff[i] + kb, bb + 8192 + (wv + 4 * i) * 1024);
        }
    };

    f32x4 hacc[4][2], gacc[4][2];
#pragma unroll
    for (int m = 0; m < 4; ++m)
#pragma unroll
        for (int n = 0; n < 2; ++n) {
            hacc[m][n] = f32x4{0.f, 0.f, 0.f, 0.f};
            gacc[m][n] = f32x4{0.f, 0.f, 0.f, 0.f};
        }

    stage(0, 0);
    stage(1, 1);
#pragma unroll 1
    for (int ks = 0; ks < 6; ++ks) {
        int cur = ks & 1;
        if (ks < 5) asm volatile("s_waitcnt vmcnt(8)" ::: "memory");
        else        asm volatile("s_waitcnt vmcnt(0)" ::: "memory");
        __builtin_amdgcn_s_barrier();
        const char* Ab = &As[cur][0];
        const char* Bb = &Bs[cur][0];
        __builtin_amdgcn_s_setprio(1);
#pragma unroll
        for (int ksub = 0; ksub < 4; ++ksub) {
            int koff = ksub * 32 + lk * 8;
            long af[4];
#pragma unroll
            for (int m = 0; m < 4; ++m) {
                int row = wr * 64 + m * 16 + l15;
                af[m] = *(const long*)(Ab + row * 128 + (koff ^ ((row & 7) << 4)));
            }
#pragma unroll
            for (int n = 0; n < 2; ++n) {
                int rowf = wc * 32 + n * 16 + l15;
                int off = rowf * 128 + (koff ^ ((rowf & 7) << 4));
                long b1 = *(const long*)(Bb + off);
                long b3 = *(const long*)(Bb + 8192 + off);
#pragma unroll
                for (int m = 0; m < 4; ++m) {
                    hacc[m][n] = __builtin_amdgcn_mfma_f32_16x16x32_fp8_fp8(af[m], b1, hacc[m][n], 0, 0, 0);
                    gacc[m][n] = __builtin_amdgcn_mfma_f32_16x16x32_fp8_fp8(af[m], b3, gacc[m][n], 0, 0, 0);
                }
            }
        }
        __builtin_amdgcn_s_setprio(0);
        __builtin_amdgcn_s_barrier();
        if (ks < 4) stage(cur, ks + 2);
    }

    // epilogue: silu(h)*silu(g) -> fp8 tile in LDS -> vectorized store
    unsigned char* al = (unsigned char*)&As[0][0];   // 128 x 64 fp8 = 8 KB
    float b1v[2], b3v[2];
#pragma unroll
    for (int n = 0; n < 2; ++n) {
        int f = fBase + wc * 32 + n * 16 + l15;
        b1v[n] = w1b[e * FF + f];
        b3v[n] = w3b[e * FF + f];
    }
#pragma unroll
    for (int m = 0; m < 4; ++m)
#pragma unroll
        for (int n = 0; n < 2; ++n)
#pragma unroll
            for (int j = 0; j < 4; ++j) {
                float h = hacc[m][n][j] + b1v[n];
                float g = gacc[m][n][j] + b3v[n];
                int row = wr * 64 + m * 16 + lk * 4 + j;
                int col = wc * 32 + n * 16 + l15;
                al[row * 64 + col] = f2fp8(siluf(h) * siluf(g));
            }
    __syncthreads();
    int r = tid >> 1, cb = (tid & 1) * 32;
    if (r < mlen) {
        unsigned char* gp = acts + (size_t)(mstart + r) * FF + fBase + cb;
        const unsigned char* lp = al + r * 64 + cb;
        *(uint4*)(gp)      = *(const uint4*)(lp);
        *(uint4*)(gp + 16) = *(const uint4*)(lp + 16);
    }
}

// ---------------------------------------------------------------------------
// GEMM2 (fp8): ffs_part[ksl][pos][d] = acts[pos][kslice] @ w2[kslice], f32 out.
// Tile 128(M) x 128(N), split-K=2 (K=1536 each, BK=128 -> 12 steps).
// ---------------------------------------------------------------------------
__global__ __launch_bounds__(256, 2)
void gemm2_kernel(const unsigned char* __restrict__ acts,
                  const unsigned char* __restrict__ w2t,
                  const int* __restrict__ tme, const int* __restrict__ tmm,
                  const int* __restrict__ tml,
                  float* __restrict__ ffs) {
    int mt = blockIdx.y;
    int e = tme[mt];
    if (e < 0) return;
    int mstart = tmm[mt], mlen = tml[mt];
    int nBase = blockIdx.x * 128;
    int ksl = blockIdx.z;

    __shared__ char As[2][16384];
    __shared__ char Bs[2][16384];

    int tid = threadIdx.x;
    int lane = tid & 63, wv = tid >> 6;
    int wr = wv & 1, wc = wv >> 1;
    int l15 = lane & 15, lk = lane >> 4;
    int lrow = lane >> 3;
    int swl = (((lane & 7) ^ lrow) << 4);

    const char* ap = (const char*)acts;
    const char* w2p = (const char*)(w2t + (size_t)e * (size_t)D * FF);
    size_t aoff[4], boff[4];
#pragma unroll
    for (int i = 0; i < 4; ++i) {
        int r = (wv + 4 * i) * 8 + lrow;
        aoff[i] = (size_t)(mstart + r) * FF + swl;
        boff[i] = (size_t)(nBase + r) * FF + swl;
    }
    int kOff = ksl * (FF / 2);   // byte offset of this K slice (fp8)

    auto stage = [&](int buf, int ks) {
        int kb = kOff + ks * 128;
        char* ab = &As[buf][0];
        char* bb = &Bs[buf][0];
#pragma unroll
        for (int i = 0; i < 4; ++i) {
            gload16(ap + aoff[i] + kb, ab + (wv + 4 * i) * 1024);
            gload16(w2p + boff[i] + kb, bb + (wv + 4 * i) * 1024);
        }
    };

    f32x4 facc[4][4];
#pragma unroll
    for (int m = 0; m < 4; ++m)
#pragma unroll
        for (int n = 0; n < 4; ++n) facc[m][n] = f32x4{0.f, 0.f, 0.f, 0.f};

    stage(0, 0);
    stage(1, 1);
#pragma unroll 1
    for (int ks = 0; ks < 12; ++ks) {
        int cur = ks & 1;
        if (ks < 11) asm volatile("s_waitcnt vmcnt(8)" ::: "memory");
        else         asm volatile("s_waitcnt vmcnt(0)" ::: "memory");
        __builtin_amdgcn_s_barrier();
        const char* Ab = &As[cur][0];
        const char* Bb = &Bs[cur][0];
        __builtin_amdgcn_s_setprio(1);
#pragma unroll
        for (int ksub = 0; ksub < 4; ++ksub) {
            int koff = ksub * 32 + lk * 8;
            long af[4], bf[4];
#pragma unroll
            for (int m = 0; m < 4; ++m) {
                int row = wr * 64 + m * 16 + l15;
                af[m] = *(const long*)(Ab + row * 128 + (koff ^ ((row & 7) << 4)));
            }
#pragma unroll
            for (int n = 0; n < 4; ++n) {
                int row = wc * 64 + n * 16 + l15;
                bf[n] = *(const long*)(Bb + row * 128 + (koff ^ ((row & 7) << 4)));
            }
#pragma unroll
            for (int m = 0; m < 4; ++m)
#pragma unroll
                for (int n = 0; n < 4; ++n)
                    facc[m][n] = __builtin_amdgcn_mfma_f32_16x16x32_fp8_fp8(af[m], bf[n], facc[m][n], 0, 0, 0);
        }
        __builtin_amdgcn_s_setprio(0);
        __builtin_amdgcn_s_barrier();
        if (ks < 10) stage(cur, ks + 2);
    }

    float* op = ffs + (size_t)ksl * PSTRIDE;
#pragma unroll
    for (int m = 0; m < 4; ++m)
#pragma unroll
        for (int j = 0; j < 4; ++j) {
            int row = wr * 64 + m * 16 + lk * 4 + j;
            if (row < mlen) {
                float* gp = op + (size_t)(mstart + row) * D + nBase + wc * 64;
#pragma unroll
                for (int n = 0; n < 4; ++n)
                    gp[n * 16 + l15] = facc[m][n][j];
            }
        }
}

// ---------------------------------------------------------------------------
// Combine — f = part0 + part1 + w2b; y = x + s*f per slot; dual LN; sum; out
// ---------------------------------------------------------------------------
__global__ __launch_bounds__(256)
void combine_kernel(const float* __restrict__ x,
                    const float* __restrict__ ffs,
                    const int* __restrict__ e_arr,
                    const int* __restrict__ pos_of,
                    const float* __restrict__ s_arr,
                    const float* __restrict__ w2b,
                    const float* __restrict__ lng,
                    const float* __restrict__ lnb,
                    float* __restrict__ out) {
    int t = blockIdx.x;
    int tid = threadIdx.x;
    int p0 = pos_of[t * 2], p1 = pos_of[t * 2 + 1];
    int e0 = e_arr[t * 2], e1 = e_arr[t * 2 + 1];
    float sw0 = s_arr[t * 2], sw1 = s_arr[t * 2 + 1];
    __shared__ float red[4][4];

    float y0[3], y1[3];
    float s0 = 0.f, q0 = 0.f, s1 = 0.f, q1 = 0.f;
#pragma unroll
    for (int m = 0; m < 3; ++m) {
        int d = tid + 256 * m;
        float xv = x[(size_t)t * D + d];
        float f0 = ffs[(size_t)p0 * D + d] + ffs[PSTRIDE + (size_t)p0 * D + d] + w2b[e0 * D + d];
        float f1 = ffs[(size_t)p1 * D + d] + ffs[PSTRIDE + (size_t)p1 * D + d] + w2b[e1 * D + d];
        float a = xv + sw0 * f0;
        float bb = xv + sw1 * f1;
        y0[m] = a; y1[m] = bb;
        s0 += a; q0 += a * a;
        s1 += bb; q1 += bb * bb;
    }
    for (int off = 32; off; off >>= 1) {
        s0 += __shfl_xor(s0, off);
        q0 += __shfl_xor(q0, off);
        s1 += __shfl_xor(s1, off);
        q1 += __shfl_xor(q1, off);
    }
    int wv = tid >> 6, lane = tid & 63;
    if (lane == 0) { red[wv][0] = s0; red[wv][1] = q0; red[wv][2] = s1; red[wv][3] = q1; }
    __syncthreads();
    s0 = red[0][0] + red[1][0] + red[2][0] + red[3][0];
    q0 = red[0][1] + red[1][1] + red[2][1] + red[3][1];
    s1 = red[0][2] + red[1][2] + red[2][2] + red[3][2];
    q1 = red[0][3] + red[1][3] + red[2][3] + red[3][3];

    const float invD = 1.0f / (float)D;
    float mu0 = s0 * invD, var0 = q0 * invD - mu0 * mu0;
    float mu1 = s1 * invD, var1 = q1 * invD - mu1 * mu1;
    float r0 = rsqrtf(var0 + 1e-5f);
    float r1 = rsqrtf(var1 + 1e-5f);

#pragma unroll
    for (int m = 0; m < 3; ++m) {
        int d = tid + 256 * m;
        out[(size_t)t * D + d] =
            (y0[m] - mu0) * r0 * lng[e0 * D + d] + lnb[e0 * D + d] +
            (y1[m] - mu1) * r1 * lng[e1 * D + d] + lnb[e1 * D + d];
    }
}

// ---------------------------------------------------------------------------
extern "C" void kernel_launch(void* const* d_in, const int* in_sizes, int n_in,
                              void* d_out, int out_size, void* d_ws, size_t ws_size,
                              hipStream_t stream) {
    const float* x   = (const float*)d_in[0];
    const float* rw  = (const float*)d_in[1];
    const float* rb  = (const float*)d_in[2];
    const float* dgw = (const float*)d_in[3];
    const float* dgb = (const float*)d_in[4];
    const float* w1  = (const float*)d_in[5];
    const float* w1b = (const float*)d_in[6];
    const float* w2  = (const float*)d_in[7];
    const float* w2b = (const float*)d_in[8];
    const float* w3  = (const float*)d_in[9];
    const float* w3b = (const float*)d_in[10];
    const float* lng = (const float*)d_in[11];
    const float* lnb = (const float*)d_in[12];

    float* out = (float*)d_out;
    float* load_out = out + (size_t)T * D;

    char* w = (char*)d_ws;
    size_t off = 0;
    auto alloc = [&](size_t bytes) -> void* {
        void* p = w + off;
        off = (off + bytes + 255) & ~(size_t)255;
        return p;
    };
    int* counts   = (int*)alloc(8 * sizeof(int));
    int* bases    = (int*)alloc(9 * sizeof(int));
    int* cursor   = (int*)alloc(8 * sizeof(int));
    int* e_arr    = (int*)alloc(NPOS * sizeof(int));
    int* a_tok    = (int*)alloc(NPOS * sizeof(int));
    int* pos_of   = (int*)alloc(NPOS * sizeof(int));
    float* s_arr  = (float*)alloc(NPOS * sizeof(float));
    int* tme      = (int*)alloc(MAXTILE * sizeof(int));
    int* tmm      = (int*)alloc(MAXTILE * sizeof(int));
    int* tml      = (int*)alloc(MAXTILE * sizeof(int));
    unsigned char* xb  = (unsigned char*)alloc((size_t)T * D);
    unsigned char* w1t = (unsigned char*)alloc((size_t)E * D * FF);
    unsigned char* w3t = (unsigned char*)alloc((size_t)E * D * FF);
    unsigned char* w2t = (unsigned char*)alloc((size_t)E * D * FF);
    unsigned char* acts = (unsigned char*)alloc((size_t)(NPOS + 128) * FF);
    float* ffs    = (float*)alloc(2 * PSTRIDE * sizeof(float));

    (void)hipMemsetAsync(counts, 0, 8 * sizeof(int), stream);
    transpose_all<<<dim3(48, 6, 24), 256, 0, stream>>>(w1, w3, w2, w1t, w3t, w2t);
    router_kernel<<<T / 4, 256, 0, stream>>>(x, rw, rb, dgw, dgb, xb, e_arr, s_arr, counts);
    scan_kernel<<<1, 64, 0, stream>>>(counts, bases, cursor, load_out, tme, tmm, tml);
    assign_kernel<<<(T + 255) / 256, 256, 0, stream>>>(e_arr, cursor, a_tok, pos_of);
    gemm1_kernel<<<dim3(FF / 64, MAXTILE), 256, 0, stream>>>(
        xb, w1t, w1b, w3t, w3b, a_tok, tme, tmm, tml, acts);
    gemm2_kernel<<<dim3(D / 128, MAXTILE, 2), 256, 0, stream>>>(
        acts, w2t, tme, tmm, tml, ffs);
    combine_kernel<<<T, 256, 0, stream>>>(x, ffs, e_arr, pos_of, s_arr, w2b, lng, lnb, out);
}

// Round 10
// 219.759 us; speedup vs baseline: 1.3597x; 1.0078x over previous
//
#include <hip/hip_runtime.h>
#include <math.h>

#define T 2048
#define D 768
#define E 8
#define FF 3072
#define NPOS (2 * T)
#define MAXTILE 40
#define PSTRIDE ((size_t)(NPOS + 128) * D)

using f32x4 = __attribute__((ext_vector_type(4))) float;

template<bool HI>
__device__ __forceinline__ unsigned f2fp8pk(float a, float b, unsigned old) {
    return __builtin_amdgcn_cvt_pk_fp8_f32(a, b, (int)old, HI);
}
__device__ __forceinline__ unsigned char f2fp8(float f) {
    return (unsigned char)(__builtin_amdgcn_cvt_pk_fp8_f32(f, 0.f, 0, false) & 0xff);
}
__device__ __forceinline__ float siluf(float v) {
    return v / (1.0f + __expf(-v));
}
__device__ __forceinline__ void gload16(const void* g, void* l) {
    __builtin_amdgcn_global_load_lds(
        (const __attribute__((address_space(1))) void*)g,
        (__attribute__((address_space(3))) void*)l, 16, 0, 0);
}

// ---------------------------------------------------------------------------
// Fused transpose+convert all 3 weights: f32 [8][R][C] -> fp8 [8][C][R].
// Tile 128 rows x 128 cols: reads 512B/row (4 lines), writes 128B/row.
// LDS u32 packed-row words [128 cols][33]; 33-stride => bank=(c+w)%32.
// Also zeroes `counts` from block (0,0,0) (replaces a memset dispatch).
// ---------------------------------------------------------------------------
__global__ __launch_bounds__(256)
void transpose_all(const float* __restrict__ w1, const float* __restrict__ w3,
                   const float* __restrict__ w2,
                   unsigned char* __restrict__ w1t, unsigned char* __restrict__ w3t,
                   unsigned char* __restrict__ w2t,
                   int* __restrict__ counts) {
    __shared__ unsigned tbw[128][33];   // 16.9 KB
    int zi = blockIdx.z;
    const float* in; unsigned char* out; int R, C, r0, c0;
    if (zi < 16) {
        R = D; C = FF;
        int z = zi & 7;
        if (zi < 8) { in = w1 + (size_t)z * R * C; out = w1t + (size_t)z * R * C; }
        else        { in = w3 + (size_t)z * R * C; out = w3t + (size_t)z * R * C; }
        c0 = blockIdx.x * 128;            // 24 tiles over FF
        r0 = blockIdx.y * 128;            // 6 tiles over D
    } else {
        R = FF; C = D;
        int z = zi - 16;
        in = w2 + (size_t)z * R * C; out = w2t + (size_t)z * R * C;
        int idx = blockIdx.y * 24 + blockIdx.x;   // 0..143
        c0 = (idx % 6) * 128;             // 6 tiles over D
        r0 = (idx / 6) * 128;             // 24 tiles over FF
    }
    if (zi == 0 && blockIdx.x == 0 && blockIdx.y == 0 && threadIdx.x < 8)
        counts[threadIdx.x] = 0;

    int tid = threadIdx.x;
    int cb  = (tid & 31) * 4;             // col group 0..124
    int rgb = tid >> 5;                   // packed-word row base 0..7

    // phase 1: load 16 float4 (4 word-rows x 4 rows each), pack, LDS store
    float4 v[4][4];
#pragma unroll
    for (int p = 0; p < 4; ++p) {
        int rb = (rgb + 8 * p) * 4;
        const float* ip = in + (size_t)(r0 + rb) * C + c0 + cb;
        v[p][0] = *(const float4*)(ip);
        v[p][1] = *(const float4*)(ip + C);
        v[p][2] = *(const float4*)(ip + 2 * C);
        v[p][3] = *(const float4*)(ip + 3 * C);
    }
#pragma unroll
    for (int p = 0; p < 4; ++p) {
        int rg = rgb + 8 * p;
        unsigned pk;
        pk = f2fp8pk<false>(v[p][0].x, v[p][1].x, 0); pk = f2fp8pk<true>(v[p][2].x, v[p][3].x, pk);
        tbw[cb + 0][rg] = pk;
        pk = f2fp8pk<false>(v[p][0].y, v[p][1].y, 0); pk = f2fp8pk<true>(v[p][2].y, v[p][3].y, pk);
        tbw[cb + 1][rg] = pk;
        pk = f2fp8pk<false>(v[p][0].z, v[p][1].z, 0); pk = f2fp8pk<true>(v[p][2].z, v[p][3].z, pk);
        tbw[cb + 2][rg] = pk;
        pk = f2fp8pk<false>(v[p][0].w, v[p][1].w, 0); pk = f2fp8pk<true>(v[p][2].w, v[p][3].w, pk);
        tbw[cb + 3][rg] = pk;
    }
    __syncthreads();

    // phase 2: 8 lanes emit one 128B output line; 4 rows per thread
#pragma unroll
    for (int p = 0; p < 4; ++p) {
        int c  = (tid >> 3) + 32 * p;     // output row (input col) 0..127
        int gs = tid & 7;                 // 16B granule
        const unsigned* bp = &tbw[c][gs * 4];
        uint4 val;
        val.x = bp[0]; val.y = bp[1]; val.z = bp[2]; val.w = bp[3];
        *(uint4*)(out + (size_t)(c0 + c) * R + r0 + gs * 16) = val;
    }
}

// ---------------------------------------------------------------------------
// Router (+ fused x -> fp8 conversion). Routing math stays f32.
// ---------------------------------------------------------------------------
__global__ void router_kernel(const float* __restrict__ x,
                              const float* __restrict__ rw,
                              const float* __restrict__ rb,
                              const float* __restrict__ dgw,
                              const float* __restrict__ dgb,
                              unsigned char* __restrict__ xb,
                              int* __restrict__ e_arr,
                              float* __restrict__ s_arr,
                              int* __restrict__ counts) {
    int lane = threadIdx.x & 63;
    int wv = threadIdx.x >> 6;
    int t = blockIdx.x * 4 + wv;
    if (t >= T) return;

    float lg[E], dl[E];
#pragma unroll
    for (int e = 0; e < E; ++e) { lg[e] = 0.f; dl[e] = 0.f; }

    const float* xt = x + (size_t)t * D;
    unsigned char* xbt = xb + (size_t)t * D;
#pragma unroll
    for (int i = 0; i < D / 64; ++i) {
        int d = lane + 64 * i;
        float xv = xt[d];
        xbt[d] = f2fp8(xv);
#pragma unroll
        for (int e = 0; e < E; ++e) {
            lg[e] = fmaf(xv, rw[d * E + e], lg[e]);
            dl[e] = fmaf(xv, dgw[e * D + d], dl[e]);
        }
    }
#pragma unroll
    for (int e = 0; e < E; ++e) {
        for (int off = 32; off; off >>= 1) {
            lg[e] += __shfl_xor(lg[e], off);
            dl[e] += __shfl_xor(dl[e], off);
        }
    }
    if (lane == 0) {
        float p[E];
        float m = -1e30f;
#pragma unroll
        for (int e = 0; e < E; ++e) { lg[e] += rb[e]; m = fmaxf(m, lg[e]); }
        float s = 0.f;
#pragma unroll
        for (int e = 0; e < E; ++e) { p[e] = __expf(lg[e] - m); s += p[e]; }
        float inv = 1.0f / s;
#pragma unroll
        for (int e = 0; e < E; ++e) p[e] *= inv;

        int i0 = 0; float b0 = p[0];
#pragma unroll
        for (int e = 1; e < E; ++e) if (p[e] > b0) { b0 = p[e]; i0 = e; }
        int i1 = -1; float b1 = -1.0f;
#pragma unroll
        for (int e = 0; e < E; ++e) if (e != i0 && p[e] > b1) { b1 = p[e]; i1 = e; }

        float eb = __expf(b1 - b0);
        float w0 = 1.0f / (1.0f + eb);
        float w1 = eb / (1.0f + eb);

        float dg0 = 1.0f / (1.0f + __expf(-(dl[i0] + dgb[i0])));
        float dg1 = 1.0f / (1.0f + __expf(-(dl[i1] + dgb[i1])));

        e_arr[t * 2 + 0] = i0;
        e_arr[t * 2 + 1] = i1;
        s_arr[t * 2 + 0] = dg0 * w0;
        s_arr[t * 2 + 1] = dg1 * w1;
        atomicAdd(&counts[i0], 1);
        atomicAdd(&counts[i1], 1);
    }
}

// ---------------------------------------------------------------------------
// Scan + assign fused (single block): bases/cursor/load/tiles, then scatter
// ---------------------------------------------------------------------------
__global__ __launch_bounds__(256)
void scan_assign_kernel(const int* __restrict__ counts,
                        int* __restrict__ bases,
                        int* __restrict__ cursor,
                        float* __restrict__ load_out,
                        int* __restrict__ tme, int* __restrict__ tmm,
                        int* __restrict__ tml,
                        const int* __restrict__ e_arr,
                        int* __restrict__ a_tok,
                        int* __restrict__ pos_of) {
    if (threadIdx.x == 0) {
        int b = 0, nt = 0;
        for (int e = 0; e < E; ++e) {
            int c = counts[e];
            bases[e] = b;
            cursor[e] = b;
            load_out[e] = (float)c;
            for (int m = 0; m < c; m += 128) {
                tme[nt] = e;
                tmm[nt] = b + m;
                tml[nt] = (c - m < 128) ? (c - m) : 128;
                ++nt;
            }
            b += c;
        }
        bases[E] = b;
        for (; nt < MAXTILE; ++nt) tme[nt] = -1;
    }
    __syncthreads();
    for (int t = threadIdx.x; t < T; t += 256) {
#pragma unroll
        for (int s = 0; s < 2; ++s) {
            int e = e_arr[t * 2 + s];
            int pos = atomicAdd(&cursor[e], 1);
            a_tok[pos] = t;
            pos_of[t * 2 + s] = pos;
        }
    }
}

// ---------------------------------------------------------------------------
// GEMM1 (fp8): acts[pos][f] = fp8(silu(x@w1+b1)*silu(x@w3+b3)).
// Tile 128(M) x 64(F), K=768, BK=128 (6 steps), counted vmcnt(8), setprio.
// ---------------------------------------------------------------------------
__global__ __launch_bounds__(256, 2)
void gemm1_kernel(const unsigned char* __restrict__ xb,
                  const unsigned char* __restrict__ w1t, const float* __restrict__ w1b,
                  const unsigned char* __restrict__ w3t, const float* __restrict__ w3b,
                  const int* __restrict__ a_tok,
                  const int* __restrict__ tme, const int* __restrict__ tmm,
                  const int* __restrict__ tml,
                  unsigned char* __restrict__ acts) {
    int mt = blockIdx.y;
    int e = tme[mt];
    if (e < 0) return;
    int mstart = tmm[mt], mlen = tml[mt];
    int fBase = blockIdx.x * 64;

    __shared__ char As[2][16384];   // A: 128 rows x 128 B (BK=128 fp8)
    __shared__ char Bs[2][16384];   // [0,8K)=w1 64x128B, [8K,16K)=w3

    int tid = threadIdx.x;
    int lane = tid & 63, wv = tid >> 6;
    int wr = wv & 1, wc = wv >> 1;
    int l15 = lane & 15, lk = lane >> 4;
    int lrow = lane >> 3;
    int swl = (((lane & 7) ^ lrow) << 4);

    const char* xbp = (const char*)xb;
    size_t aoff[4];
#pragma unroll
    for (int i = 0; i < 4; ++i) {
        int r = (wv + 4 * i) * 8 + lrow;
        int rr = r < mlen ? r : mlen - 1;
        aoff[i] = (size_t)a_tok[mstart + rr] * D + swl;
    }
    const char* w1p = (const char*)(w1t + (size_t)e * FF * D);
    const char* w3p = (const char*)(w3t + (size_t)e * FF * D);
    size_t boff[2];
#pragma unroll
    for (int i = 0; i < 2; ++i) {
        int f = (wv + 4 * i) * 8 + lrow;
        boff[i] = (size_t)(fBase + f) * D + swl;
    }

    auto stage = [&](int buf, int ks) {
        int kb = ks * 128;
        char* ab = &As[buf][0];
        char* bb = &Bs[buf][0];
#pragma unroll
        for (int i = 0; i < 4; ++i)
            gload16(xbp + aoff[i] + kb, ab + (wv + 4 * i) * 1024);
#pragma unroll
        for (int i = 0; i < 2; ++i) {
            gload16(w1p + boff[i] + kb, bb + (wv + 4 * i) * 1024);
            gload16(w3p + boff[i] + kb, bb + 8192 + (wv + 4 * i) * 1024);
        }
    };

    f32x4 hacc[4][2], gacc[4][2];
#pragma unroll
    for (int m = 0; m < 4; ++m)
#pragma unroll
        for (int n = 0; n < 2; ++n) {
            hacc[m][n] = f32x4{0.f, 0.f, 0.f, 0.f};
            gacc[m][n] = f32x4{0.f, 0.f, 0.f, 0.f};
        }

    stage(0, 0);
    stage(1, 1);
#pragma unroll 1
    for (int ks = 0; ks < 6; ++ks) {
        int cur = ks & 1;
        if (ks < 5) asm volatile("s_waitcnt vmcnt(8)" ::: "memory");
        else        asm volatile("s_waitcnt vmcnt(0)" ::: "memory");
        __builtin_amdgcn_s_barrier();
        const char* Ab = &As[cur][0];
        const char* Bb = &Bs[cur][0];
        __builtin_amdgcn_s_setprio(1);
#pragma unroll
        for (int ksub = 0; ksub < 4; ++ksub) {
            int koff = ksub * 32 + lk * 8;
            long af[4];
#pragma unroll
            for (int m = 0; m < 4; ++m) {
                int row = wr * 64 + m * 16 + l15;
                af[m] = *(const long*)(Ab + row * 128 + (koff ^ ((row & 7) << 4)));
            }
#pragma unroll
            for (int n = 0; n < 2; ++n) {
                int rowf = wc * 32 + n * 16 + l15;
                int off = rowf * 128 + (koff ^ ((rowf & 7) << 4));
                long b1 = *(const long*)(Bb + off);
                long b3 = *(const long*)(Bb + 8192 + off);
#pragma unroll
                for (int m = 0; m < 4; ++m) {
                    hacc[m][n] = __builtin_amdgcn_mfma_f32_16x16x32_fp8_fp8(af[m], b1, hacc[m][n], 0, 0, 0);
                    gacc[m][n] = __builtin_amdgcn_mfma_f32_16x16x32_fp8_fp8(af[m], b3, gacc[m][n], 0, 0, 0);
                }
            }
        }
        __builtin_amdgcn_s_setprio(0);
        __builtin_amdgcn_s_barrier();
        if (ks < 4) stage(cur, ks + 2);
    }

    // epilogue: silu(h)*silu(g) -> fp8 tile in LDS -> vectorized store
    unsigned char* al = (unsigned char*)&As[0][0];   // 128 x 64 fp8 = 8 KB
    float b1v[2], b3v[2];
#pragma unroll
    for (int n = 0; n < 2; ++n) {
        int f = fBase + wc * 32 + n * 16 + l15;
        b1v[n] = w1b[e * FF + f];
        b3v[n] = w3b[e * FF + f];
    }
#pragma unroll
    for (int m = 0; m < 4; ++m)
#pragma unroll
        for (int n = 0; n < 2; ++n)
#pragma unroll
            for (int j = 0; j < 4; ++j) {
                float h = hacc[m][n][j] + b1v[n];
                float g = gacc[m][n][j] + b3v[n];
                int row = wr * 64 + m * 16 + lk * 4 + j;
                int col = wc * 32 + n * 16 + l15;
                al[row * 64 + col] = f2fp8(siluf(h) * siluf(g));
            }
    __syncthreads();
    int r = tid >> 1, cb = (tid & 1) * 32;
    if (r < mlen) {
        unsigned char* gp = acts + (size_t)(mstart + r) * FF + fBase + cb;
        const unsigned char* lp = al + r * 64 + cb;
        *(uint4*)(gp)      = *(const uint4*)(lp);
        *(uint4*)(gp + 16) = *(const uint4*)(lp + 16);
    }
}

// ---------------------------------------------------------------------------
// GEMM2 (fp8): ffs_part[ksl][pos][d] = acts[pos][kslice] @ w2[kslice], f32 out.
// Tile 128(M) x 128(N), split-K=2 (K=1536 each, BK=128 -> 12 steps).
// ---------------------------------------------------------------------------
__global__ __launch_bounds__(256, 2)
void gemm2_kernel(const unsigned char* __restrict__ acts,
                  const unsigned char* __restrict__ w2t,
                  const int* __restrict__ tme, const int* __restrict__ tmm,
                  const int* __restrict__ tml,
                  float* __restrict__ ffs) {
    int mt = blockIdx.y;
    int e = tme[mt];
    if (e < 0) return;
    int mstart = tmm[mt], mlen = tml[mt];
    int nBase = blockIdx.x * 128;
    int ksl = blockIdx.z;

    __shared__ char As[2][16384];
    __shared__ char Bs[2][16384];

    int tid = threadIdx.x;
    int lane = tid & 63, wv = tid >> 6;
    int wr = wv & 1, wc = wv >> 1;
    int l15 = lane & 15, lk = lane >> 4;
    int lrow = lane >> 3;
    int swl = (((lane & 7) ^ lrow) << 4);

    const char* ap = (const char*)acts;
    const char* w2p = (const char*)(w2t + (size_t)e * (size_t)D * FF);
    size_t aoff[4], boff[4];
#pragma unroll
    for (int i = 0; i < 4; ++i) {
        int r = (wv + 4 * i) * 8 + lrow;
        aoff[i] = (size_t)(mstart + r) * FF + swl;
        boff[i] = (size_t)(nBase + r) * FF + swl;
    }
    int kOff = ksl * (FF / 2);   // byte offset of this K slice (fp8)

    auto stage = [&](int buf, int ks) {
        int kb = kOff + ks * 128;
        char* ab = &As[buf][0];
        char* bb = &Bs[buf][0];
#pragma unroll
        for (int i = 0; i < 4; ++i) {
            gload16(ap + aoff[i] + kb, ab + (wv + 4 * i) * 1024);
            gload16(w2p + boff[i] + kb, bb + (wv + 4 * i) * 1024);
        }
    };

    f32x4 facc[4][4];
#pragma unroll
    for (int m = 0; m < 4; ++m)
#pragma unroll
        for (int n = 0; n < 4; ++n) facc[m][n] = f32x4{0.f, 0.f, 0.f, 0.f};

    stage(0, 0);
    stage(1, 1);
#pragma unroll 1
    for (int ks = 0; ks < 12; ++ks) {
        int cur = ks & 1;
        if (ks < 11) asm volatile("s_waitcnt vmcnt(8)" ::: "memory");
        else         asm volatile("s_waitcnt vmcnt(0)" ::: "memory");
        __builtin_amdgcn_s_barrier();
        const char* Ab = &As[cur][0];
        const char* Bb = &Bs[cur][0];
        __builtin_amdgcn_s_setprio(1);
#pragma unroll
        for (int ksub = 0; ksub < 4; ++ksub) {
            int koff = ksub * 32 + lk * 8;
            long af[4], bf[4];
#pragma unroll
            for (int m = 0; m < 4; ++m) {
                int row = wr * 64 + m * 16 + l15;
                af[m] = *(const long*)(Ab + row * 128 + (koff ^ ((row & 7) << 4)));
            }
#pragma unroll
            for (int n = 0; n < 4; ++n) {
                int row = wc * 64 + n * 16 + l15;
                bf[n] = *(const long*)(Bb + row * 128 + (koff ^ ((row & 7) << 4)));
            }
#pragma unroll
            for (int m = 0; m < 4; ++m)
#pragma unroll
                for (int n = 0; n < 4; ++n)
                    facc[m][n] = __builtin_amdgcn_mfma_f32_16x16x32_fp8_fp8(af[m], bf[n], facc[m][n], 0, 0, 0);
        }
        __builtin_amdgcn_s_setprio(0);
        __builtin_amdgcn_s_barrier();
        if (ks < 10) stage(cur, ks + 2);
    }

    float* op = ffs + (size_t)ksl * PSTRIDE;
#pragma unroll
    for (int m = 0; m < 4; ++m)
#pragma unroll
        for (int j = 0; j < 4; ++j) {
            int row = wr * 64 + m * 16 + lk * 4 + j;
            if (row < mlen) {
                float* gp = op + (size_t)(mstart + row) * D + nBase + wc * 64;
#pragma unroll
                for (int n = 0; n < 4; ++n)
                    gp[n * 16 + l15] = facc[m][n][j];
            }
        }
}

// ---------------------------------------------------------------------------
// Combine — f = part0 + part1 + w2b; y = x + s*f per slot; dual LN; sum; out
// ---------------------------------------------------------------------------
__global__ __launch_bounds__(256)
void combine_kernel(const float* __restrict__ x,
                    const float* __restrict__ ffs,
                    const int* __restrict__ e_arr,
                    const int* __restrict__ pos_of,
                    const float* __restrict__ s_arr,
                    const float* __restrict__ w2b,
                    const float* __restrict__ lng,
                    const float* __restrict__ lnb,
                    float* __restrict__ out) {
    int t = blockIdx.x;
    int tid = threadIdx.x;
    int p0 = pos_of[t * 2], p1 = pos_of[t * 2 + 1];
    int e0 = e_arr[t * 2], e1 = e_arr[t * 2 + 1];
    float sw0 = s_arr[t * 2], sw1 = s_arr[t * 2 + 1];
    __shared__ float red[4][4];

    float y0[3], y1[3];
    float s0 = 0.f, q0 = 0.f, s1 = 0.f, q1 = 0.f;
#pragma unroll
    for (int m = 0; m < 3; ++m) {
        int d = tid + 256 * m;
        float xv = x[(size_t)t * D + d];
        float f0 = ffs[(size_t)p0 * D + d] + ffs[PSTRIDE + (size_t)p0 * D + d] + w2b[e0 * D + d];
        float f1 = ffs[(size_t)p1 * D + d] + ffs[PSTRIDE + (size_t)p1 * D + d] + w2b[e1 * D + d];
        float a = xv + sw0 * f0;
        float bb = xv + sw1 * f1;
        y0[m] = a; y1[m] = bb;
        s0 += a; q0 += a * a;
        s1 += bb; q1 += bb * bb;
    }
    for (int off = 32; off; off >>= 1) {
        s0 += __shfl_xor(s0, off);
        q0 += __shfl_xor(q0, off);
        s1 += __shfl_xor(s1, off);
        q1 += __shfl_xor(q1, off);
    }
    int wv = tid >> 6, lane = tid & 63;
    if (lane == 0) { red[wv][0] = s0; red[wv][1] = q0; red[wv][2] = s1; red[wv][3] = q1; }
    __syncthreads();
    s0 = red[0][0] + red[1][0] + red[2][0] + red[3][0];
    q0 = red[0][1] + red[1][1] + red[2][1] + red[3][1];
    s1 = red[0][2] + red[1][2] + red[2][2] + red[3][2];
    q1 = red[0][3] + red[1][3] + red[2][3] + red[3][3];

    const float invD = 1.0f / (float)D;
    float mu0 = s0 * invD, var0 = q0 * invD - mu0 * mu0;
    float mu1 = s1 * invD, var1 = q1 * invD - mu1 * mu1;
    float r0 = rsqrtf(var0 + 1e-5f);
    float r1 = rsqrtf(var1 + 1e-5f);

#pragma unroll
    for (int m = 0; m < 3; ++m) {
        int d = tid + 256 * m;
        out[(size_t)t * D + d] =
            (y0[m] - mu0) * r0 * lng[e0 * D + d] + lnb[e0 * D + d] +
            (y1[m] - mu1) * r1 * lng[e1 * D + d] + lnb[e1 * D + d];
    }
}

// ---------------------------------------------------------------------------
extern "C" void kernel_launch(void* const* d_in, const int* in_sizes, int n_in,
                              void* d_out, int out_size, void* d_ws, size_t ws_size,
                              hipStream_t stream) {
    const float* x   = (const float*)d_in[0];
    const float* rw  = (const float*)d_in[1];
    const float* rb  = (const float*)d_in[2];
    const float* dgw = (const float*)d_in[3];
    const float* dgb = (const float*)d_in[4];
    const float* w1  = (const float*)d_in[5];
    const float* w1b = (const float*)d_in[6];
    const float* w2  = (const float*)d_in[7];
    const float* w2b = (const float*)d_in[8];
    const float* w3  = (const float*)d_in[9];
    const float* w3b = (const float*)d_in[10];
    const float* lng = (const float*)d_in[11];
    const float* lnb = (const float*)d_in[12];

    float* out = (float*)d_out;
    float* load_out = out + (size_t)T * D;

    char* w = (char*)d_ws;
    size_t off = 0;
    auto alloc = [&](size_t bytes) -> void* {
        void* p = w + off;
        off = (off + bytes + 255) & ~(size_t)255;
        return p;
    };
    int* counts   = (int*)alloc(8 * sizeof(int));
    int* bases    = (int*)alloc(9 * sizeof(int));
    int* cursor   = (int*)alloc(8 * sizeof(int));
    int* e_arr    = (int*)alloc(NPOS * sizeof(int));
    int* a_tok    = (int*)alloc(NPOS * sizeof(int));
    int* pos_of   = (int*)alloc(NPOS * sizeof(int));
    float* s_arr  = (float*)alloc(NPOS * sizeof(float));
    int* tme      = (int*)alloc(MAXTILE * sizeof(int));
    int* tmm      = (int*)alloc(MAXTILE * sizeof(int));
    int* tml      = (int*)alloc(MAXTILE * sizeof(int));
    unsigned char* xb  = (unsigned char*)alloc((size_t)T * D);
    unsigned char* w1t = (unsigned char*)alloc((size_t)E * D * FF);
    unsigned char* w3t = (unsigned char*)alloc((size_t)E * D * FF);
    unsigned char* w2t = (unsigned char*)alloc((size_t)E * D * FF);
    unsigned char* acts = (unsigned char*)alloc((size_t)(NPOS + 128) * FF);
    float* ffs    = (float*)alloc(2 * PSTRIDE * sizeof(float));

    transpose_all<<<dim3(24, 6, 24), 256, 0, stream>>>(w1, w3, w2, w1t, w3t, w2t, counts);
    router_kernel<<<T / 4, 256, 0, stream>>>(x, rw, rb, dgw, dgb, xb, e_arr, s_arr, counts);
    scan_assign_kernel<<<1, 256, 0, stream>>>(counts, bases, cursor, load_out,
                                              tme, tmm, tml, e_arr, a_tok, pos_of);
    gemm1_kernel<<<dim3(FF / 64, MAXTILE), 256, 0, stream>>>(
        xb, w1t, w1b, w3t, w3b, a_tok, tme, tmm, tml, acts);
    gemm2_kernel<<<dim3(D / 128, MAXTILE, 2), 256, 0, stream>>>(
        acts, w2t, tme, tmm, tml, ffs);
    combine_kernel<<<T, 256, 0, stream>>>(x, ffs, e_arr, pos_of, s_arr, w2b, lng, lnb, out);
}

// Round 11
// 153.404 us; speedup vs baseline: 1.9478x; 1.4325x over previous
//
#include <hip/hip_runtime.h>
#include <math.h>

#define T 2048
#define D 768
#define E 8
#define FF 3072
#define NPOS (2 * T)
#define MAXTILE 40
#define PSTRIDE ((size_t)(NPOS + 128) * D)

using f32x4 = __attribute__((ext_vector_type(4))) float;

template<bool HI>
__device__ __forceinline__ unsigned f2fp8pk(float a, float b, unsigned old) {
    return __builtin_amdgcn_cvt_pk_fp8_f32(a, b, (int)old, HI);
}
__device__ __forceinline__ unsigned char f2fp8(float f) {
    return (unsigned char)(__builtin_amdgcn_cvt_pk_fp8_f32(f, 0.f, 0, false) & 0xff);
}
__device__ __forceinline__ float siluf(float v) {
    return v / (1.0f + __expf(-v));
}
__device__ __forceinline__ void gload16(const void* g, void* l) {
    __builtin_amdgcn_global_load_lds(
        (const __attribute__((address_space(1))) void*)g,
        (__attribute__((address_space(3))) void*)l, 16, 0, 0);
}

// ---------------------------------------------------------------------------
// transpose128: one 128x128 f32 tile -> fp8 transposed, via gload_lds staging.
// in: rows (r0..r0+127) x cols (c0..c0+127) of [*][C] f32.
// out: row (c0+c) has byte stride Rb; writes bytes [r0, r0+128) per row.
// smem: 64KB. Stage f32 (async DMA, full MLP) -> convert+pack -> line stores.
// ---------------------------------------------------------------------------
__device__ __forceinline__ void transpose128(const float* __restrict__ in,
                                             unsigned char* __restrict__ out,
                                             int C, int Rb, int r0, int c0,
                                             char* smem, int tid) {
    int wv = tid >> 6, lane = tid & 63;
    size_t rowB = (size_t)C * 4;
    const char* inb = (const char*)in + (size_t)r0 * rowB + (size_t)c0 * 4;
    const char* src_lane = inb + (size_t)(lane >> 5) * rowB + (lane & 31) * 16;
#pragma unroll
    for (int i = 0; i < 16; ++i) {
        int rpair = i * 4 + wv;
        gload16(src_lane + (size_t)(2 * rpair) * rowB, smem + rpair * 1024);
    }
    asm volatile("s_waitcnt vmcnt(0)" ::: "memory");
    __syncthreads();

    const float* fin = (const float*)smem;
    int cb = (tid & 31) * 4;
    int rgb = tid >> 5;
    unsigned pk[4][4];
#pragma unroll
    for (int p = 0; p < 4; ++p) {
        int rb = (rgb + 8 * p) * 4;
        float4 q0 = *(const float4*)(fin + (rb + 0) * 128 + cb);
        float4 q1 = *(const float4*)(fin + (rb + 1) * 128 + cb);
        float4 q2 = *(const float4*)(fin + (rb + 2) * 128 + cb);
        float4 q3 = *(const float4*)(fin + (rb + 3) * 128 + cb);
        unsigned w;
        w = f2fp8pk<false>(q0.x, q1.x, 0); w = f2fp8pk<true>(q2.x, q3.x, w); pk[p][0] = w;
        w = f2fp8pk<false>(q0.y, q1.y, 0); w = f2fp8pk<true>(q2.y, q3.y, w); pk[p][1] = w;
        w = f2fp8pk<false>(q0.z, q1.z, 0); w = f2fp8pk<true>(q2.z, q3.z, w); pk[p][2] = w;
        w = f2fp8pk<false>(q0.w, q1.w, 0); w = f2fp8pk<true>(q2.w, q3.w, w); pk[p][3] = w;
    }
    __syncthreads();   // all fin reads complete before packed region overwrite
    unsigned* po = (unsigned*)smem;    // [128 cols][33 words]
#pragma unroll
    for (int p = 0; p < 4; ++p) {
        int rg = rgb + 8 * p;
#pragma unroll
        for (int j = 0; j < 4; ++j)
            po[(cb + j) * 33 + rg] = pk[p][j];
    }
    __syncthreads();
#pragma unroll
    for (int p = 0; p < 4; ++p) {
        int c = (tid >> 3) + 32 * p;
        int gs = tid & 7;
        const unsigned* bp = &po[c * 33 + gs * 4];
        uint4 val;
        val.x = bp[0]; val.y = bp[1]; val.z = bp[2]; val.w = bp[3];
        *(uint4*)(out + (size_t)(c0 + c) * Rb + r0 + gs * 16) = val;
    }
}

// ---------------------------------------------------------------------------
// Dispatch 1: router blocks [0,512) + w1/w3 transpose blocks [512, 2816)
// ---------------------------------------------------------------------------
__global__ __launch_bounds__(256, 2)
void pre_kernel(const float* __restrict__ x,
                const float* __restrict__ rw, const float* __restrict__ rbias,
                const float* __restrict__ dgw, const float* __restrict__ dgb,
                const float* __restrict__ w1, const float* __restrict__ w3,
                unsigned char* __restrict__ xb,
                int* __restrict__ e_arr, float* __restrict__ s_arr,
                unsigned char* __restrict__ w1t, unsigned char* __restrict__ w3t) {
    __shared__ __align__(16) char smem[65536];
    int bid = blockIdx.x;
    int tid = threadIdx.x;

    if (bid >= 512) {
        int idx = bid - 512;            // 0..2303
        int z = idx / 144;              // 0..15
        int rem = idx % 144;
        int r0 = (rem % 6) * 128;       // over D
        int c0 = (rem / 6) * 128;       // over FF
        const float* in;
        unsigned char* outp;
        if (z < 8) { in = w1 + (size_t)z * D * FF; outp = w1t + (size_t)z * D * FF; }
        else       { in = w3 + (size_t)(z - 8) * D * FF; outp = w3t + (size_t)(z - 8) * D * FF; }
        transpose128(in, outp, FF, D, r0, c0, smem, tid);
        return;
    }

    // ---- router flavor ----
    int lane = tid & 63;
    int wv = tid >> 6;
    int t = bid * 4 + wv;

    float lg[E], dl[E];
#pragma unroll
    for (int e = 0; e < E; ++e) { lg[e] = 0.f; dl[e] = 0.f; }

    const float* xt = x + (size_t)t * D;
    unsigned char* xbt = xb + (size_t)t * D;
#pragma unroll
    for (int i = 0; i < D / 64; ++i) {
        int d = lane + 64 * i;
        float xv = xt[d];
        xbt[d] = f2fp8(xv);
#pragma unroll
        for (int e = 0; e < E; ++e) {
            lg[e] = fmaf(xv, rw[d * E + e], lg[e]);
            dl[e] = fmaf(xv, dgw[e * D + d], dl[e]);
        }
    }
#pragma unroll
    for (int e = 0; e < E; ++e) {
        for (int off = 32; off; off >>= 1) {
            lg[e] += __shfl_xor(lg[e], off);
            dl[e] += __shfl_xor(dl[e], off);
        }
    }
    if (lane == 0) {
        float p[E];
        float m = -1e30f;
#pragma unroll
        for (int e = 0; e < E; ++e) { lg[e] += rbias[e]; m = fmaxf(m, lg[e]); }
        float s = 0.f;
#pragma unroll
        for (int e = 0; e < E; ++e) { p[e] = __expf(lg[e] - m); s += p[e]; }
        float inv = 1.0f / s;
#pragma unroll
        for (int e = 0; e < E; ++e) p[e] *= inv;

        int i0 = 0; float b0 = p[0];
#pragma unroll
        for (int e = 1; e < E; ++e) if (p[e] > b0) { b0 = p[e]; i0 = e; }
        int i1 = -1; float b1 = -1.0f;
#pragma unroll
        for (int e = 0; e < E; ++e) if (e != i0 && p[e] > b1) { b1 = p[e]; i1 = e; }

        float eb = __expf(b1 - b0);
        float w0 = 1.0f / (1.0f + eb);
        float w1v = eb / (1.0f + eb);

        float dg0 = 1.0f / (1.0f + __expf(-(dl[i0] + dgb[i0])));
        float dg1 = 1.0f / (1.0f + __expf(-(dl[i1] + dgb[i1])));

        e_arr[t * 2 + 0] = i0;
        e_arr[t * 2 + 1] = i1;
        s_arr[t * 2 + 0] = dg0 * w0;
        s_arr[t * 2 + 1] = dg1 * w1v;
    }
}

// ---------------------------------------------------------------------------
// Dispatch 2: scan+assign, counts computed in-LDS from e_arr (no global counts)
// ---------------------------------------------------------------------------
__global__ __launch_bounds__(256)
void scan_assign_kernel(const int* __restrict__ e_arr,
                        float* __restrict__ load_out,
                        int* __restrict__ tme, int* __restrict__ tmm,
                        int* __restrict__ tml,
                        int* __restrict__ a_tok,
                        int* __restrict__ pos_of) {
    __shared__ int lcnt[E];
    __shared__ int lcur[E];
    int tid = threadIdx.x;
    if (tid < E) lcnt[tid] = 0;
    __syncthreads();
    for (int t = tid; t < T; t += 256) {
        atomicAdd(&lcnt[e_arr[t * 2]], 1);
        atomicAdd(&lcnt[e_arr[t * 2 + 1]], 1);
    }
    __syncthreads();
    if (tid == 0) {
        int b = 0, nt = 0;
        for (int e = 0; e < E; ++e) {
            int c = lcnt[e];
            lcur[e] = b;
            load_out[e] = (float)c;
            for (int m = 0; m < c; m += 128) {
                tme[nt] = e;
                tmm[nt] = b + m;
                tml[nt] = (c - m < 128) ? (c - m) : 128;
                ++nt;
            }
            b += c;
        }
        for (; nt < MAXTILE; ++nt) tme[nt] = -1;
    }
    __syncthreads();
    for (int t = tid; t < T; t += 256) {
#pragma unroll
        for (int s = 0; s < 2; ++s) {
            int e = e_arr[t * 2 + s];
            int pos = atomicAdd(&lcur[e], 1);
            a_tok[pos] = t;
            pos_of[t * 2 + s] = pos;
        }
    }
}

// ---------------------------------------------------------------------------
// Dispatch 3: w2 transpose blocks [0,1152) + GEMM1 blocks [1152, 3072)
// GEMM1 (fp8): acts = fp8(silu(x@w1+b1)*silu(x@w3+b3)); 128x64 tile, BK=128.
// ---------------------------------------------------------------------------
__global__ __launch_bounds__(256, 2)
void gemm1_w2t_kernel(const float* __restrict__ w2, unsigned char* __restrict__ w2t,
                      const unsigned char* __restrict__ xb,
                      const unsigned char* __restrict__ w1t, const float* __restrict__ w1b,
                      const unsigned char* __restrict__ w3t, const float* __restrict__ w3b,
                      const int* __restrict__ a_tok,
                      const int* __restrict__ tme, const int* __restrict__ tmm,
                      const int* __restrict__ tml,
                      unsigned char* __restrict__ acts) {
    __shared__ __align__(16) char smem[65536];
    int bid = blockIdx.x;
    int tid = threadIdx.x;

    if (bid < 1152) {   // w2 transpose: [FF][D] f32 -> [D][FF] fp8
        int z = bid / 144;
        int rem = bid % 144;
        int r0 = (rem % 24) * 128;      // over FF
        int c0 = (rem / 24) * 128;      // over D
        transpose128(w2 + (size_t)z * FF * D, w2t + (size_t)z * FF * D,
                     D, FF, r0, c0, smem, tid);
        return;
    }

    int g = bid - 1152;
    int mt = g / 48;
    int e = tme[mt];
    if (e < 0) return;
    int mstart = tmm[mt], mlen = tml[mt];
    int fBase = (g % 48) * 64;

    char (*As)[16384] = (char(*)[16384])smem;
    char (*Bs)[16384] = (char(*)[16384])(smem + 32768);

    int lane = tid & 63, wv = tid >> 6;
    int wr = wv & 1, wc = wv >> 1;
    int l15 = lane & 15, lk = lane >> 4;
    int lrow = lane >> 3;
    int swl = (((lane & 7) ^ lrow) << 4);

    const char* xbp = (const char*)xb;
    size_t aoff[4];
#pragma unroll
    for (int i = 0; i < 4; ++i) {
        int r = (wv + 4 * i) * 8 + lrow;
        int rr = r < mlen ? r : mlen - 1;
        aoff[i] = (size_t)a_tok[mstart + rr] * D + swl;
    }
    const char* w1p = (const char*)(w1t + (size_t)e * FF * D);
    const char* w3p = (const char*)(w3t + (size_t)e * FF * D);
    size_t boff[2];
#pragma unroll
    for (int i = 0; i < 2; ++i) {
        int f = (wv + 4 * i) * 8 + lrow;
        boff[i] = (size_t)(fBase + f) * D + swl;
    }

    auto stage = [&](int buf, int ks) {
        int kb = ks * 128;
        char* ab = &As[buf][0];
        char* bb = &Bs[buf][0];
#pragma unroll
        for (int i = 0; i < 4; ++i)
            gload16(xbp + aoff[i] + kb, ab + (wv + 4 * i) * 1024);
#pragma unroll
        for (int i = 0; i < 2; ++i) {
            gload16(w1p + boff[i] + kb, bb + (wv + 4 * i) * 1024);
            gload16(w3p + boff[i] + kb, bb + 8192 + (wv + 4 * i) * 1024);
        }
    };

    f32x4 hacc[4][2], gacc[4][2];
#pragma unroll
    for (int m = 0; m < 4; ++m)
#pragma unroll
        for (int n = 0; n < 2; ++n) {
            hacc[m][n] = f32x4{0.f, 0.f, 0.f, 0.f};
            gacc[m][n] = f32x4{0.f, 0.f, 0.f, 0.f};
        }

    stage(0, 0);
    stage(1, 1);
#pragma unroll 1
    for (int ks = 0; ks < 6; ++ks) {
        int cur = ks & 1;
        if (ks < 5) asm volatile("s_waitcnt vmcnt(8)" ::: "memory");
        else        asm volatile("s_waitcnt vmcnt(0)" ::: "memory");
        __builtin_amdgcn_s_barrier();
        const char* Ab = &As[cur][0];
        const char* Bb = &Bs[cur][0];
        __builtin_amdgcn_s_setprio(1);
#pragma unroll
        for (int ksub = 0; ksub < 4; ++ksub) {
            int koff = ksub * 32 + lk * 8;
            long af[4];
#pragma unroll
            for (int m = 0; m < 4; ++m) {
                int row = wr * 64 + m * 16 + l15;
                af[m] = *(const long*)(Ab + row * 128 + (koff ^ ((row & 7) << 4)));
            }
#pragma unroll
            for (int n = 0; n < 2; ++n) {
                int rowf = wc * 32 + n * 16 + l15;
                int off = rowf * 128 + (koff ^ ((rowf & 7) << 4));
                long b1 = *(const long*)(Bb + off);
                long b3 = *(const long*)(Bb + 8192 + off);
#pragma unroll
                for (int m = 0; m < 4; ++m) {
                    hacc[m][n] = __builtin_amdgcn_mfma_f32_16x16x32_fp8_fp8(af[m], b1, hacc[m][n], 0, 0, 0);
                    gacc[m][n] = __builtin_amdgcn_mfma_f32_16x16x32_fp8_fp8(af[m], b3, gacc[m][n], 0, 0, 0);
                }
            }
        }
        __builtin_amdgcn_s_setprio(0);
        __builtin_amdgcn_s_barrier();
        if (ks < 4) stage(cur, ks + 2);
    }

    unsigned char* al = (unsigned char*)&As[0][0];
    float b1v[2], b3v[2];
#pragma unroll
    for (int n = 0; n < 2; ++n) {
        int f = fBase + wc * 32 + n * 16 + l15;
        b1v[n] = w1b[e * FF + f];
        b3v[n] = w3b[e * FF + f];
    }
#pragma unroll
    for (int m = 0; m < 4; ++m)
#pragma unroll
        for (int n = 0; n < 2; ++n)
#pragma unroll
            for (int j = 0; j < 4; ++j) {
                float h = hacc[m][n][j] + b1v[n];
                float gg = gacc[m][n][j] + b3v[n];
                int row = wr * 64 + m * 16 + lk * 4 + j;
                int col = wc * 32 + n * 16 + l15;
                al[row * 64 + col] = f2fp8(siluf(h) * siluf(gg));
            }
    __syncthreads();
    int r = tid >> 1, cb = (tid & 1) * 32;
    if (r < mlen) {
        unsigned char* gp = acts + (size_t)(mstart + r) * FF + fBase + cb;
        const unsigned char* lp = al + r * 64 + cb;
        *(uint4*)(gp)      = *(const uint4*)(lp);
        *(uint4*)(gp + 16) = *(const uint4*)(lp + 16);
    }
}

// ---------------------------------------------------------------------------
// GEMM2 (fp8): 128x128 tile, split-K=2, BK=128 -> 12 steps. Unchanged.
// ---------------------------------------------------------------------------
__global__ __launch_bounds__(256, 2)
void gemm2_kernel(const unsigned char* __restrict__ acts,
                  const unsigned char* __restrict__ w2t,
                  const int* __restrict__ tme, const int* __restrict__ tmm,
                  const int* __restrict__ tml,
                  float* __restrict__ ffs) {
    int mt = blockIdx.y;
    int e = tme[mt];
    if (e < 0) return;
    int mstart = tmm[mt], mlen = tml[mt];
    int nBase = blockIdx.x * 128;
    int ksl = blockIdx.z;

    __shared__ char As[2][16384];
    __shared__ char Bs[2][16384];

    int tid = threadIdx.x;
    int lane = tid & 63, wv = tid >> 6;
    int wr = wv & 1, wc = wv >> 1;
    int l15 = lane & 15, lk = lane >> 4;
    int lrow = lane >> 3;
    int swl = (((lane & 7) ^ lrow) << 4);

    const char* ap = (const char*)acts;
    const char* w2p = (const char*)(w2t + (size_t)e * (size_t)D * FF);
    size_t aoff[4], boff[4];
#pragma unroll
    for (int i = 0; i < 4; ++i) {
        int r = (wv + 4 * i) * 8 + lrow;
        aoff[i] = (size_t)(mstart + r) * FF + swl;
        boff[i] = (size_t)(nBase + r) * FF + swl;
    }
    int kOff = ksl * (FF / 2);

    auto stage = [&](int buf, int ks) {
        int kb = kOff + ks * 128;
        char* ab = &As[buf][0];
        char* bb = &Bs[buf][0];
#pragma unroll
        for (int i = 0; i < 4; ++i) {
            gload16(ap + aoff[i] + kb, ab + (wv + 4 * i) * 1024);
            gload16(w2p + boff[i] + kb, bb + (wv + 4 * i) * 1024);
        }
    };

    f32x4 facc[4][4];
#pragma unroll
    for (int m = 0; m < 4; ++m)
#pragma unroll
        for (int n = 0; n < 4; ++n) facc[m][n] = f32x4{0.f, 0.f, 0.f, 0.f};

    stage(0, 0);
    stage(1, 1);
#pragma unroll 1
    for (int ks = 0; ks < 12; ++ks) {
        int cur = ks & 1;
        if (ks < 11) asm volatile("s_waitcnt vmcnt(8)" ::: "memory");
        else         asm volatile("s_waitcnt vmcnt(0)" ::: "memory");
        __builtin_amdgcn_s_barrier();
        const char* Ab = &As[cur][0];
        const char* Bb = &Bs[cur][0];
        __builtin_amdgcn_s_setprio(1);
#pragma unroll
        for (int ksub = 0; ksub < 4; ++ksub) {
            int koff = ksub * 32 + lk * 8;
            long af[4], bf[4];
#pragma unroll
            for (int m = 0; m < 4; ++m) {
                int row = wr * 64 + m * 16 + l15;
                af[m] = *(const long*)(Ab + row * 128 + (koff ^ ((row & 7) << 4)));
            }
#pragma unroll
            for (int n = 0; n < 4; ++n) {
                int row = wc * 64 + n * 16 + l15;
                bf[n] = *(const long*)(Bb + row * 128 + (koff ^ ((row & 7) << 4)));
            }
#pragma unroll
            for (int m = 0; m < 4; ++m)
#pragma unroll
                for (int n = 0; n < 4; ++n)
                    facc[m][n] = __builtin_amdgcn_mfma_f32_16x16x32_fp8_fp8(af[m], bf[n], facc[m][n], 0, 0, 0);
        }
        __builtin_amdgcn_s_setprio(0);
        __builtin_amdgcn_s_barrier();
        if (ks < 10) stage(cur, ks + 2);
    }

    float* op = ffs + (size_t)ksl * PSTRIDE;
#pragma unroll
    for (int m = 0; m < 4; ++m)
#pragma unroll
        for (int j = 0; j < 4; ++j) {
            int row = wr * 64 + m * 16 + lk * 4 + j;
            if (row < mlen) {
                float* gp = op + (size_t)(mstart + row) * D + nBase + wc * 64;
#pragma unroll
                for (int n = 0; n < 4; ++n)
                    gp[n * 16 + l15] = facc[m][n][j];
            }
        }
}

// ---------------------------------------------------------------------------
// Combine — unchanged
// ---------------------------------------------------------------------------
__global__ __launch_bounds__(256)
void combine_kernel(const float* __restrict__ x,
                    const float* __restrict__ ffs,
                    const int* __restrict__ e_arr,
                    const int* __restrict__ pos_of,
                    const float* __restrict__ s_arr,
                    const float* __restrict__ w2b,
                    const float* __restrict__ lng,
                    const float* __restrict__ lnb,
                    float* __restrict__ out) {
    int t = blockIdx.x;
    int tid = threadIdx.x;
    int p0 = pos_of[t * 2], p1 = pos_of[t * 2 + 1];
    int e0 = e_arr[t * 2], e1 = e_arr[t * 2 + 1];
    float sw0 = s_arr[t * 2], sw1 = s_arr[t * 2 + 1];
    __shared__ float red[4][4];

    float y0[3], y1[3];
    float s0 = 0.f, q0 = 0.f, s1 = 0.f, q1 = 0.f;
#pragma unroll
    for (int m = 0; m < 3; ++m) {
        int d = tid + 256 * m;
        float xv = x[(size_t)t * D + d];
        float f0 = ffs[(size_t)p0 * D + d] + ffs[PSTRIDE + (size_t)p0 * D + d] + w2b[e0 * D + d];
        float f1 = ffs[(size_t)p1 * D + d] + ffs[PSTRIDE + (size_t)p1 * D + d] + w2b[e1 * D + d];
        float a = xv + sw0 * f0;
        float bb = xv + sw1 * f1;
        y0[m] = a; y1[m] = bb;
        s0 += a; q0 += a * a;
        s1 += bb; q1 += bb * bb;
    }
    for (int off = 32; off; off >>= 1) {
        s0 += __shfl_xor(s0, off);
        q0 += __shfl_xor(q0, off);
        s1 += __shfl_xor(s1, off);
        q1 += __shfl_xor(q1, off);
    }
    int wv = tid >> 6, lane = tid & 63;
    if (lane == 0) { red[wv][0] = s0; red[wv][1] = q0; red[wv][2] = s1; red[wv][3] = q1; }
    __syncthreads();
    s0 = red[0][0] + red[1][0] + red[2][0] + red[3][0];
    q0 = red[0][1] + red[1][1] + red[2][1] + red[3][1];
    s1 = red[0][2] + red[1][2] + red[2][2] + red[3][2];
    q1 = red[0][3] + red[1][3] + red[2][3] + red[3][3];

    const float invD = 1.0f / (float)D;
    float mu0 = s0 * invD, var0 = q0 * invD - mu0 * mu0;
    float mu1 = s1 * invD, var1 = q1 * invD - mu1 * mu1;
    float r0 = rsqrtf(var0 + 1e-5f);
    float r1 = rsqrtf(var1 + 1e-5f);

#pragma unroll
    for (int m = 0; m < 3; ++m) {
        int d = tid + 256 * m;
        out[(size_t)t * D + d] =
            (y0[m] - mu0) * r0 * lng[e0 * D + d] + lnb[e0 * D + d] +
            (y1[m] - mu1) * r1 * lng[e1 * D + d] + lnb[e1 * D + d];
    }
}

// ---------------------------------------------------------------------------
extern "C" void kernel_launch(void* const* d_in, const int* in_sizes, int n_in,
                              void* d_out, int out_size, void* d_ws, size_t ws_size,
                              hipStream_t stream) {
    const float* x   = (const float*)d_in[0];
    const float* rw  = (const float*)d_in[1];
    const float* rb  = (const float*)d_in[2];
    const float* dgw = (const float*)d_in[3];
    const float* dgb = (const float*)d_in[4];
    const float* w1  = (const float*)d_in[5];
    const float* w1b = (const float*)d_in[6];
    const float* w2  = (const float*)d_in[7];
    const float* w2b = (const float*)d_in[8];
    const float* w3  = (const float*)d_in[9];
    const float* w3b = (const float*)d_in[10];
    const float* lng = (const float*)d_in[11];
    const float* lnb = (const float*)d_in[12];

    float* out = (float*)d_out;
    float* load_out = out + (size_t)T * D;

    char* w = (char*)d_ws;
    size_t off = 0;
    auto alloc = [&](size_t bytes) -> void* {
        void* p = w + off;
        off = (off + bytes + 255) & ~(size_t)255;
        return p;
    };
    int* e_arr    = (int*)alloc(NPOS * sizeof(int));
    int* a_tok    = (int*)alloc(NPOS * sizeof(int));
    int* pos_of   = (int*)alloc(NPOS * sizeof(int));
    float* s_arr  = (float*)alloc(NPOS * sizeof(float));
    int* tme      = (int*)alloc(MAXTILE * sizeof(int));
    int* tmm      = (int*)alloc(MAXTILE * sizeof(int));
    int* tml      = (int*)alloc(MAXTILE * sizeof(int));
    unsigned char* xb  = (unsigned char*)alloc((size_t)T * D);
    unsigned char* w1t = (unsigned char*)alloc((size_t)E * D * FF);
    unsigned char* w3t = (unsigned char*)alloc((size_t)E * D * FF);
    unsigned char* w2t = (unsigned char*)alloc((size_t)E * D * FF);
    unsigned char* acts = (unsigned char*)alloc((size_t)(NPOS + 128) * FF);
    float* ffs    = (float*)alloc(2 * PSTRIDE * sizeof(float));

    pre_kernel<<<512 + 2304, 256, 0, stream>>>(x, rw, rb, dgw, dgb, w1, w3,
                                               xb, e_arr, s_arr, w1t, w3t);
    scan_assign_kernel<<<1, 256, 0, stream>>>(e_arr, load_out, tme, tmm, tml,
                                              a_tok, pos_of);
    gemm1_w2t_kernel<<<1152 + 1920, 256, 0, stream>>>(
        w2, w2t, xb, w1t, w1b, w3t, w3b, a_tok, tme, tmm, tml, acts);
    gemm2_kernel<<<dim3(D / 128, MAXTILE, 2), 256, 0, stream>>>(
        acts, w2t, tme, tmm, tml, ffs);
    combine_kernel<<<T, 256, 0, stream>>>(x, ffs, e_arr, pos_of, s_arr, w2b, lng, lnb, out);
}

// Round 12
// 148.275 us; speedup vs baseline: 2.0152x; 1.0346x over previous
//
#include <hip/hip_runtime.h>
#include <math.h>

#define T 2048
#define D 768
#define E 8
#define FF 3072
#define NPOS (2 * T)
#define MAXTILE 40
#define PSTRIDE ((size_t)(NPOS + 128) * D)

using f32x4 = __attribute__((ext_vector_type(4))) float;

template<bool HI>
__device__ __forceinline__ unsigned f2fp8pk(float a, float b, unsigned old) {
    return __builtin_amdgcn_cvt_pk_fp8_f32(a, b, (int)old, HI);
}
__device__ __forceinline__ unsigned char f2fp8(float f) {
    return (unsigned char)(__builtin_amdgcn_cvt_pk_fp8_f32(f, 0.f, 0, false) & 0xff);
}
__device__ __forceinline__ float siluf(float v) {
    return v / (1.0f + __expf(-v));
}
__device__ __forceinline__ void gload16(const void* g, void* l) {
    __builtin_amdgcn_global_load_lds(
        (const __attribute__((address_space(1))) void*)g,
        (__attribute__((address_space(3))) void*)l, 16, 0, 0);
}

// ---------------------------------------------------------------------------
// transpose128: one 128x128 f32 tile -> fp8 transposed, via gload_lds staging.
// ---------------------------------------------------------------------------
__device__ __forceinline__ void transpose128(const float* __restrict__ in,
                                             unsigned char* __restrict__ out,
                                             int C, int Rb, int r0, int c0,
                                             char* smem, int tid) {
    int wv = tid >> 6, lane = tid & 63;
    size_t rowB = (size_t)C * 4;
    const char* inb = (const char*)in + (size_t)r0 * rowB + (size_t)c0 * 4;
    const char* src_lane = inb + (size_t)(lane >> 5) * rowB + (lane & 31) * 16;
#pragma unroll
    for (int i = 0; i < 16; ++i) {
        int rpair = i * 4 + wv;
        gload16(src_lane + (size_t)(2 * rpair) * rowB, smem + rpair * 1024);
    }
    asm volatile("s_waitcnt vmcnt(0)" ::: "memory");
    __syncthreads();

    const float* fin = (const float*)smem;
    int cb = (tid & 31) * 4;
    int rgb = tid >> 5;
    unsigned pk[4][4];
#pragma unroll
    for (int p = 0; p < 4; ++p) {
        int rb = (rgb + 8 * p) * 4;
        float4 q0 = *(const float4*)(fin + (rb + 0) * 128 + cb);
        float4 q1 = *(const float4*)(fin + (rb + 1) * 128 + cb);
        float4 q2 = *(const float4*)(fin + (rb + 2) * 128 + cb);
        float4 q3 = *(const float4*)(fin + (rb + 3) * 128 + cb);
        unsigned w;
        w = f2fp8pk<false>(q0.x, q1.x, 0); w = f2fp8pk<true>(q2.x, q3.x, w); pk[p][0] = w;
        w = f2fp8pk<false>(q0.y, q1.y, 0); w = f2fp8pk<true>(q2.y, q3.y, w); pk[p][1] = w;
        w = f2fp8pk<false>(q0.z, q1.z, 0); w = f2fp8pk<true>(q2.z, q3.z, w); pk[p][2] = w;
        w = f2fp8pk<false>(q0.w, q1.w, 0); w = f2fp8pk<true>(q2.w, q3.w, w); pk[p][3] = w;
    }
    __syncthreads();
    unsigned* po = (unsigned*)smem;    // [128 cols][33 words]
#pragma unroll
    for (int p = 0; p < 4; ++p) {
        int rg = rgb + 8 * p;
#pragma unroll
        for (int j = 0; j < 4; ++j)
            po[(cb + j) * 33 + rg] = pk[p][j];
    }
    __syncthreads();
#pragma unroll
    for (int p = 0; p < 4; ++p) {
        int c = (tid >> 3) + 32 * p;
        int gs = tid & 7;
        const unsigned* bp = &po[c * 33 + gs * 4];
        uint4 val;
        val.x = bp[0]; val.y = bp[1]; val.z = bp[2]; val.w = bp[3];
        *(uint4*)(out + (size_t)(c0 + c) * Rb + r0 + gs * 16) = val;
    }
}

// ---------------------------------------------------------------------------
// Dispatch 1: router blocks [0,512) + w1/w3 transpose blocks [512, 2816)
// ---------------------------------------------------------------------------
__global__ __launch_bounds__(256, 2)
void pre_kernel(const float* __restrict__ x,
                const float* __restrict__ rw, const float* __restrict__ rbias,
                const float* __restrict__ dgw, const float* __restrict__ dgb,
                const float* __restrict__ w1, const float* __restrict__ w3,
                unsigned char* __restrict__ xb,
                int* __restrict__ e_arr, float* __restrict__ s_arr,
                unsigned char* __restrict__ w1t, unsigned char* __restrict__ w3t) {
    __shared__ __align__(16) char smem[65536];
    int bid = blockIdx.x;
    int tid = threadIdx.x;

    if (bid >= 512) {
        int idx = bid - 512;
        int z = idx / 144;
        int rem = idx % 144;
        int r0 = (rem % 6) * 128;
        int c0 = (rem / 6) * 128;
        const float* in;
        unsigned char* outp;
        if (z < 8) { in = w1 + (size_t)z * D * FF; outp = w1t + (size_t)z * D * FF; }
        else       { in = w3 + (size_t)(z - 8) * D * FF; outp = w3t + (size_t)(z - 8) * D * FF; }
        transpose128(in, outp, FF, D, r0, c0, smem, tid);
        return;
    }

    int lane = tid & 63;
    int wv = tid >> 6;
    int t = bid * 4 + wv;

    float lg[E], dl[E];
#pragma unroll
    for (int e = 0; e < E; ++e) { lg[e] = 0.f; dl[e] = 0.f; }

    const float* xt = x + (size_t)t * D;
    unsigned char* xbt = xb + (size_t)t * D;
#pragma unroll
    for (int i = 0; i < D / 64; ++i) {
        int d = lane + 64 * i;
        float xv = xt[d];
        xbt[d] = f2fp8(xv);
#pragma unroll
        for (int e = 0; e < E; ++e) {
            lg[e] = fmaf(xv, rw[d * E + e], lg[e]);
            dl[e] = fmaf(xv, dgw[e * D + d], dl[e]);
        }
    }
#pragma unroll
    for (int e = 0; e < E; ++e) {
        for (int off = 32; off; off >>= 1) {
            lg[e] += __shfl_xor(lg[e], off);
            dl[e] += __shfl_xor(dl[e], off);
        }
    }
    if (lane == 0) {
        float p[E];
        float m = -1e30f;
#pragma unroll
        for (int e = 0; e < E; ++e) { lg[e] += rbias[e]; m = fmaxf(m, lg[e]); }
        float s = 0.f;
#pragma unroll
        for (int e = 0; e < E; ++e) { p[e] = __expf(lg[e] - m); s += p[e]; }
        float inv = 1.0f / s;
#pragma unroll
        for (int e = 0; e < E; ++e) p[e] *= inv;

        int i0 = 0; float b0 = p[0];
#pragma unroll
        for (int e = 1; e < E; ++e) if (p[e] > b0) { b0 = p[e]; i0 = e; }
        int i1 = -1; float b1 = -1.0f;
#pragma unroll
        for (int e = 0; e < E; ++e) if (e != i0 && p[e] > b1) { b1 = p[e]; i1 = e; }

        float eb = __expf(b1 - b0);
        float w0 = 1.0f / (1.0f + eb);
        float w1v = eb / (1.0f + eb);

        float dg0 = 1.0f / (1.0f + __expf(-(dl[i0] + dgb[i0])));
        float dg1 = 1.0f / (1.0f + __expf(-(dl[i1] + dgb[i1])));

        e_arr[t * 2 + 0] = i0;
        e_arr[t * 2 + 1] = i1;
        s_arr[t * 2 + 0] = dg0 * w0;
        s_arr[t * 2 + 1] = dg1 * w1v;
    }
}

// ---------------------------------------------------------------------------
// Dispatch 2: scan+assign (counts in-LDS)
// ---------------------------------------------------------------------------
__global__ __launch_bounds__(256)
void scan_assign_kernel(const int* __restrict__ e_arr,
                        float* __restrict__ load_out,
                        int* __restrict__ tme, int* __restrict__ tmm,
                        int* __restrict__ tml,
                        int* __restrict__ a_tok,
                        int* __restrict__ pos_of) {
    __shared__ int lcnt[E];
    __shared__ int lcur[E];
    int tid = threadIdx.x;
    if (tid < E) lcnt[tid] = 0;
    __syncthreads();
    for (int t = tid; t < T; t += 256) {
        atomicAdd(&lcnt[e_arr[t * 2]], 1);
        atomicAdd(&lcnt[e_arr[t * 2 + 1]], 1);
    }
    __syncthreads();
    if (tid == 0) {
        int b = 0, nt = 0;
        for (int e = 0; e < E; ++e) {
            int c = lcnt[e];
            lcur[e] = b;
            load_out[e] = (float)c;
            for (int m = 0; m < c; m += 128) {
                tme[nt] = e;
                tmm[nt] = b + m;
                tml[nt] = (c - m < 128) ? (c - m) : 128;
                ++nt;
            }
            b += c;
        }
        for (; nt < MAXTILE; ++nt) tme[nt] = -1;
    }
    __syncthreads();
    for (int t = tid; t < T; t += 256) {
#pragma unroll
        for (int s = 0; s < 2; ++s) {
            int e = e_arr[t * 2 + s];
            int pos = atomicAdd(&lcur[e], 1);
            a_tok[pos] = t;
            pos_of[t * 2 + s] = pos;
        }
    }
}

// ---------------------------------------------------------------------------
// Dispatch 3: GEMM1 blocks [0,960) + w2 transpose blocks [960, 2112).
// GEMM1: persistent 2-M-tile pipeline, 128x64 tile, BK=128, counted vmcnt.
// LDS: A dbuf 32KB + B dbuf 32KB + epilogue 8KB = 72KB -> 2 blocks/CU.
// ---------------------------------------------------------------------------
__global__ __launch_bounds__(256, 2)
void gemm1_w2t_kernel(const float* __restrict__ w2, unsigned char* __restrict__ w2t,
                      const unsigned char* __restrict__ xb,
                      const unsigned char* __restrict__ w1t, const float* __restrict__ w1b,
                      const unsigned char* __restrict__ w3t, const float* __restrict__ w3b,
                      const int* __restrict__ a_tok,
                      const int* __restrict__ tme, const int* __restrict__ tmm,
                      const int* __restrict__ tml,
                      unsigned char* __restrict__ acts) {
    __shared__ __align__(16) char smem[73728];   // 72KB
    int bid = blockIdx.x;
    int tid = threadIdx.x;

    if (bid >= 960) {   // ---- w2 transpose flavor ----
        int idx = bid - 960;
        int z = idx / 144;
        int rem = idx % 144;
        int r0 = (rem % 24) * 128;
        int c0 = (rem / 24) * 128;
        transpose128(w2 + (size_t)z * FF * D, w2t + (size_t)z * FF * D,
                     D, FF, r0, c0, smem, tid);
        return;
    }

    // ---- gemm1 persistent flavor ----
    int slot = bid / 48;
    int fBase = (bid % 48) * 64;
    int mt0 = slot * 2;
    int e0 = tme[mt0];
    if (e0 < 0) return;
    int e1 = tme[mt0 + 1];
    bool have2 = (e1 >= 0);
    int mstart0 = tmm[mt0], mlen0 = tml[mt0];
    int mstart1 = have2 ? tmm[mt0 + 1] : mstart0;
    int mlen1   = have2 ? tml[mt0 + 1] : mlen0;
    if (!have2) e1 = e0;

    char* As = smem;              // 2 x 16KB
    char* Bs = smem + 32768;      // 2 x 16KB
    unsigned char* eplds = (unsigned char*)(smem + 65536);  // 8KB

    int lane = tid & 63, wv = tid >> 6;
    int wr = wv & 1, wc = wv >> 1;
    int l15 = lane & 15, lk = lane >> 4;
    int lrow = lane >> 3;
    int swl = (((lane & 7) ^ lrow) << 4);

    const char* xbp = (const char*)xb;
    const char* w1p0 = (const char*)(w1t + (size_t)e0 * FF * D);
    const char* w3p0 = (const char*)(w3t + (size_t)e0 * FF * D);
    const char* w1p1 = (const char*)(w1t + (size_t)e1 * FF * D);
    const char* w3p1 = (const char*)(w3t + (size_t)e1 * FF * D);

    size_t boff[2];
#pragma unroll
    for (int i = 0; i < 2; ++i) {
        int f = (wv + 4 * i) * 8 + lrow;
        boff[i] = (size_t)(fBase + f) * D + swl;
    }

    // prologue: all VMEM reads (tokens, biases) before pipeline starts
    size_t a0[4], a1[4];
#pragma unroll
    for (int i = 0; i < 4; ++i) {
        int r = (wv + 4 * i) * 8 + lrow;
        int rr0 = r < mlen0 ? r : mlen0 - 1;
        int rr1 = r < mlen1 ? r : mlen1 - 1;
        a0[i] = (size_t)a_tok[mstart0 + rr0] * D + swl;
        a1[i] = (size_t)a_tok[mstart1 + rr1] * D + swl;
    }
    float tb1[2][2], tb3[2][2];
#pragma unroll
    for (int n = 0; n < 2; ++n) {
        int f = fBase + wc * 32 + n * 16 + l15;
        tb1[0][n] = w1b[e0 * FF + f];
        tb3[0][n] = w3b[e0 * FF + f];
        tb1[1][n] = w1b[e1 * FF + f];
        tb3[1][n] = w3b[e1 * FF + f];
    }

    auto stage = [&](int buf, const size_t* ao, const char* w1p_, const char* w3p_, int ks) {
        int kb = ks * 128;
        char* ab = As + buf * 16384;
        char* bb = Bs + buf * 16384;
#pragma unroll
        for (int i = 0; i < 4; ++i)
            gload16(xbp + ao[i] + kb, ab + (wv + 4 * i) * 1024);
#pragma unroll
        for (int i = 0; i < 2; ++i) {
            gload16(w1p_ + boff[i] + kb, bb + (wv + 4 * i) * 1024);
            gload16(w3p_ + boff[i] + kb, bb + 8192 + (wv + 4 * i) * 1024);
        }
    };

    f32x4 hacc[4][2], gacc[4][2];
    auto zacc = [&]() {
#pragma unroll
        for (int m = 0; m < 4; ++m)
#pragma unroll
            for (int n = 0; n < 2; ++n) {
                hacc[m][n] = f32x4{0.f, 0.f, 0.f, 0.f};
                gacc[m][n] = f32x4{0.f, 0.f, 0.f, 0.f};
            }
    };

    auto computeStep = [&](int buf) {
        const char* Ab = As + buf * 16384;
        const char* Bb = Bs + buf * 16384;
        __builtin_amdgcn_s_setprio(1);
#pragma unroll
        for (int ksub = 0; ksub < 4; ++ksub) {
            int koff = ksub * 32 + lk * 8;
            long af[4];
#pragma unroll
            for (int m = 0; m < 4; ++m) {
                int row = wr * 64 + m * 16 + l15;
                af[m] = *(const long*)(Ab + row * 128 + (koff ^ ((row & 7) << 4)));
            }
#pragma unroll
            for (int n = 0; n < 2; ++n) {
                int rowf = wc * 32 + n * 16 + l15;
                int off = rowf * 128 + (koff ^ ((rowf & 7) << 4));
                long b1 = *(const long*)(Bb + off);
                long b3 = *(const long*)(Bb + 8192 + off);
#pragma unroll
                for (int m = 0; m < 4; ++m) {
                    hacc[m][n] = __builtin_amdgcn_mfma_f32_16x16x32_fp8_fp8(af[m], b1, hacc[m][n], 0, 0, 0);
                    gacc[m][n] = __builtin_amdgcn_mfma_f32_16x16x32_fp8_fp8(af[m], b3, gacc[m][n], 0, 0, 0);
                }
            }
        }
        __builtin_amdgcn_s_setprio(0);
    };

    auto epilogueT = [&](const float b1v[2], const float b3v[2], int mstart_, int mlen_) {
#pragma unroll
        for (int m = 0; m < 4; ++m)
#pragma unroll
            for (int n = 0; n < 2; ++n)
#pragma unroll
                for (int j = 0; j < 4; ++j) {
                    float h = hacc[m][n][j] + b1v[n];
                    float gg = gacc[m][n][j] + b3v[n];
                    int row = wr * 64 + m * 16 + lk * 4 + j;
                    int col = wc * 32 + n * 16 + l15;
                    eplds[row * 64 + col] = f2fp8(siluf(h) * siluf(gg));
                }
        __syncthreads();
        int r = tid >> 1, cb = (tid & 1) * 32;
        if (r < mlen_) {
            unsigned char* gp = acts + (size_t)(mstart_ + r) * FF + fBase + cb;
            const unsigned char* lp = eplds + r * 64 + cb;
            *(uint4*)(gp)      = *(const uint4*)(lp);
            *(uint4*)(gp + 16) = *(const uint4*)(lp + 16);
        }
    };

#define G1_WAIT8 asm volatile("s_waitcnt vmcnt(8)" ::: "memory")
#define G1_BAR   __builtin_amdgcn_s_barrier()

    // ---- tile 0 ----
    zacc();
    stage(0, a0, w1p0, w3p0, 0);
    stage(1, a0, w1p0, w3p0, 1);
    asm volatile("s_waitcnt vmcnt(0)" ::: "memory");
    __syncthreads();

    /*s0*/ computeStep(0); G1_BAR; stage(0, a0, w1p0, w3p0, 2);
    /*s1*/ G1_BAR; computeStep(1); G1_BAR; stage(1, a0, w1p0, w3p0, 3);
    /*s2*/ G1_WAIT8; G1_BAR; computeStep(0); G1_BAR; stage(0, a0, w1p0, w3p0, 4);
    /*s3*/ G1_WAIT8; G1_BAR; computeStep(1); G1_BAR; stage(1, a0, w1p0, w3p0, 5);
    /*s4*/ G1_WAIT8; G1_BAR; computeStep(0); G1_BAR; stage(0, a1, w1p1, w3p1, 0);
    /*s5*/ G1_WAIT8; G1_BAR; computeStep(1); G1_BAR; stage(1, a1, w1p1, w3p1, 1);

    epilogueT(tb1[0], tb3[0], mstart0, mlen0);
    asm volatile("s_waitcnt vmcnt(0)" ::: "memory");
    __syncthreads();

    if (have2) {
        // ---- tile 1 (data for s0/s1 already resident) ----
        zacc();
        /*s0*/ computeStep(0); G1_BAR; stage(0, a1, w1p1, w3p1, 2);
        /*s1*/ G1_BAR; computeStep(1); G1_BAR; stage(1, a1, w1p1, w3p1, 3);
        /*s2*/ G1_WAIT8; G1_BAR; computeStep(0); G1_BAR; stage(0, a1, w1p1, w3p1, 4);
        /*s3*/ G1_WAIT8; G1_BAR; computeStep(1); G1_BAR; stage(1, a1, w1p1, w3p1, 5);
        /*s4*/ G1_WAIT8; G1_BAR; computeStep(0); G1_BAR;
        /*s5*/ asm volatile("s_waitcnt vmcnt(0)" ::: "memory"); G1_BAR; computeStep(1); G1_BAR;
        epilogueT(tb1[1], tb3[1], mstart1, mlen1);
    }
#undef G1_WAIT8
#undef G1_BAR
}

// ---------------------------------------------------------------------------
// GEMM2 (fp8): 128x128 tile, split-K=2, BK=128 -> 12 steps. Unchanged.
// ---------------------------------------------------------------------------
__global__ __launch_bounds__(256, 2)
void gemm2_kernel(const unsigned char* __restrict__ acts,
                  const unsigned char* __restrict__ w2t,
                  const int* __restrict__ tme, const int* __restrict__ tmm,
                  const int* __restrict__ tml,
                  float* __restrict__ ffs) {
    int mt = blockIdx.y;
    int e = tme[mt];
    if (e < 0) return;
    int mstart = tmm[mt], mlen = tml[mt];
    int nBase = blockIdx.x * 128;
    int ksl = blockIdx.z;

    __shared__ char As[2][16384];
    __shared__ char Bs[2][16384];

    int tid = threadIdx.x;
    int lane = tid & 63, wv = tid >> 6;
    int wr = wv & 1, wc = wv >> 1;
    int l15 = lane & 15, lk = lane >> 4;
    int lrow = lane >> 3;
    int swl = (((lane & 7) ^ lrow) << 4);

    const char* ap = (const char*)acts;
    const char* w2p = (const char*)(w2t + (size_t)e * (size_t)D * FF);
    size_t aoff[4], boff[4];
#pragma unroll
    for (int i = 0; i < 4; ++i) {
        int r = (wv + 4 * i) * 8 + lrow;
        aoff[i] = (size_t)(mstart + r) * FF + swl;
        boff[i] = (size_t)(nBase + r) * FF + swl;
    }
    int kOff = ksl * (FF / 2);

    auto stage = [&](int buf, int ks) {
        int kb = kOff + ks * 128;
        char* ab = &As[buf][0];
        char* bb = &Bs[buf][0];
#pragma unroll
        for (int i = 0; i < 4; ++i) {
            gload16(ap + aoff[i] + kb, ab + (wv + 4 * i) * 1024);
            gload16(w2p + boff[i] + kb, bb + (wv + 4 * i) * 1024);
        }
    };

    f32x4 facc[4][4];
#pragma unroll
    for (int m = 0; m < 4; ++m)
#pragma unroll
        for (int n = 0; n < 4; ++n) facc[m][n] = f32x4{0.f, 0.f, 0.f, 0.f};

    stage(0, 0);
    stage(1, 1);
#pragma unroll 1
    for (int ks = 0; ks < 12; ++ks) {
        int cur = ks & 1;
        if (ks < 11) asm volatile("s_waitcnt vmcnt(8)" ::: "memory");
        else         asm volatile("s_waitcnt vmcnt(0)" ::: "memory");
        __builtin_amdgcn_s_barrier();
        const char* Ab = &As[cur][0];
        const char* Bb = &Bs[cur][0];
        __builtin_amdgcn_s_setprio(1);
#pragma unroll
        for (int ksub = 0; ksub < 4; ++ksub) {
            int koff = ksub * 32 + lk * 8;
            long af[4], bf[4];
#pragma unroll
            for (int m = 0; m < 4; ++m) {
                int row = wr * 64 + m * 16 + l15;
                af[m] = *(const long*)(Ab + row * 128 + (koff ^ ((row & 7) << 4)));
            }
#pragma unroll
            for (int n = 0; n < 4; ++n) {
                int row = wc * 64 + n * 16 + l15;
                bf[n] = *(const long*)(Bb + row * 128 + (koff ^ ((row & 7) << 4)));
            }
#pragma unroll
            for (int m = 0; m < 4; ++m)
#pragma unroll
                for (int n = 0; n < 4; ++n)
                    facc[m][n] = __builtin_amdgcn_mfma_f32_16x16x32_fp8_fp8(af[m], bf[n], facc[m][n], 0, 0, 0);
        }
        __builtin_amdgcn_s_setprio(0);
        __builtin_amdgcn_s_barrier();
        if (ks < 10) stage(cur, ks + 2);
    }

    float* op = ffs + (size_t)ksl * PSTRIDE;
#pragma unroll
    for (int m = 0; m < 4; ++m)
#pragma unroll
        for (int j = 0; j < 4; ++j) {
            int row = wr * 64 + m * 16 + lk * 4 + j;
            if (row < mlen) {
                float* gp = op + (size_t)(mstart + row) * D + nBase + wc * 64;
#pragma unroll
                for (int n = 0; n < 4; ++n)
                    gp[n * 16 + l15] = facc[m][n][j];
            }
        }
}

// ---------------------------------------------------------------------------
// Combine — unchanged
// ---------------------------------------------------------------------------
__global__ __launch_bounds__(256)
void combine_kernel(const float* __restrict__ x,
                    const float* __restrict__ ffs,
                    const int* __restrict__ e_arr,
                    const int* __restrict__ pos_of,
                    const float* __restrict__ s_arr,
                    const float* __restrict__ w2b,
                    const float* __restrict__ lng,
                    const float* __restrict__ lnb,
                    float* __restrict__ out) {
    int t = blockIdx.x;
    int tid = threadIdx.x;
    int p0 = pos_of[t * 2], p1 = pos_of[t * 2 + 1];
    int e0 = e_arr[t * 2], e1 = e_arr[t * 2 + 1];
    float sw0 = s_arr[t * 2], sw1 = s_arr[t * 2 + 1];
    __shared__ float red[4][4];

    float y0[3], y1[3];
    float s0 = 0.f, q0 = 0.f, s1 = 0.f, q1 = 0.f;
#pragma unroll
    for (int m = 0; m < 3; ++m) {
        int d = tid + 256 * m;
        float xv = x[(size_t)t * D + d];
        float f0 = ffs[(size_t)p0 * D + d] + ffs[PSTRIDE + (size_t)p0 * D + d] + w2b[e0 * D + d];
        float f1 = ffs[(size_t)p1 * D + d] + ffs[PSTRIDE + (size_t)p1 * D + d] + w2b[e1 * D + d];
        float a = xv + sw0 * f0;
        float bb = xv + sw1 * f1;
        y0[m] = a; y1[m] = bb;
        s0 += a; q0 += a * a;
        s1 += bb; q1 += bb * bb;
    }
    for (int off = 32; off; off >>= 1) {
        s0 += __shfl_xor(s0, off);
        q0 += __shfl_xor(q0, off);
        s1 += __shfl_xor(s1, off);
        q1 += __shfl_xor(q1, off);
    }
    int wv = tid >> 6, lane = tid & 63;
    if (lane == 0) { red[wv][0] = s0; red[wv][1] = q0; red[wv][2] = s1; red[wv][3] = q1; }
    __syncthreads();
    s0 = red[0][0] + red[1][0] + red[2][0] + red[3][0];
    q0 = red[0][1] + red[1][1] + red[2][1] + red[3][1];
    s1 = red[0][2] + red[1][2] + red[2][2] + red[3][2];
    q1 = red[0][3] + red[1][3] + red[2][3] + red[3][3];

    const float invD = 1.0f / (float)D;
    float mu0 = s0 * invD, var0 = q0 * invD - mu0 * mu0;
    float mu1 = s1 * invD, var1 = q1 * invD - mu1 * mu1;
    float r0 = rsqrtf(var0 + 1e-5f);
    float r1 = rsqrtf(var1 + 1e-5f);

#pragma unroll
    for (int m = 0; m < 3; ++m) {
        int d = tid + 256 * m;
        out[(size_t)t * D + d] =
            (y0[m] - mu0) * r0 * lng[e0 * D + d] + lnb[e0 * D + d] +
            (y1[m] - mu1) * r1 * lng[e1 * D + d] + lnb[e1 * D + d];
    }
}

// ---------------------------------------------------------------------------
extern "C" void kernel_launch(void* const* d_in, const int* in_sizes, int n_in,
                              void* d_out, int out_size, void* d_ws, size_t ws_size,
                              hipStream_t stream) {
    const float* x   = (const float*)d_in[0];
    const float* rw  = (const float*)d_in[1];
    const float* rb  = (const float*)d_in[2];
    const float* dgw = (const float*)d_in[3];
    const float* dgb = (const float*)d_in[4];
    const float* w1  = (const float*)d_in[5];
    const float* w1b = (const float*)d_in[6];
    const float* w2  = (const float*)d_in[7];
    const float* w2b = (const float*)d_in[8];
    const float* w3  = (const float*)d_in[9];
    const float* w3b = (const float*)d_in[10];
    const float* lng = (const float*)d_in[11];
    const float* lnb = (const float*)d_in[12];

    float* out = (float*)d_out;
    float* load_out = out + (size_t)T * D;

    char* w = (char*)d_ws;
    size_t off = 0;
    auto alloc = [&](size_t bytes) -> void* {
        void* p = w + off;
        off = (off + bytes + 255) & ~(size_t)255;
        return p;
    };
    int* e_arr    = (int*)alloc(NPOS * sizeof(int));
    int* a_tok    = (int*)alloc(NPOS * sizeof(int));
    int* pos_of   = (int*)alloc(NPOS * sizeof(int));
    float* s_arr  = (float*)alloc(NPOS * sizeof(float));
    int* tme      = (int*)alloc(MAXTILE * sizeof(int));
    int* tmm      = (int*)alloc(MAXTILE * sizeof(int));
    int* tml      = (int*)alloc(MAXTILE * sizeof(int));
    unsigned char* xb  = (unsigned char*)alloc((size_t)T * D);
    unsigned char* w1t = (unsigned char*)alloc((size_t)E * D * FF);
    unsigned char* w3t = (unsigned char*)alloc((size_t)E * D * FF);
    unsigned char* w2t = (unsigned char*)alloc((size_t)E * D * FF);
    unsigned char* acts = (unsigned char*)alloc((size_t)(NPOS + 128) * FF);
    float* ffs    = (float*)alloc(2 * PSTRIDE * sizeof(float));

    pre_kernel<<<512 + 2304, 256, 0, stream>>>(x, rw, rb, dgw, dgb, w1, w3,
                                               xb, e_arr, s_arr, w1t, w3t);
    scan_assign_kernel<<<1, 256, 0, stream>>>(e_arr, load_out, tme, tmm, tml,
                                              a_tok, pos_of);
    gemm1_w2t_kernel<<<960 + 1152, 256, 0, stream>>>(
        w2, w2t, xb, w1t, w1b, w3t, w3b, a_tok, tme, tmm, tml, acts);
    gemm2_kernel<<<dim3(D / 128, MAXTILE, 2), 256, 0, stream>>>(
        acts, w2t, tme, tmm, tml, ffs);
    combine_kernel<<<T, 256, 0, stream>>>(x, ffs, e_arr, pos_of, s_arr, w2b, lng, lnb, out);
}

// Round 13
// 147.604 us; speedup vs baseline: 2.0244x; 1.0045x over previous
//
#include <hip/hip_runtime.h>
#include <math.h>

#define T 2048
#define D 768
#define E 8
#define FF 3072
#define NPOS (2 * T)
#define MAXTILE 40
#define PSTRIDE ((size_t)(NPOS + 128) * D)

using f32x4 = __attribute__((ext_vector_type(4))) float;

template<bool HI>
__device__ __forceinline__ unsigned f2fp8pk(float a, float b, unsigned old) {
    return __builtin_amdgcn_cvt_pk_fp8_f32(a, b, (int)old, HI);
}
__device__ __forceinline__ unsigned char f2fp8(float f) {
    return (unsigned char)(__builtin_amdgcn_cvt_pk_fp8_f32(f, 0.f, 0, false) & 0xff);
}
__device__ __forceinline__ float siluf(float v) {
    return v / (1.0f + __expf(-v));
}
__device__ __forceinline__ void gload16(const void* g, void* l) {
    __builtin_amdgcn_global_load_lds(
        (const __attribute__((address_space(1))) void*)g,
        (__attribute__((address_space(3))) void*)l, 16, 0, 0);
}

#define SMEM_BYTES 73984   // 32K S0 + 32K S1 + 8.25K po  (gemm1 uses 72K of it)

// ---------------------------------------------------------------------------
// transpose128_pipe: 128x128 f32 tile -> fp8 transposed, software-pipelined:
// both 128x64 half-DMAs issued up front; convert+write of half0 overlaps
// half1's flight (vmcnt(8) / vmcnt(2) counted waits, never an idle drain).
// ---------------------------------------------------------------------------
__device__ __forceinline__ void transpose128_pipe(const float* __restrict__ in,
                                                  unsigned char* __restrict__ out,
                                                  int C, int Rb, int r0, int c0,
                                                  char* smem, int tid) {
    char* S[2] = { smem, smem + 32768 };
    unsigned* po = (unsigned*)(smem + 65536);   // [64 cols][33 words]
    int wv = tid >> 6, lane = tid & 63;
    size_t rowB = (size_t)C * 4;
    const char* base = (const char*)in + (size_t)r0 * rowB + (size_t)c0 * 4;

    // issue both half-tile DMAs back-to-back (16 wave-instrs in flight)
#pragma unroll
    for (int h = 0; h < 2; ++h) {
        const char* hb = base + h * 256;
        char* Sh = S[h];
#pragma unroll
        for (int i = 0; i < 8; ++i) {
            int j = i * 4 + wv;   // 4-row group 0..31
            gload16(hb + (size_t)(4 * j + (lane >> 4)) * rowB + (lane & 15) * 16,
                    Sh + j * 1024 + lane * 16);
        }
    }

    int rgb = tid >> 4;                       // 0..15
    int cb = (((tid & 15) + rgb) & 15) * 4;   // rotated: 2-way banks on fin reads
#pragma unroll 1
    for (int h = 0; h < 2; ++h) {
        if (h == 0) asm volatile("s_waitcnt vmcnt(8)" ::: "memory");
        else        asm volatile("s_waitcnt vmcnt(2)" ::: "memory");
        __syncthreads();          // half resident; prev po reads finished
        const float* fin = (const float*)S[h];   // linear [128 rows][64 cols]
        unsigned pk[2][4];
#pragma unroll
        for (int p = 0; p < 2; ++p) {
            int rb = (rgb + 16 * p) * 4;
            float4 q0 = *(const float4*)(fin + (rb + 0) * 64 + cb);
            float4 q1 = *(const float4*)(fin + (rb + 1) * 64 + cb);
            float4 q2 = *(const float4*)(fin + (rb + 2) * 64 + cb);
            float4 q3 = *(const float4*)(fin + (rb + 3) * 64 + cb);
            unsigned w;
            w = f2fp8pk<false>(q0.x, q1.x, 0); w = f2fp8pk<true>(q2.x, q3.x, w); pk[p][0] = w;
            w = f2fp8pk<false>(q0.y, q1.y, 0); w = f2fp8pk<true>(q2.y, q3.y, w); pk[p][1] = w;
            w = f2fp8pk<false>(q0.z, q1.z, 0); w = f2fp8pk<true>(q2.z, q3.z, w); pk[p][2] = w;
            w = f2fp8pk<false>(q0.w, q1.w, 0); w = f2fp8pk<true>(q2.w, q3.w, w); pk[p][3] = w;
        }
#pragma unroll
        for (int p = 0; p < 2; ++p) {
            int rg = rgb + 16 * p;
#pragma unroll
            for (int j = 0; j < 4; ++j)
                po[(cb + j) * 33 + rg] = pk[p][j];
        }
        __syncthreads();          // po complete
        // write out: 8 lanes x 16B = one 128B line per output row
#pragma unroll
        for (int p = 0; p < 2; ++p) {
            int c = (tid >> 3) + 32 * p;
            int gs = tid & 7;
            const unsigned* bp = &po[c * 33 + gs * 4];
            uint4 val;
            val.x = bp[0]; val.y = bp[1]; val.z = bp[2]; val.w = bp[3];
            *(uint4*)(out + (size_t)(c0 + h * 64 + c) * Rb + r0 + gs * 16) = val;
        }
    }
}

// ---------------------------------------------------------------------------
// Dispatch 1: router blocks [0,512) + w1/w3 transpose blocks [512, 2816)
// ---------------------------------------------------------------------------
__global__ __launch_bounds__(256, 2)
void pre_kernel(const float* __restrict__ x,
                const float* __restrict__ rw, const float* __restrict__ rbias,
                const float* __restrict__ dgw, const float* __restrict__ dgb,
                const float* __restrict__ w1, const float* __restrict__ w3,
                unsigned char* __restrict__ xb,
                int* __restrict__ e_arr, float* __restrict__ s_arr,
                unsigned char* __restrict__ w1t, unsigned char* __restrict__ w3t) {
    __shared__ __align__(16) char smem[SMEM_BYTES];
    int bid = blockIdx.x;
    int tid = threadIdx.x;

    if (bid >= 512) {
        int idx = bid - 512;
        int z = idx / 144;
        int rem = idx % 144;
        int r0 = (rem % 6) * 128;
        int c0 = (rem / 6) * 128;
        const float* in;
        unsigned char* outp;
        if (z < 8) { in = w1 + (size_t)z * D * FF; outp = w1t + (size_t)z * D * FF; }
        else       { in = w3 + (size_t)(z - 8) * D * FF; outp = w3t + (size_t)(z - 8) * D * FF; }
        transpose128_pipe(in, outp, FF, D, r0, c0, smem, tid);
        return;
    }

    int lane = tid & 63;
    int wv = tid >> 6;
    int t = bid * 4 + wv;

    float lg[E], dl[E];
#pragma unroll
    for (int e = 0; e < E; ++e) { lg[e] = 0.f; dl[e] = 0.f; }

    const float* xt = x + (size_t)t * D;
    unsigned char* xbt = xb + (size_t)t * D;
#pragma unroll
    for (int i = 0; i < D / 64; ++i) {
        int d = lane + 64 * i;
        float xv = xt[d];
        xbt[d] = f2fp8(xv);
#pragma unroll
        for (int e = 0; e < E; ++e) {
            lg[e] = fmaf(xv, rw[d * E + e], lg[e]);
            dl[e] = fmaf(xv, dgw[e * D + d], dl[e]);
        }
    }
#pragma unroll
    for (int e = 0; e < E; ++e) {
        for (int off = 32; off; off >>= 1) {
            lg[e] += __shfl_xor(lg[e], off);
            dl[e] += __shfl_xor(dl[e], off);
        }
    }
    if (lane == 0) {
        float p[E];
        float m = -1e30f;
#pragma unroll
        for (int e = 0; e < E; ++e) { lg[e] += rbias[e]; m = fmaxf(m, lg[e]); }
        float s = 0.f;
#pragma unroll
        for (int e = 0; e < E; ++e) { p[e] = __expf(lg[e] - m); s += p[e]; }
        float inv = 1.0f / s;
#pragma unroll
        for (int e = 0; e < E; ++e) p[e] *= inv;

        int i0 = 0; float b0 = p[0];
#pragma unroll
        for (int e = 1; e < E; ++e) if (p[e] > b0) { b0 = p[e]; i0 = e; }
        int i1 = -1; float b1 = -1.0f;
#pragma unroll
        for (int e = 0; e < E; ++e) if (e != i0 && p[e] > b1) { b1 = p[e]; i1 = e; }

        float eb = __expf(b1 - b0);
        float w0 = 1.0f / (1.0f + eb);
        float w1v = eb / (1.0f + eb);

        float dg0 = 1.0f / (1.0f + __expf(-(dl[i0] + dgb[i0])));
        float dg1 = 1.0f / (1.0f + __expf(-(dl[i1] + dgb[i1])));

        e_arr[t * 2 + 0] = i0;
        e_arr[t * 2 + 1] = i1;
        s_arr[t * 2 + 0] = dg0 * w0;
        s_arr[t * 2 + 1] = dg1 * w1v;
    }
}

// ---------------------------------------------------------------------------
// Dispatch 2: scan+assign (counts in-LDS)
// ---------------------------------------------------------------------------
__global__ __launch_bounds__(256)
void scan_assign_kernel(const int* __restrict__ e_arr,
                        float* __restrict__ load_out,
                        int* __restrict__ tme, int* __restrict__ tmm,
                        int* __restrict__ tml,
                        int* __restrict__ a_tok,
                        int* __restrict__ pos_of) {
    __shared__ int lcnt[E];
    __shared__ int lcur[E];
    int tid = threadIdx.x;
    if (tid < E) lcnt[tid] = 0;
    __syncthreads();
    for (int t = tid; t < T; t += 256) {
        atomicAdd(&lcnt[e_arr[t * 2]], 1);
        atomicAdd(&lcnt[e_arr[t * 2 + 1]], 1);
    }
    __syncthreads();
    if (tid == 0) {
        int b = 0, nt = 0;
        for (int e = 0; e < E; ++e) {
            int c = lcnt[e];
            lcur[e] = b;
            load_out[e] = (float)c;
            for (int m = 0; m < c; m += 128) {
                tme[nt] = e;
                tmm[nt] = b + m;
                tml[nt] = (c - m < 128) ? (c - m) : 128;
                ++nt;
            }
            b += c;
        }
        for (; nt < MAXTILE; ++nt) tme[nt] = -1;
    }
    __syncthreads();
    for (int t = tid; t < T; t += 256) {
#pragma unroll
        for (int s = 0; s < 2; ++s) {
            int e = e_arr[t * 2 + s];
            int pos = atomicAdd(&lcur[e], 1);
            a_tok[pos] = t;
            pos_of[t * 2 + s] = pos;
        }
    }
}

// ---------------------------------------------------------------------------
// Dispatch 3: GEMM1 blocks [0,960) + w2 transpose blocks [960, 2112).
// GEMM1: persistent 2-M-tile pipeline, 128x64 tile, BK=128, counted vmcnt.
// ---------------------------------------------------------------------------
__global__ __launch_bounds__(256, 2)
void gemm1_w2t_kernel(const float* __restrict__ w2, unsigned char* __restrict__ w2t,
                      const unsigned char* __restrict__ xb,
                      const unsigned char* __restrict__ w1t, const float* __restrict__ w1b,
                      const unsigned char* __restrict__ w3t, const float* __restrict__ w3b,
                      const int* __restrict__ a_tok,
                      const int* __restrict__ tme, const int* __restrict__ tmm,
                      const int* __restrict__ tml,
                      unsigned char* __restrict__ acts) {
    __shared__ __align__(16) char smem[SMEM_BYTES];
    int bid = blockIdx.x;
    int tid = threadIdx.x;

    if (bid >= 960) {   // ---- w2 transpose flavor ----
        int idx = bid - 960;
        int z = idx / 144;
        int rem = idx % 144;
        int r0 = (rem % 24) * 128;
        int c0 = (rem / 24) * 128;
        transpose128_pipe(w2 + (size_t)z * FF * D, w2t + (size_t)z * FF * D,
                          D, FF, r0, c0, smem, tid);
        return;
    }

    // ---- gemm1 persistent flavor ----
    int slot = bid / 48;
    int fBase = (bid % 48) * 64;
    int mt0 = slot * 2;
    int e0 = tme[mt0];
    if (e0 < 0) return;
    int e1 = tme[mt0 + 1];
    bool have2 = (e1 >= 0);
    int mstart0 = tmm[mt0], mlen0 = tml[mt0];
    int mstart1 = have2 ? tmm[mt0 + 1] : mstart0;
    int mlen1   = have2 ? tml[mt0 + 1] : mlen0;
    if (!have2) e1 = e0;

    char* As = smem;              // 2 x 16KB
    char* Bs = smem + 32768;      // 2 x 16KB
    unsigned char* eplds = (unsigned char*)(smem + 65536);  // 8KB

    int lane = tid & 63, wv = tid >> 6;
    int wr = wv & 1, wc = wv >> 1;
    int l15 = lane & 15, lk = lane >> 4;
    int lrow = lane >> 3;
    int swl = (((lane & 7) ^ lrow) << 4);

    const char* xbp = (const char*)xb;
    const char* w1p0 = (const char*)(w1t + (size_t)e0 * FF * D);
    const char* w3p0 = (const char*)(w3t + (size_t)e0 * FF * D);
    const char* w1p1 = (const char*)(w1t + (size_t)e1 * FF * D);
    const char* w3p1 = (const char*)(w3t + (size_t)e1 * FF * D);

    size_t boff[2];
#pragma unroll
    for (int i = 0; i < 2; ++i) {
        int f = (wv + 4 * i) * 8 + lrow;
        boff[i] = (size_t)(fBase + f) * D + swl;
    }

    size_t a0[4], a1[4];
#pragma unroll
    for (int i = 0; i < 4; ++i) {
        int r = (wv + 4 * i) * 8 + lrow;
        int rr0 = r < mlen0 ? r : mlen0 - 1;
        int rr1 = r < mlen1 ? r : mlen1 - 1;
        a0[i] = (size_t)a_tok[mstart0 + rr0] * D + swl;
        a1[i] = (size_t)a_tok[mstart1 + rr1] * D + swl;
    }
    float tb1[2][2], tb3[2][2];
#pragma unroll
    for (int n = 0; n < 2; ++n) {
        int f = fBase + wc * 32 + n * 16 + l15;
        tb1[0][n] = w1b[e0 * FF + f];
        tb3[0][n] = w3b[e0 * FF + f];
        tb1[1][n] = w1b[e1 * FF + f];
        tb3[1][n] = w3b[e1 * FF + f];
    }

    auto stage = [&](int buf, const size_t* ao, const char* w1p_, const char* w3p_, int ks) {
        int kb = ks * 128;
        char* ab = As + buf * 16384;
        char* bb = Bs + buf * 16384;
#pragma unroll
        for (int i = 0; i < 4; ++i)
            gload16(xbp + ao[i] + kb, ab + (wv + 4 * i) * 1024);
#pragma unroll
        for (int i = 0; i < 2; ++i) {
            gload16(w1p_ + boff[i] + kb, bb + (wv + 4 * i) * 1024);
            gload16(w3p_ + boff[i] + kb, bb + 8192 + (wv + 4 * i) * 1024);
        }
    };

    f32x4 hacc[4][2], gacc[4][2];
    auto zacc = [&]() {
#pragma unroll
        for (int m = 0; m < 4; ++m)
#pragma unroll
            for (int n = 0; n < 2; ++n) {
                hacc[m][n] = f32x4{0.f, 0.f, 0.f, 0.f};
                gacc[m][n] = f32x4{0.f, 0.f, 0.f, 0.f};
            }
    };

    auto computeStep = [&](int buf) {
        const char* Ab = As + buf * 16384;
        const char* Bb = Bs + buf * 16384;
        __builtin_amdgcn_s_setprio(1);
#pragma unroll
        for (int ksub = 0; ksub < 4; ++ksub) {
            int koff = ksub * 32 + lk * 8;
            long af[4];
#pragma unroll
            for (int m = 0; m < 4; ++m) {
                int row = wr * 64 + m * 16 + l15;
                af[m] = *(const long*)(Ab + row * 128 + (koff ^ ((row & 7) << 4)));
            }
#pragma unroll
            for (int n = 0; n < 2; ++n) {
                int rowf = wc * 32 + n * 16 + l15;
                int off = rowf * 128 + (koff ^ ((rowf & 7) << 4));
                long b1 = *(const long*)(Bb + off);
                long b3 = *(const long*)(Bb + 8192 + off);
#pragma unroll
                for (int m = 0; m < 4; ++m) {
                    hacc[m][n] = __builtin_amdgcn_mfma_f32_16x16x32_fp8_fp8(af[m], b1, hacc[m][n], 0, 0, 0);
                    gacc[m][n] = __builtin_amdgcn_mfma_f32_16x16x32_fp8_fp8(af[m], b3, gacc[m][n], 0, 0, 0);
                }
            }
        }
        __builtin_amdgcn_s_setprio(0);
    };

    auto epilogueT = [&](const float b1v[2], const float b3v[2], int mstart_, int mlen_) {
#pragma unroll
        for (int m = 0; m < 4; ++m)
#pragma unroll
            for (int n = 0; n < 2; ++n)
#pragma unroll
                for (int j = 0; j < 4; ++j) {
                    float h = hacc[m][n][j] + b1v[n];
                    float gg = gacc[m][n][j] + b3v[n];
                    int row = wr * 64 + m * 16 + lk * 4 + j;
                    int col = wc * 32 + n * 16 + l15;
                    eplds[row * 64 + col] = f2fp8(siluf(h) * siluf(gg));
                }
        __syncthreads();
        int r = tid >> 1, cb = (tid & 1) * 32;
        if (r < mlen_) {
            unsigned char* gp = acts + (size_t)(mstart_ + r) * FF + fBase + cb;
            const unsigned char* lp = eplds + r * 64 + cb;
            *(uint4*)(gp)      = *(const uint4*)(lp);
            *(uint4*)(gp + 16) = *(const uint4*)(lp + 16);
        }
    };

#define G1_WAIT8 asm volatile("s_waitcnt vmcnt(8)" ::: "memory")
#define G1_BAR   __builtin_amdgcn_s_barrier()

    zacc();
    stage(0, a0, w1p0, w3p0, 0);
    stage(1, a0, w1p0, w3p0, 1);
    asm volatile("s_waitcnt vmcnt(0)" ::: "memory");
    __syncthreads();

    /*s0*/ computeStep(0); G1_BAR; stage(0, a0, w1p0, w3p0, 2);
    /*s1*/ G1_BAR; computeStep(1); G1_BAR; stage(1, a0, w1p0, w3p0, 3);
    /*s2*/ G1_WAIT8; G1_BAR; computeStep(0); G1_BAR; stage(0, a0, w1p0, w3p0, 4);
    /*s3*/ G1_WAIT8; G1_BAR; computeStep(1); G1_BAR; stage(1, a0, w1p0, w3p0, 5);
    /*s4*/ G1_WAIT8; G1_BAR; computeStep(0); G1_BAR; stage(0, a1, w1p1, w3p1, 0);
    /*s5*/ G1_WAIT8; G1_BAR; computeStep(1); G1_BAR; stage(1, a1, w1p1, w3p1, 1);

    epilogueT(tb1[0], tb3[0], mstart0, mlen0);
    asm volatile("s_waitcnt vmcnt(0)" ::: "memory");
    __syncthreads();

    if (have2) {
        zacc();
        /*s0*/ computeStep(0); G1_BAR; stage(0, a1, w1p1, w3p1, 2);
        /*s1*/ G1_BAR; computeStep(1); G1_BAR; stage(1, a1, w1p1, w3p1, 3);
        /*s2*/ G1_WAIT8; G1_BAR; computeStep(0); G1_BAR; stage(0, a1, w1p1, w3p1, 4);
        /*s3*/ G1_WAIT8; G1_BAR; computeStep(1); G1_BAR; stage(1, a1, w1p1, w3p1, 5);
        /*s4*/ G1_WAIT8; G1_BAR; computeStep(0); G1_BAR;
        /*s5*/ asm volatile("s_waitcnt vmcnt(0)" ::: "memory"); G1_BAR; computeStep(1); G1_BAR;
        epilogueT(tb1[1], tb3[1], mstart1, mlen1);
    }
#undef G1_WAIT8
#undef G1_BAR
}

// ---------------------------------------------------------------------------
// GEMM2 (fp8): 128x128 tile, split-K=2, BK=128 -> 12 steps. Unchanged.
// ---------------------------------------------------------------------------
__global__ __launch_bounds__(256, 2)
void gemm2_kernel(const unsigned char* __restrict__ acts,
                  const unsigned char* __restrict__ w2t,
                  const int* __restrict__ tme, const int* __restrict__ tmm,
                  const int* __restrict__ tml,
                  float* __restrict__ ffs) {
    int mt = blockIdx.y;
    int e = tme[mt];
    if (e < 0) return;
    int mstart = tmm[mt], mlen = tml[mt];
    int nBase = blockIdx.x * 128;
    int ksl = blockIdx.z;

    __shared__ char As[2][16384];
    __shared__ char Bs[2][16384];

    int tid = threadIdx.x;
    int lane = tid & 63, wv = tid >> 6;
    int wr = wv & 1, wc = wv >> 1;
    int l15 = lane & 15, lk = lane >> 4;
    int lrow = lane >> 3;
    int swl = (((lane & 7) ^ lrow) << 4);

    const char* ap = (const char*)acts;
    const char* w2p = (const char*)(w2t + (size_t)e * (size_t)D * FF);
    size_t aoff[4], boff[4];
#pragma unroll
    for (int i = 0; i < 4; ++i) {
        int r = (wv + 4 * i) * 8 + lrow;
        aoff[i] = (size_t)(mstart + r) * FF + swl;
        boff[i] = (size_t)(nBase + r) * FF + swl;
    }
    int kOff = ksl * (FF / 2);

    auto stage = [&](int buf, int ks) {
        int kb = kOff + ks * 128;
        char* ab = &As[buf][0];
        char* bb = &Bs[buf][0];
#pragma unroll
        for (int i = 0; i < 4; ++i) {
            gload16(ap + aoff[i] + kb, ab + (wv + 4 * i) * 1024);
            gload16(w2p + boff[i] + kb, bb + (wv + 4 * i) * 1024);
        }
    };

    f32x4 facc[4][4];
#pragma unroll
    for (int m = 0; m < 4; ++m)
#pragma unroll
        for (int n = 0; n < 4; ++n) facc[m][n] = f32x4{0.f, 0.f, 0.f, 0.f};

    stage(0, 0);
    stage(1, 1);
#pragma unroll 1
    for (int ks = 0; ks < 12; ++ks) {
        int cur = ks & 1;
        if (ks < 11) asm volatile("s_waitcnt vmcnt(8)" ::: "memory");
        else         asm volatile("s_waitcnt vmcnt(0)" ::: "memory");
        __builtin_amdgcn_s_barrier();
        const char* Ab = &As[cur][0];
        const char* Bb = &Bs[cur][0];
        __builtin_amdgcn_s_setprio(1);
#pragma unroll
        for (int ksub = 0; ksub < 4; ++ksub) {
            int koff = ksub * 32 + lk * 8;
            long af[4], bf[4];
#pragma unroll
            for (int m = 0; m < 4; ++m) {
                int row = wr * 64 + m * 16 + l15;
                af[m] = *(const long*)(Ab + row * 128 + (koff ^ ((row & 7) << 4)));
            }
#pragma unroll
            for (int n = 0; n < 4; ++n) {
                int row = wc * 64 + n * 16 + l15;
                bf[n] = *(const long*)(Bb + row * 128 + (koff ^ ((row & 7) << 4)));
            }
#pragma unroll
            for (int m = 0; m < 4; ++m)
#pragma unroll
                for (int n = 0; n < 4; ++n)
                    facc[m][n] = __builtin_amdgcn_mfma_f32_16x16x32_fp8_fp8(af[m], bf[n], facc[m][n], 0, 0, 0);
        }
        __builtin_amdgcn_s_setprio(0);
        __builtin_amdgcn_s_barrier();
        if (ks < 10) stage(cur, ks + 2);
    }

    float* op = ffs + (size_t)ksl * PSTRIDE;
#pragma unroll
    for (int m = 0; m < 4; ++m)
#pragma unroll
        for (int j = 0; j < 4; ++j) {
            int row = wr * 64 + m * 16 + lk * 4 + j;
            if (row < mlen) {
                float* gp = op + (size_t)(mstart + row) * D + nBase + wc * 64;
#pragma unroll
                for (int n = 0; n < 4; ++n)
                    gp[n * 16 + l15] = facc[m][n][j];
            }
        }
}

// ---------------------------------------------------------------------------
// Combine — unchanged
// ---------------------------------------------------------------------------
__global__ __launch_bounds__(256)
void combine_kernel(const float* __restrict__ x,
                    const float* __restrict__ ffs,
                    const int* __restrict__ e_arr,
                    const int* __restrict__ pos_of,
                    const float* __restrict__ s_arr,
                    const float* __restrict__ w2b,
                    const float* __restrict__ lng,
                    const float* __restrict__ lnb,
                    float* __restrict__ out) {
    int t = blockIdx.x;
    int tid = threadIdx.x;
    int p0 = pos_of[t * 2], p1 = pos_of[t * 2 + 1];
    int e0 = e_arr[t * 2], e1 = e_arr[t * 2 + 1];
    float sw0 = s_arr[t * 2], sw1 = s_arr[t * 2 + 1];
    __shared__ float red[4][4];

    float y0[3], y1[3];
    float s0 = 0.f, q0 = 0.f, s1 = 0.f, q1 = 0.f;
#pragma unroll
    for (int m = 0; m < 3; ++m) {
        int d = tid + 256 * m;
        float xv = x[(size_t)t * D + d];
        float f0 = ffs[(size_t)p0 * D + d] + ffs[PSTRIDE + (size_t)p0 * D + d] + w2b[e0 * D + d];
        float f1 = ffs[(size_t)p1 * D + d] + ffs[PSTRIDE + (size_t)p1 * D + d] + w2b[e1 * D + d];
        float a = xv + sw0 * f0;
        float bb = xv + sw1 * f1;
        y0[m] = a; y1[m] = bb;
        s0 += a; q0 += a * a;
        s1 += bb; q1 += bb * bb;
    }
    for (int off = 32; off; off >>= 1) {
        s0 += __shfl_xor(s0, off);
        q0 += __shfl_xor(q0, off);
        s1 += __shfl_xor(s1, off);
        q1 += __shfl_xor(q1, off);
    }
    int wv = tid >> 6, lane = tid & 63;
    if (lane == 0) { red[wv][0] = s0; red[wv][1] = q0; red[wv][2] = s1; red[wv][3] = q1; }
    __syncthreads();
    s0 = red[0][0] + red[1][0] + red[2][0] + red[3][0];
    q0 = red[0][1] + red[1][1] + red[2][1] + red[3][1];
    s1 = red[0][2] + red[1][2] + red[2][2] + red[3][2];
    q1 = red[0][3] + red[1][3] + red[2][3] + red[3][3];

    const float invD = 1.0f / (float)D;
    float mu0 = s0 * invD, var0 = q0 * invD - mu0 * mu0;
    float mu1 = s1 * invD, var1 = q1 * invD - mu1 * mu1;
    float r0 = rsqrtf(var0 + 1e-5f);
    float r1 = rsqrtf(var1 + 1e-5f);

#pragma unroll
    for (int m = 0; m < 3; ++m) {
        int d = tid + 256 * m;
        out[(size_t)t * D + d] =
            (y0[m] - mu0) * r0 * lng[e0 * D + d] + lnb[e0 * D + d] +
            (y1[m] - mu1) * r1 * lng[e1 * D + d] + lnb[e1 * D + d];
    }
}

// ---------------------------------------------------------------------------
extern "C" void kernel_launch(void* const* d_in, const int* in_sizes, int n_in,
                              void* d_out, int out_size, void* d_ws, size_t ws_size,
                              hipStream_t stream) {
    const float* x   = (const float*)d_in[0];
    const float* rw  = (const float*)d_in[1];
    const float* rb  = (const float*)d_in[2];
    const float* dgw = (const float*)d_in[3];
    const float* dgb = (const float*)d_in[4];
    const float* w1  = (const float*)d_in[5];
    const float* w1b = (const float*)d_in[6];
    const float* w2  = (const float*)d_in[7];
    const float* w2b = (const float*)d_in[8];
    const float* w3  = (const float*)d_in[9];
    const float* w3b = (const float*)d_in[10];
    const float* lng = (const float*)d_in[11];
    const float* lnb = (const float*)d_in[12];

    float* out = (float*)d_out;
    float* load_out = out + (size_t)T * D;

    char* w = (char*)d_ws;
    size_t off = 0;
    auto alloc = [&](size_t bytes) -> void* {
        void* p = w + off;
        off = (off + bytes + 255) & ~(size_t)255;
        return p;
    };
    int* e_arr    = (int*)alloc(NPOS * sizeof(int));
    int* a_tok    = (int*)alloc(NPOS * sizeof(int));
    int* pos_of   = (int*)alloc(NPOS * sizeof(int));
    float* s_arr  = (float*)alloc(NPOS * sizeof(float));
    int* tme      = (int*)alloc(MAXTILE * sizeof(int));
    int* tmm      = (int*)alloc(MAXTILE * sizeof(int));
    int* tml      = (int*)alloc(MAXTILE * sizeof(int));
    unsigned char* xb  = (unsigned char*)alloc((size_t)T * D);
    unsigned char* w1t = (unsigned char*)alloc((size_t)E * D * FF);
    unsigned char* w3t = (unsigned char*)alloc((size_t)E * D * FF);
    unsigned char* w2t = (unsigned char*)alloc((size_t)E * D * FF);
    unsigned char* acts = (unsigned char*)alloc((size_t)(NPOS + 128) * FF);
    float* ffs    = (float*)alloc(2 * PSTRIDE * sizeof(float));

    pre_kernel<<<512 + 2304, 256, 0, stream>>>(x, rw, rb, dgw, dgb, w1, w3,
                                               xb, e_arr, s_arr, w1t, w3t);
    scan_assign_kernel<<<1, 256, 0, stream>>>(e_arr, load_out, tme, tmm, tml,
                                              a_tok, pos_of);
    gemm1_w2t_kernel<<<960 + 1152, 256, 0, stream>>>(
        w2, w2t, xb, w1t, w1b, w3t, w3b, a_tok, tme, tmm, tml, acts);
    gemm2_kernel<<<dim3(D / 128, MAXTILE, 2), 256, 0, stream>>>(
        acts, w2t, tme, tmm, tml, ffs);
    combine_kernel<<<T, 256, 0, stream>>>(x, ffs, e_arr, pos_of, s_arr, w2b, lng, lnb, out);
}